// Round 2
// baseline (2793.488 us; speedup 1.0000x reference)
//
#include <hip/hip_runtime.h>
#include <hip/hip_bf16.h>

#define F_IN    256
#define D_HID   64
#define H_HEADS 8
#define NC      10
#define ALPHA   0.2f
#define FLAG_THRESH 64

// ---------- bf16 helpers ----------
__device__ __forceinline__ float bfu2f(unsigned short u) {
    union { float f; unsigned int i; } c; c.i = ((unsigned int)u) << 16; return c.f;
}
__device__ __forceinline__ unsigned short f2bfu(float f) {
    union { float f; unsigned int i; } c; c.f = f;
    unsigned int x = c.i;
    x += 0x7fffu + ((x >> 16) & 1u);   // round-to-nearest-even
    return (unsigned short)(x >> 16);
}

// ---------- dtype detection: are the float inputs stored as f32 or bf16? ----------
// For bf16 data, both 16-bit halves of a word are plausible small values.
// For f32 data, the low 16 bits are mantissa noise -> as bf16, exponent field
// is ~uniform(0..255) -> ~46% of words look "huge". Count them.
__global__ void detect_kernel(const unsigned int* __restrict__ x, int* __restrict__ flag) {
    int t = threadIdx.x;
    int cnt = 0;
    for (int i = t; i < 4096; i += 256) {
        unsigned int w = x[i];
        unsigned int e = (w >> 7) & 0xffu;   // exponent of low-half-as-bf16
        if (e >= 140u) cnt++;                 // |v| >= 2^13 -> impossible for real data
    }
    atomicAdd(flag, cnt);
}

// ---------- canonicalize any float tensor to f32 ----------
__global__ __launch_bounds__(256) void convert_kernel(
    const void* __restrict__ src, float* __restrict__ dst, long n,
    const int* __restrict__ flagp)
{
    long i = (long)blockIdx.x * 256 + threadIdx.x;
    if (i >= n) return;
    bool isf32 = (*flagp > FLAG_THRESH);
    dst[i] = isf32 ? ((const float*)src)[i]
                   : bfu2f(((const unsigned short*)src)[i]);
}

// ---------- layer-1 GEMM: h_all[n, h*64+d] = sum_k x[n,k] * W_heads[h,k,d] ----------
// grid (ceil(N/64), 8); block 256. Each block: 64 rows x one head (64 cols).
__global__ __launch_bounds__(256) void gemm1_kernel(
    const float* __restrict__ x,      // [N,256] f32
    const float* __restrict__ Wh,     // [8,256,64] f32
    float* __restrict__ h_all,        // [N,512] f32 out
    int N)
{
    __shared__ float Xs[64][33];
    __shared__ float Ws[32][64];
    const int nb = blockIdx.x, hh = blockIdx.y;
    const int t  = threadIdx.x;
    const int tx = t & 15, ty = t >> 4;
    const int n0 = nb * 64;
    const float* Wb = Wh + hh * (F_IN * D_HID);

    float acc[4][4] = {{0.f}};

    for (int k0 = 0; k0 < F_IN; k0 += 32) {
        // X tile: 64 rows x 32 k = 512 float4; W tile: 32 k x 64 d = 512 float4
        float4 xv[2], wv[2];
        #pragma unroll
        for (int p = 0; p < 2; ++p) {
            int q = t + p * 256;
            int xr = q >> 3, xc = (q & 7) * 4;
            if (n0 + xr < N) xv[p] = *(const float4*)(x + (long)(n0 + xr) * F_IN + k0 + xc);
            else             xv[p] = make_float4(0.f, 0.f, 0.f, 0.f);
            int wr = q >> 4, wc = (q & 15) * 4;
            wv[p] = *(const float4*)(Wb + (long)(k0 + wr) * D_HID + wc);
        }

        __syncthreads();
        #pragma unroll
        for (int p = 0; p < 2; ++p) {
            int q = t + p * 256;
            int xr = q >> 3, xc = (q & 7) * 4;
            Xs[xr][xc + 0] = xv[p].x; Xs[xr][xc + 1] = xv[p].y;
            Xs[xr][xc + 2] = xv[p].z; Xs[xr][xc + 3] = xv[p].w;
            int wr = q >> 4, wc = (q & 15) * 4;
            *(float4*)&Ws[wr][wc] = wv[p];
        }
        __syncthreads();

        #pragma unroll 8
        for (int kk = 0; kk < 32; ++kk) {
            float xr4[4], wc4[4];
            #pragma unroll
            for (int i = 0; i < 4; ++i) xr4[i] = Xs[ty * 4 + i][kk];
            #pragma unroll
            for (int j = 0; j < 4; ++j) wc4[j] = Ws[kk][tx * 4 + j];
            #pragma unroll
            for (int i = 0; i < 4; ++i)
                #pragma unroll
                for (int j = 0; j < 4; ++j) acc[i][j] += xr4[i] * wc4[j];
        }
    }

    #pragma unroll
    for (int i = 0; i < 4; ++i) {
        int n = n0 + ty * 4 + i;
        if (n < N)
            *(float4*)(h_all + (long)n * 512 + hh * 64 + tx * 4) =
                make_float4(acc[i][0], acc[i][1], acc[i][2], acc[i][3]);
    }
}

// ---------- per-node attention score halves (layer 1) ----------
__global__ __launch_bounds__(256) void attn1_kernel(
    const float* __restrict__ h_all,   // [N,512] f32
    const float* __restrict__ ah,      // [8,128] f32
    float* __restrict__ s_src, float* __restrict__ s_dst, int N)
{
    int tid = blockIdx.x * 256 + threadIdx.x;
    if (tid >= N * H_HEADS) return;
    int h = tid & 7;
    const float* hp = h_all + (long)(tid >> 3) * 512 + h * 64;
    const float* ap = ah + h * 128;
    float s1 = 0.f, s2 = 0.f;
    #pragma unroll
    for (int d = 0; d < 64; ++d) {
        float hv = hp[d];
        s1 += hv * ap[d];
        s2 += hv * ap[64 + d];
    }
    s_src[tid] = s1;
    s_dst[tid] = s2;
}

// ---------- layer-1 edge scatter: one wave per (edge, head), 64 lanes = 64 feats ----------
__global__ __launch_bounds__(256) void edge_pass1_kernel(
    const int* __restrict__ src, const int* __restrict__ dst,
    const float* __restrict__ h_all,
    const float* __restrict__ s_src, const float* __restrict__ s_dst,
    float* __restrict__ rowsum, float* __restrict__ agg, int E)
{
    int lane = threadIdx.x & 63;
    long w = (long)blockIdx.x * 4 + (threadIdx.x >> 6);
    int h = (int)(w & 7);
    long e = w >> 3;
    if (e >= E) return;
    int s = src[e], d = dst[e];
    float sc = s_src[s * 8 + h] + s_dst[d * 8 + h];
    float lr = sc > 0.f ? sc : ALPHA * sc;
    float ev = __expf(-lr);
    if (lane == 0) atomicAdd(&rowsum[s * 8 + h], ev);
    float hv = h_all[(long)d * 512 + h * 64 + lane];
    atomicAdd(&agg[(long)s * 512 + h * 64 + lane], ev * hv);
}

// ---------- layer-1 normalize + ELU (in place: agg -> xcat) ----------
__global__ __launch_bounds__(256) void finalize1_kernel(
    float* __restrict__ agg, const float* __restrict__ rowsum, int N)
{
    long tid = (long)blockIdx.x * 256 + threadIdx.x;
    if (tid >= (long)N * 512) return;
    int j = (int)(tid & 511);
    int n = (int)(tid >> 9);
    float v = agg[tid] / rowsum[n * 8 + (j >> 6)];
    agg[tid] = v > 0.f ? v : __expf(v) - 1.f;
}

// ---------- layer-2 GEMM: h2[n,c] = sum_k xcat[n,k] * W_out[k,c] ----------
__global__ __launch_bounds__(256) void gemm2_kernel(
    const float* __restrict__ xcat,   // [N,512] f32
    const float* __restrict__ Wo,     // [512,10] f32
    float* __restrict__ h2, int N)
{
    __shared__ float Ws[512 * NC];
    for (int i = threadIdx.x; i < 512 * NC; i += 256) Ws[i] = Wo[i];
    __syncthreads();
    int tid = blockIdx.x * 256 + threadIdx.x;
    if (tid >= N * NC) return;
    int c = tid % NC;
    int n = tid / NC;
    const float* xp = xcat + (long)n * 512;
    float acc = 0.f;
    for (int k = 0; k < 512; k += 4) {
        float4 xv = *(const float4*)(xp + k);
        acc += xv.x * Ws[(k + 0) * NC + c];
        acc += xv.y * Ws[(k + 1) * NC + c];
        acc += xv.z * Ws[(k + 2) * NC + c];
        acc += xv.w * Ws[(k + 3) * NC + c];
    }
    h2[tid] = acc;
}

// ---------- per-node score halves (layer 2) ----------
__global__ __launch_bounds__(256) void attn2_kernel(
    const float* __restrict__ h2, const float* __restrict__ ao,
    float* __restrict__ s_src2, float* __restrict__ s_dst2, int N)
{
    int n = blockIdx.x * 256 + threadIdx.x;
    if (n >= N) return;
    float s1 = 0.f, s2 = 0.f;
    #pragma unroll
    for (int c = 0; c < NC; ++c) {
        float v = h2[n * NC + c];
        s1 += v * ao[c];
        s2 += v * ao[NC + c];
    }
    s_src2[n] = s1;
    s_dst2[n] = s2;
}

// ---------- layer-2 edge scatter: one thread per edge ----------
__global__ __launch_bounds__(256) void edge_pass2_kernel(
    const int* __restrict__ src, const int* __restrict__ dst,
    const float* __restrict__ h2,
    const float* __restrict__ s_src2, const float* __restrict__ s_dst2,
    float* __restrict__ rowsum2, float* __restrict__ agg2, int E)
{
    int e = blockIdx.x * 256 + threadIdx.x;
    if (e >= E) return;
    int s = src[e], d = dst[e];
    float sc = s_src2[s] + s_dst2[d];
    float lr = sc > 0.f ? sc : ALPHA * sc;
    float ev = __expf(-lr);
    atomicAdd(&rowsum2[s], ev);
    const float* hp = h2 + (long)d * NC;
    float* ap = agg2 + (long)s * NC;
    #pragma unroll
    for (int c = 0; c < NC; ++c) atomicAdd(&ap[c], ev * hp[c]);
}

// ---------- layer-2 normalize + ELU + log_softmax -> out (dtype per flag) ----------
__global__ __launch_bounds__(256) void finalize2_kernel(
    const float* __restrict__ agg2, const float* __restrict__ rowsum2,
    void* __restrict__ out, const int* __restrict__ flagp, int N)
{
    int n = blockIdx.x * 256 + threadIdx.x;
    if (n >= N) return;
    float inv = 1.f / rowsum2[n];
    float o[NC], m = -1e30f;
    #pragma unroll
    for (int c = 0; c < NC; ++c) {
        float v = agg2[n * NC + c] * inv;
        v = v > 0.f ? v : __expf(v) - 1.f;   // elu
        o[c] = v;
        m = fmaxf(m, v);
    }
    float sum = 0.f;
    #pragma unroll
    for (int c = 0; c < NC; ++c) sum += __expf(o[c] - m);
    float lse = m + logf(sum);
    bool isf32 = (*flagp > FLAG_THRESH);
    if (isf32) {
        float* op = (float*)out;
        #pragma unroll
        for (int c = 0; c < NC; ++c) op[n * NC + c] = o[c] - lse;
    } else {
        unsigned short* op = (unsigned short*)out;
        #pragma unroll
        for (int c = 0; c < NC; ++c) op[n * NC + c] = f2bfu(o[c] - lse);
    }
}

extern "C" void kernel_launch(void* const* d_in, const int* in_sizes, int n_in,
                              void* d_out, int out_size, void* d_ws, size_t ws_size,
                              hipStream_t stream)
{
    const void* x_raw  = d_in[0];             // [N,256] f32 or bf16
    const int*  esrc   = (const int*)d_in[1]; // [E]
    const int*  edst   = (const int*)d_in[2]; // [E]
    const void* Wh_raw = d_in[3];             // [8,256,64]
    const void* ah_raw = d_in[4];             // [8,128]
    const void* Wo_raw = d_in[5];             // [512,10]
    const void* ao_raw = d_in[6];             // [20]

    const int N = in_sizes[0] / F_IN;
    const int E = in_sizes[1];

    char* ws = (char*)d_ws;
    size_t off = 0;
    auto alloc = [&](size_t bytes) -> void* {
        void* p = ws + off;
        off = (off + bytes + 255) & ~(size_t)255;
        return p;
    };
    int*   flag  = (int*)  alloc(4);
    float* x32   = (float*)alloc((size_t)N * F_IN * 4);        // 51.2 MB
    float* Wh32  = (float*)alloc((size_t)H_HEADS * F_IN * D_HID * 4);
    float* ah32  = (float*)alloc((size_t)H_HEADS * 2 * D_HID * 4);
    float* Wo32  = (float*)alloc((size_t)H_HEADS * D_HID * NC * 4);
    float* ao32  = (float*)alloc((size_t)2 * NC * 4);
    float* h_all = (float*)alloc((size_t)N * 512 * 4);         // 102.4 MB
    float* agg1  = (float*)alloc((size_t)N * 512 * 4);         // 102.4 MB
    float* s1s   = (float*)alloc((size_t)N * 8 * 4);
    float* s1d   = (float*)alloc((size_t)N * 8 * 4);
    float* rs1   = (float*)alloc((size_t)N * 8 * 4);
    float* h2    = (float*)alloc((size_t)N * NC * 4);
    float* s2s   = (float*)alloc((size_t)N * 4);
    float* s2d   = (float*)alloc((size_t)N * 4);
    float* rs2   = (float*)alloc((size_t)N * 4);
    float* agg2  = (float*)alloc((size_t)N * NC * 4);
    (void)ws_size;

    // zero accumulators + flag (ws re-poisoned 0xAA before every timed launch)
    hipMemsetAsync(flag, 0, 4, stream);
    hipMemsetAsync(agg1, 0, (size_t)N * 512 * 4, stream);
    hipMemsetAsync(rs1,  0, (size_t)N * 8 * 4, stream);
    hipMemsetAsync(rs2,  0, (size_t)N * 4, stream);
    hipMemsetAsync(agg2, 0, (size_t)N * NC * 4, stream);

    // dtype detect + canonicalize to f32
    detect_kernel<<<1, 256, 0, stream>>>((const unsigned int*)x_raw, flag);
    long nx = (long)N * F_IN;
    convert_kernel<<<(unsigned)((nx + 255) / 256), 256, 0, stream>>>(x_raw, x32, nx, flag);
    convert_kernel<<<(H_HEADS * F_IN * D_HID + 255) / 256, 256, 0, stream>>>(Wh_raw, Wh32, H_HEADS * F_IN * D_HID, flag);
    convert_kernel<<<(H_HEADS * 2 * D_HID + 255) / 256, 256, 0, stream>>>(ah_raw, ah32, H_HEADS * 2 * D_HID, flag);
    convert_kernel<<<(512 * NC + 255) / 256, 256, 0, stream>>>(Wo_raw, Wo32, 512 * NC, flag);
    convert_kernel<<<1, 256, 0, stream>>>(ao_raw, ao32, 2 * NC, flag);

    // layer 1
    dim3 g1((N + 63) / 64, H_HEADS);
    gemm1_kernel<<<g1, 256, 0, stream>>>(x32, Wh32, h_all, N);
    attn1_kernel<<<(N * H_HEADS + 255) / 256, 256, 0, stream>>>(h_all, ah32, s1s, s1d, N);
    long waves1 = (long)E * H_HEADS;
    edge_pass1_kernel<<<(unsigned)((waves1 + 3) / 4), 256, 0, stream>>>(esrc, edst, h_all, s1s, s1d, rs1, agg1, E);
    finalize1_kernel<<<(unsigned)(((long)N * 512 + 255) / 256), 256, 0, stream>>>(agg1, rs1, N);

    // layer 2
    gemm2_kernel<<<(N * NC + 255) / 256, 256, 0, stream>>>(agg1, Wo32, h2, N);
    attn2_kernel<<<(N + 255) / 256, 256, 0, stream>>>(h2, ao32, s2s, s2d, N);
    edge_pass2_kernel<<<(E + 255) / 256, 256, 0, stream>>>(esrc, edst, h2, s2s, s2d, rs2, agg2, E);
    finalize2_kernel<<<(N + 255) / 256, 256, 0, stream>>>(agg2, rs2, d_out, flag, N);
}

// Round 3
// 992.916 us; speedup vs baseline: 2.8134x; 2.8134x over previous
//
#include <hip/hip_runtime.h>
#include <hip/hip_bf16.h>

#define F_IN    256
#define D_HID   64
#define H_HEADS 8
#define NC      10
#define ALPHA   0.2f
#define FLAG_THRESH 64
#define SCAN_T  1024

// ---------- bf16 helpers ----------
__device__ __forceinline__ float bfu2f(unsigned short u) {
    union { float f; unsigned int i; } c; c.i = ((unsigned int)u) << 16; return c.f;
}
__device__ __forceinline__ unsigned short f2bfu(float f) {
    union { float f; unsigned int i; } c; c.f = f;
    unsigned int x = c.i;
    x += 0x7fffu + ((x >> 16) & 1u);   // round-to-nearest-even
    return (unsigned short)(x >> 16);
}

// ---------- dtype detection (f32 vs bf16 storage) ----------
__global__ void detect_kernel(const unsigned int* __restrict__ x, int* __restrict__ flag) {
    int t = threadIdx.x;
    int cnt = 0;
    for (int i = t; i < 4096; i += 256) {
        unsigned int w = x[i];
        unsigned int e = (w >> 7) & 0xffu;   // exponent of low-half-as-bf16
        if (e >= 140u) cnt++;
    }
    atomicAdd(flag, cnt);
}

// ---------- canonicalize any float tensor to f32 ----------
__global__ __launch_bounds__(256) void convert_kernel(
    const void* __restrict__ src, float* __restrict__ dst, long n,
    const int* __restrict__ flagp)
{
    long i = (long)blockIdx.x * 256 + threadIdx.x;
    if (i >= n) return;
    bool isf32 = (*flagp > FLAG_THRESH);
    dst[i] = isf32 ? ((const float*)src)[i]
                   : bfu2f(((const unsigned short*)src)[i]);
}

// ---------- CSR build: histogram ----------
__global__ __launch_bounds__(256) void hist_kernel(
    const int* __restrict__ src, int* __restrict__ counts, int E)
{
    int e = blockIdx.x * 256 + threadIdx.x;
    if (e < E) atomicAdd(&counts[src[e]], 1);
}

// ---------- CSR build: single-block exclusive scan over counts[N] ----------
__global__ __launch_bounds__(SCAN_T) void scan_kernel(
    const int* __restrict__ counts, int* __restrict__ row_start, int N, int E)
{
    __shared__ int sums[SCAN_T];
    int t = threadIdx.x;
    int chunk = (N + SCAN_T - 1) / SCAN_T;
    int b = t * chunk, e = min(b + chunk, N);
    int s = 0;
    for (int i = b; i < e; ++i) s += counts[i];
    sums[t] = s;
    __syncthreads();
    for (int off = 1; off < SCAN_T; off <<= 1) {
        int u = (t >= off) ? sums[t - off] : 0;
        __syncthreads();
        sums[t] += u;
        __syncthreads();
    }
    int running = sums[t] - s;   // exclusive prefix of this thread's chunk
    for (int i = b; i < e; ++i) { row_start[i] = running; running += counts[i]; }
    if (t == SCAN_T - 1) row_start[N] = E;
}

// ---------- CSR build: scatter dst ids into rows ----------
__global__ __launch_bounds__(256) void scatter_kernel(
    const int* __restrict__ src, const int* __restrict__ dst,
    const int* __restrict__ row_start, int* __restrict__ cursor,
    int* __restrict__ csr_dst, int E)
{
    int e = blockIdx.x * 256 + threadIdx.x;
    if (e >= E) return;
    int s = src[e];
    int pos = atomicAdd(&cursor[s], 1);
    csr_dst[row_start[s] + pos] = dst[e];
}

// ---------- layer-1 GEMM: h_all[n, h*64+d] = sum_k x[n,k] * W_heads[h,k,d] ----------
__global__ __launch_bounds__(256) void gemm1_kernel(
    const float* __restrict__ x,      // [N,256] f32
    const float* __restrict__ Wh,     // [8,256,64] f32
    float* __restrict__ h_all,        // [N,512] f32 out
    int N)
{
    __shared__ float Xs[64][33];
    __shared__ float Ws[32][64];
    const int nb = blockIdx.x, hh = blockIdx.y;
    const int t  = threadIdx.x;
    const int tx = t & 15, ty = t >> 4;
    const int n0 = nb * 64;
    const float* Wb = Wh + hh * (F_IN * D_HID);

    float acc[4][4] = {{0.f}};

    for (int k0 = 0; k0 < F_IN; k0 += 32) {
        float4 xv[2], wv[2];
        #pragma unroll
        for (int p = 0; p < 2; ++p) {
            int q = t + p * 256;
            int xr = q >> 3, xc = (q & 7) * 4;
            if (n0 + xr < N) xv[p] = *(const float4*)(x + (long)(n0 + xr) * F_IN + k0 + xc);
            else             xv[p] = make_float4(0.f, 0.f, 0.f, 0.f);
            int wr = q >> 4, wc = (q & 15) * 4;
            wv[p] = *(const float4*)(Wb + (long)(k0 + wr) * D_HID + wc);
        }

        __syncthreads();
        #pragma unroll
        for (int p = 0; p < 2; ++p) {
            int q = t + p * 256;
            int xr = q >> 3, xc = (q & 7) * 4;
            Xs[xr][xc + 0] = xv[p].x; Xs[xr][xc + 1] = xv[p].y;
            Xs[xr][xc + 2] = xv[p].z; Xs[xr][xc + 3] = xv[p].w;
            int wr = q >> 4, wc = (q & 15) * 4;
            *(float4*)&Ws[wr][wc] = wv[p];
        }
        __syncthreads();

        #pragma unroll 8
        for (int kk = 0; kk < 32; ++kk) {
            float xr4[4], wc4[4];
            #pragma unroll
            for (int i = 0; i < 4; ++i) xr4[i] = Xs[ty * 4 + i][kk];
            #pragma unroll
            for (int j = 0; j < 4; ++j) wc4[j] = Ws[kk][tx * 4 + j];
            #pragma unroll
            for (int i = 0; i < 4; ++i)
                #pragma unroll
                for (int j = 0; j < 4; ++j) acc[i][j] += xr4[i] * wc4[j];
        }
    }

    #pragma unroll
    for (int i = 0; i < 4; ++i) {
        int n = n0 + ty * 4 + i;
        if (n < N)
            *(float4*)(h_all + (long)n * 512 + hh * 64 + tx * 4) =
                make_float4(acc[i][0], acc[i][1], acc[i][2], acc[i][3]);
    }
}

// ---------- per-node attention score halves (layer 1) ----------
__global__ __launch_bounds__(256) void attn1_kernel(
    const float* __restrict__ h_all,   // [N,512] f32
    const float* __restrict__ ah,      // [8,128] f32
    float* __restrict__ s_src, float* __restrict__ s_dst, int N)
{
    int tid = blockIdx.x * 256 + threadIdx.x;
    if (tid >= N * H_HEADS) return;
    int h = tid & 7;
    const float* hp = h_all + (long)(tid >> 3) * 512 + h * 64;
    const float* ap = ah + h * 128;
    float s1 = 0.f, s2 = 0.f;
    #pragma unroll
    for (int d = 0; d < 64; ++d) {
        float hv = hp[d];
        s1 += hv * ap[d];
        s2 += hv * ap[64 + d];
    }
    s_src[tid] = s1;
    s_dst[tid] = s2;
}

// ---------- layer-1 CSR gather: wave per (node, head), lanes = 64 feats ----------
// Fuses normalize + ELU; writes xcat directly. NO atomics.
__global__ __launch_bounds__(256) void edge_agg1_kernel(
    const int* __restrict__ row_start, const int* __restrict__ csr_dst,
    const float* __restrict__ h_all,
    const float* __restrict__ s_src, const float* __restrict__ s_dst,
    float* __restrict__ xcat, int N)
{
    int lane = threadIdx.x & 63;
    int h = (int)blockIdx.y * 4 + (threadIdx.x >> 6);
    int n = blockIdx.x;
    int beg = row_start[n], end = row_start[n + 1];
    float ss = s_src[n * 8 + h];
    float acc = 0.f, rs = 0.f;
    for (int i = beg; i < end; ++i) {
        int d = csr_dst[i];
        float sc = ss + s_dst[d * 8 + h];
        float lr = sc > 0.f ? sc : ALPHA * sc;
        float ev = __expf(-lr);
        rs += ev;
        acc += ev * h_all[(long)d * 512 + h * 64 + lane];
    }
    float v = acc / rs;
    xcat[(long)n * 512 + h * 64 + lane] = v > 0.f ? v : __expf(v) - 1.f;
}

// ---------- layer-2 GEMM: h2[n,c] = sum_k xcat[n,k] * W_out[k,c] ----------
__global__ __launch_bounds__(256) void gemm2_kernel(
    const float* __restrict__ xcat,   // [N,512] f32
    const float* __restrict__ Wo,     // [512,10] f32
    float* __restrict__ h2, int N)
{
    __shared__ float Ws[512 * NC];
    for (int i = threadIdx.x; i < 512 * NC; i += 256) Ws[i] = Wo[i];
    __syncthreads();
    int tid = blockIdx.x * 256 + threadIdx.x;
    if (tid >= N * NC) return;
    int c = tid % NC;
    int n = tid / NC;
    const float* xp = xcat + (long)n * 512;
    float acc = 0.f;
    for (int k = 0; k < 512; k += 4) {
        float4 xv = *(const float4*)(xp + k);
        acc += xv.x * Ws[(k + 0) * NC + c];
        acc += xv.y * Ws[(k + 1) * NC + c];
        acc += xv.z * Ws[(k + 2) * NC + c];
        acc += xv.w * Ws[(k + 3) * NC + c];
    }
    h2[tid] = acc;
}

// ---------- per-node score halves (layer 2) ----------
__global__ __launch_bounds__(256) void attn2_kernel(
    const float* __restrict__ h2, const float* __restrict__ ao,
    float* __restrict__ s_src2, float* __restrict__ s_dst2, int N)
{
    int n = blockIdx.x * 256 + threadIdx.x;
    if (n >= N) return;
    float s1 = 0.f, s2 = 0.f;
    #pragma unroll
    for (int c = 0; c < NC; ++c) {
        float v = h2[n * NC + c];
        s1 += v * ao[c];
        s2 += v * ao[NC + c];
    }
    s_src2[n] = s1;
    s_dst2[n] = s2;
}

// ---------- layer-2 CSR gather: wave per node, lanes split edges ----------
// Fuses normalize + ELU + log_softmax; writes d_out. NO atomics.
__global__ __launch_bounds__(256) void edge_agg2_kernel(
    const int* __restrict__ row_start, const int* __restrict__ csr_dst,
    const float* __restrict__ h2,
    const float* __restrict__ s_src2, const float* __restrict__ s_dst2,
    void* __restrict__ out, const int* __restrict__ flagp, int N)
{
    int lane = threadIdx.x & 63;
    int n = blockIdx.x * 4 + (threadIdx.x >> 6);
    if (n >= N) return;
    int beg = row_start[n], end = row_start[n + 1];
    float ss = s_src2[n];
    float rs = 0.f, acc[NC];
    #pragma unroll
    for (int c = 0; c < NC; ++c) acc[c] = 0.f;
    for (int i = beg + lane; i < end; i += 64) {
        int d = csr_dst[i];
        float sc = ss + s_dst2[d];
        float lr = sc > 0.f ? sc : ALPHA * sc;
        float ev = __expf(-lr);
        rs += ev;
        const float* hp = h2 + (long)d * NC;
        #pragma unroll
        for (int c = 0; c < NC; ++c) acc[c] += ev * hp[c];
    }
    #pragma unroll
    for (int off = 32; off >= 1; off >>= 1) {
        rs += __shfl_xor(rs, off, 64);
        #pragma unroll
        for (int c = 0; c < NC; ++c) acc[c] += __shfl_xor(acc[c], off, 64);
    }
    if (lane == 0) {
        float inv = 1.f / rs;
        float o[NC], m = -1e30f;
        #pragma unroll
        for (int c = 0; c < NC; ++c) {
            float v = acc[c] * inv;
            v = v > 0.f ? v : __expf(v) - 1.f;   // elu
            o[c] = v;
            m = fmaxf(m, v);
        }
        float sum = 0.f;
        #pragma unroll
        for (int c = 0; c < NC; ++c) sum += __expf(o[c] - m);
        float lse = m + logf(sum);
        bool isf32 = (*flagp > FLAG_THRESH);
        if (isf32) {
            float* op = (float*)out;
            #pragma unroll
            for (int c = 0; c < NC; ++c) op[n * NC + c] = o[c] - lse;
        } else {
            unsigned short* op = (unsigned short*)out;
            #pragma unroll
            for (int c = 0; c < NC; ++c) op[n * NC + c] = f2bfu(o[c] - lse);
        }
    }
}

extern "C" void kernel_launch(void* const* d_in, const int* in_sizes, int n_in,
                              void* d_out, int out_size, void* d_ws, size_t ws_size,
                              hipStream_t stream)
{
    const void* x_raw  = d_in[0];
    const int*  esrc   = (const int*)d_in[1];
    const int*  edst   = (const int*)d_in[2];
    const void* Wh_raw = d_in[3];
    const void* ah_raw = d_in[4];
    const void* Wo_raw = d_in[5];
    const void* ao_raw = d_in[6];

    const int N = in_sizes[0] / F_IN;
    const int E = in_sizes[1];

    char* ws = (char*)d_ws;
    size_t off = 0;
    auto alloc = [&](size_t bytes) -> void* {
        void* p = ws + off;
        off = (off + bytes + 255) & ~(size_t)255;
        return p;
    };
    int*   flag      = (int*)  alloc(4);
    float* x32       = (float*)alloc((size_t)N * F_IN * 4);
    float* Wh32      = (float*)alloc((size_t)H_HEADS * F_IN * D_HID * 4);
    float* ah32      = (float*)alloc((size_t)H_HEADS * 2 * D_HID * 4);
    float* Wo32      = (float*)alloc((size_t)512 * NC * 4);
    float* ao32      = (float*)alloc((size_t)2 * NC * 4);
    float* h_all     = (float*)alloc((size_t)N * 512 * 4);
    float* xcat      = (float*)alloc((size_t)N * 512 * 4);
    float* s1s       = (float*)alloc((size_t)N * 8 * 4);
    float* s1d       = (float*)alloc((size_t)N * 8 * 4);
    float* h2        = (float*)alloc((size_t)N * NC * 4);
    float* s2s       = (float*)alloc((size_t)N * 4);
    float* s2d       = (float*)alloc((size_t)N * 4);
    int*   counts    = (int*)  alloc((size_t)N * 4);
    int*   cursor    = (int*)  alloc((size_t)N * 4);
    int*   row_start = (int*)  alloc((size_t)(N + 1) * 4);
    int*   csr_dst   = (int*)  alloc((size_t)E * 4);
    (void)ws_size;

    hipMemsetAsync(flag, 0, 4, stream);
    hipMemsetAsync(counts, 0, (size_t)N * 4, stream);
    hipMemsetAsync(cursor, 0, (size_t)N * 4, stream);

    // dtype detect + canonicalize to f32
    detect_kernel<<<1, 256, 0, stream>>>((const unsigned int*)x_raw, flag);
    long nx = (long)N * F_IN;
    convert_kernel<<<(unsigned)((nx + 255) / 256), 256, 0, stream>>>(x_raw, x32, nx, flag);
    convert_kernel<<<(H_HEADS * F_IN * D_HID + 255) / 256, 256, 0, stream>>>(Wh_raw, Wh32, H_HEADS * F_IN * D_HID, flag);
    convert_kernel<<<(H_HEADS * 2 * D_HID + 255) / 256, 256, 0, stream>>>(ah_raw, ah32, H_HEADS * 2 * D_HID, flag);
    convert_kernel<<<(512 * NC + 255) / 256, 256, 0, stream>>>(Wo_raw, Wo32, 512 * NC, flag);
    convert_kernel<<<1, 256, 0, stream>>>(ao_raw, ao32, 2 * NC, flag);

    // CSR build (shared by both layers)
    hist_kernel<<<(E + 255) / 256, 256, 0, stream>>>(esrc, counts, E);
    scan_kernel<<<1, SCAN_T, 0, stream>>>(counts, row_start, N, E);
    scatter_kernel<<<(E + 255) / 256, 256, 0, stream>>>(esrc, edst, row_start, cursor, csr_dst, E);

    // layer 1
    dim3 g1((N + 63) / 64, H_HEADS);
    gemm1_kernel<<<g1, 256, 0, stream>>>(x32, Wh32, h_all, N);
    attn1_kernel<<<(N * H_HEADS + 255) / 256, 256, 0, stream>>>(h_all, ah32, s1s, s1d, N);
    dim3 ga1(N, 2);
    edge_agg1_kernel<<<ga1, 256, 0, stream>>>(row_start, csr_dst, h_all, s1s, s1d, xcat, N);

    // layer 2
    gemm2_kernel<<<(N * NC + 255) / 256, 256, 0, stream>>>(xcat, Wo32, h2, N);
    attn2_kernel<<<(N + 255) / 256, 256, 0, stream>>>(h2, ao32, s2s, s2d, N);
    edge_agg2_kernel<<<(N + 3) / 4, 256, 0, stream>>>(row_start, csr_dst, h2, s2s, s2d, d_out, flag, N);
}

// Round 5
// 778.847 us; speedup vs baseline: 3.5867x; 1.2749x over previous
//
#include <hip/hip_runtime.h>
#include <hip/hip_bf16.h>

#define F_IN    256
#define D_HID   64
#define H_HEADS 8
#define NC      10
#define ALPHA   0.2f
#define FLAG_THRESH 64
#define SCAN_T  1024

// ---------- bf16 helpers ----------
__device__ __forceinline__ float bfu2f(unsigned short u) {
    union { float f; unsigned int i; } c; c.i = ((unsigned int)u) << 16; return c.f;
}
__device__ __forceinline__ unsigned short f2bfu(float f) {
    union { float f; unsigned int i; } c; c.f = f;
    unsigned int x = c.i;
    x += 0x7fffu + ((x >> 16) & 1u);   // round-to-nearest-even
    return (unsigned short)(x >> 16);
}

// ---------- dtype detection (f32 vs bf16 storage) ----------
__global__ void detect_kernel(const unsigned int* __restrict__ x, int* __restrict__ flag) {
    int t = threadIdx.x;
    int cnt = 0;
    for (int i = t; i < 4096; i += 256) {
        unsigned int w = x[i];
        unsigned int e = (w >> 7) & 0xffu;
        if (e >= 140u) cnt++;
    }
    atomicAdd(flag, cnt);
}

// ---------- canonicalize any float tensor to f32 ----------
__global__ __launch_bounds__(256) void convert_kernel(
    const void* __restrict__ src, float* __restrict__ dst, long n,
    const int* __restrict__ flagp)
{
    long i = (long)blockIdx.x * 256 + threadIdx.x;
    if (i >= n) return;
    bool isf32 = (*flagp > FLAG_THRESH);
    dst[i] = isf32 ? ((const float*)src)[i]
                   : bfu2f(((const unsigned short*)src)[i]);
}

// ---------- CSR build ----------
__global__ __launch_bounds__(256) void hist_kernel(
    const int* __restrict__ src, int* __restrict__ counts, int E)
{
    int e = blockIdx.x * 256 + threadIdx.x;
    if (e < E) atomicAdd(&counts[src[e]], 1);
}

__global__ __launch_bounds__(SCAN_T) void scan_kernel(
    const int* __restrict__ counts, int* __restrict__ row_start, int N, int E)
{
    __shared__ int sums[SCAN_T];
    int t = threadIdx.x;
    int chunk = (N + SCAN_T - 1) / SCAN_T;
    int b = t * chunk, e = min(b + chunk, N);
    int s = 0;
    for (int i = b; i < e; ++i) s += counts[i];
    sums[t] = s;
    __syncthreads();
    for (int off = 1; off < SCAN_T; off <<= 1) {
        int u = (t >= off) ? sums[t - off] : 0;
        __syncthreads();
        sums[t] += u;
        __syncthreads();
    }
    int running = sums[t] - s;
    for (int i = b; i < e; ++i) { row_start[i] = running; running += counts[i]; }
    if (t == SCAN_T - 1) row_start[N] = E;
}

__global__ __launch_bounds__(256) void scatter_kernel(
    const int* __restrict__ src, const int* __restrict__ dst,
    const int* __restrict__ row_start, int* __restrict__ cursor,
    int* __restrict__ csr_dst, int E)
{
    int e = blockIdx.x * 256 + threadIdx.x;
    if (e >= E) return;
    int s = src[e];
    int pos = atomicAdd(&cursor[s], 1);
    csr_dst[row_start[s] + pos] = dst[e];
}

// ---------- layer-1 GEMM + fused attn1: h_bf[n, h*64+d] bf16, s1s/s1d[n*8+h] ----------
__global__ __launch_bounds__(256) void gemm1_kernel(
    const float* __restrict__ x,      // [N,256] f32
    const float* __restrict__ Wh,     // [8,256,64] f32
    const float* __restrict__ ah,     // [8,128] f32
    unsigned short* __restrict__ h_bf, // [N,512] bf16 out
    float* __restrict__ s1s, float* __restrict__ s1d, int N)
{
    __shared__ float Xs[64][33];
    __shared__ float Ws[32][64];
    const int nb = blockIdx.x, hh = blockIdx.y;
    const int t  = threadIdx.x;
    const int tx = t & 15, ty = t >> 4;
    const int n0 = nb * 64;
    const float* Wb = Wh + hh * (F_IN * D_HID);

    float acc[4][4] = {{0.f}};

    for (int k0 = 0; k0 < F_IN; k0 += 32) {
        float4 xv[2], wv[2];
        #pragma unroll
        for (int p = 0; p < 2; ++p) {
            int q = t + p * 256;
            int xr = q >> 3, xc = (q & 7) * 4;
            if (n0 + xr < N) xv[p] = *(const float4*)(x + (long)(n0 + xr) * F_IN + k0 + xc);
            else             xv[p] = make_float4(0.f, 0.f, 0.f, 0.f);
            int wr = q >> 4, wc = (q & 15) * 4;
            wv[p] = *(const float4*)(Wb + (long)(k0 + wr) * D_HID + wc);
        }

        __syncthreads();
        #pragma unroll
        for (int p = 0; p < 2; ++p) {
            int q = t + p * 256;
            int xr = q >> 3, xc = (q & 7) * 4;
            Xs[xr][xc + 0] = xv[p].x; Xs[xr][xc + 1] = xv[p].y;
            Xs[xr][xc + 2] = xv[p].z; Xs[xr][xc + 3] = xv[p].w;
            int wr = q >> 4, wc = (q & 15) * 4;
            *(float4*)&Ws[wr][wc] = wv[p];
        }
        __syncthreads();

        #pragma unroll 8
        for (int kk = 0; kk < 32; ++kk) {
            float xr4[4], wc4[4];
            #pragma unroll
            for (int i = 0; i < 4; ++i) xr4[i] = Xs[ty * 4 + i][kk];
            #pragma unroll
            for (int j = 0; j < 4; ++j) wc4[j] = Ws[kk][tx * 4 + j];
            #pragma unroll
            for (int i = 0; i < 4; ++i)
                #pragma unroll
                for (int j = 0; j < 4; ++j) acc[i][j] += xr4[i] * wc4[j];
        }
    }

    // epilogue: per-row attention halves + bf16 store
    const float* a1 = ah + hh * 128;
    float aj1[4], aj2[4];
    #pragma unroll
    for (int j = 0; j < 4; ++j) { aj1[j] = a1[tx * 4 + j]; aj2[j] = a1[64 + tx * 4 + j]; }

    #pragma unroll
    for (int i = 0; i < 4; ++i) {
        float p1 = acc[i][0]*aj1[0] + acc[i][1]*aj1[1] + acc[i][2]*aj1[2] + acc[i][3]*aj1[3];
        float p2 = acc[i][0]*aj2[0] + acc[i][1]*aj2[1] + acc[i][2]*aj2[2] + acc[i][3]*aj2[3];
        #pragma unroll
        for (int off = 1; off < 16; off <<= 1) {
            p1 += __shfl_xor(p1, off);
            p2 += __shfl_xor(p2, off);
        }
        int n = n0 + ty * 4 + i;
        if (n < N) {
            ushort4 o;
            o.x = f2bfu(acc[i][0]); o.y = f2bfu(acc[i][1]);
            o.z = f2bfu(acc[i][2]); o.w = f2bfu(acc[i][3]);
            *(ushort4*)(h_bf + (long)n * 512 + hh * 64 + tx * 4) = o;
            if (tx == 0) { s1s[n * 8 + hh] = p1; s1d[n * 8 + hh] = p2; }
        }
    }
}

// ---------- layer-1 CSR gather: block per node, wave per head-pair ----------
// Lane l loads packed uint (2 bf16); lanes 0..31 = head 2p, 32..63 = head 2p+1.
// NOTE: every lane accumulates the FULL rowsum itself (loop is not lane-split;
// ev depends only on (myh, d)) -> no cross-lane reduction of rs. (Round-4 bug:
// a 32-lane butterfly here summed 32 identical copies -> rowsum x32.)
__global__ __launch_bounds__(256) void edge_agg1_kernel(
    const int* __restrict__ row_start, const int* __restrict__ csr_dst,
    const unsigned int* __restrict__ h_u,   // [N,256] uint (=512 bf16)
    const float* __restrict__ s1s, const float* __restrict__ s1d,
    unsigned int* __restrict__ xcat_u,      // [N,256] uint (=512 bf16)
    int N)
{
    int lane = threadIdx.x & 63;
    int pair = threadIdx.x >> 6;           // 0..3
    int n = blockIdx.x;
    int beg = row_start[n], end = row_start[n + 1];
    int myh = pair * 2 + (lane >> 5);
    float ss = s1s[n * 8 + myh];
    int uoff = pair * 64 + lane;

    float acc0 = 0.f, acc1 = 0.f, rs = 0.f;
    int dnext = csr_dst[beg];              // end > beg guaranteed (self-loop)
    for (int i = beg; i < end; ++i) {
        int d = dnext;
        if (i + 1 < end) dnext = csr_dst[i + 1];
        float sd = s1d[d * 8 + myh];
        unsigned int w = h_u[(long)d * 256 + uoff];
        float sc = ss + sd;
        float lr = sc > 0.f ? sc : ALPHA * sc;
        float ev = __expf(-lr);
        rs += ev;
        acc0 += ev * bfu2f((unsigned short)(w & 0xffffu));
        acc1 += ev * bfu2f((unsigned short)(w >> 16));
    }
    float inv = 1.f / rs;
    float v0 = acc0 * inv; v0 = v0 > 0.f ? v0 : __expf(v0) - 1.f;
    float v1 = acc1 * inv; v1 = v1 > 0.f ? v1 : __expf(v1) - 1.f;
    xcat_u[(long)n * 256 + uoff] = (unsigned int)f2bfu(v0) | ((unsigned int)f2bfu(v1) << 16);
}

// ---------- layer-2 GEMM + fused attn2: thread per node, all 10 logits ----------
__global__ __launch_bounds__(256) void gemm2_kernel(
    const unsigned short* __restrict__ xcat_bf, // [N,512] bf16
    const float* __restrict__ Wo,               // [512,10] f32
    const float* __restrict__ ao,               // [20] f32
    float* __restrict__ h2, float* __restrict__ s2s, float* __restrict__ s2d, int N)
{
    int n = blockIdx.x * 256 + threadIdx.x;
    if (n >= N) return;
    float acc[NC];
    #pragma unroll
    for (int c = 0; c < NC; ++c) acc[c] = 0.f;
    const uint4* xp = (const uint4*)(xcat_bf + (long)n * 512);
    for (int k8 = 0; k8 < 64; ++k8) {
        uint4 w = xp[k8];
        float f[8];
        f[0] = bfu2f((unsigned short)(w.x & 0xffffu)); f[1] = bfu2f((unsigned short)(w.x >> 16));
        f[2] = bfu2f((unsigned short)(w.y & 0xffffu)); f[3] = bfu2f((unsigned short)(w.y >> 16));
        f[4] = bfu2f((unsigned short)(w.z & 0xffffu)); f[5] = bfu2f((unsigned short)(w.z >> 16));
        f[6] = bfu2f((unsigned short)(w.w & 0xffffu)); f[7] = bfu2f((unsigned short)(w.w >> 16));
        #pragma unroll
        for (int u = 0; u < 8; ++u) {
            const float* wr = Wo + (k8 * 8 + u) * NC;   // uniform -> scalar loads
            #pragma unroll
            for (int c = 0; c < NC; ++c) acc[c] += f[u] * wr[c];
        }
    }
    float s1 = 0.f, s2 = 0.f;
    #pragma unroll
    for (int c = 0; c < NC; ++c) {
        h2[(long)n * NC + c] = acc[c];
        s1 += acc[c] * ao[c];
        s2 += acc[c] * ao[NC + c];
    }
    s2s[n] = s1;
    s2d[n] = s2;
}

// ---------- layer-2 CSR gather + ELU + log_softmax -> out ----------
__global__ __launch_bounds__(256) void edge_agg2_kernel(
    const int* __restrict__ row_start, const int* __restrict__ csr_dst,
    const float* __restrict__ h2,
    const float* __restrict__ s_src2, const float* __restrict__ s_dst2,
    void* __restrict__ out, const int* __restrict__ flagp, int N)
{
    int lane = threadIdx.x & 63;
    int n = blockIdx.x * 4 + (threadIdx.x >> 6);
    if (n >= N) return;
    int beg = row_start[n], end = row_start[n + 1];
    float ss = s_src2[n];
    float rs = 0.f, acc[NC];
    #pragma unroll
    for (int c = 0; c < NC; ++c) acc[c] = 0.f;
    for (int i = beg + lane; i < end; i += 64) {
        int d = csr_dst[i];
        float sc = ss + s_dst2[d];
        float lr = sc > 0.f ? sc : ALPHA * sc;
        float ev = __expf(-lr);
        rs += ev;
        const float* hp = h2 + (long)d * NC;
        #pragma unroll
        for (int c = 0; c < NC; ++c) acc[c] += ev * hp[c];
    }
    #pragma unroll
    for (int off = 32; off >= 1; off >>= 1) {
        rs += __shfl_xor(rs, off, 64);
        #pragma unroll
        for (int c = 0; c < NC; ++c) acc[c] += __shfl_xor(acc[c], off, 64);
    }
    if (lane == 0) {
        float inv = 1.f / rs;
        float o[NC], m = -1e30f;
        #pragma unroll
        for (int c = 0; c < NC; ++c) {
            float v = acc[c] * inv;
            v = v > 0.f ? v : __expf(v) - 1.f;
            o[c] = v;
            m = fmaxf(m, v);
        }
        float sum = 0.f;
        #pragma unroll
        for (int c = 0; c < NC; ++c) sum += __expf(o[c] - m);
        float lse = m + logf(sum);
        bool isf32 = (*flagp > FLAG_THRESH);
        if (isf32) {
            float* op = (float*)out;
            #pragma unroll
            for (int c = 0; c < NC; ++c) op[n * NC + c] = o[c] - lse;
        } else {
            unsigned short* op = (unsigned short*)out;
            #pragma unroll
            for (int c = 0; c < NC; ++c) op[n * NC + c] = f2bfu(o[c] - lse);
        }
    }
}

extern "C" void kernel_launch(void* const* d_in, const int* in_sizes, int n_in,
                              void* d_out, int out_size, void* d_ws, size_t ws_size,
                              hipStream_t stream)
{
    const void* x_raw  = d_in[0];
    const int*  esrc   = (const int*)d_in[1];
    const int*  edst   = (const int*)d_in[2];
    const void* Wh_raw = d_in[3];
    const void* ah_raw = d_in[4];
    const void* Wo_raw = d_in[5];
    const void* ao_raw = d_in[6];

    const int N = in_sizes[0] / F_IN;
    const int E = in_sizes[1];

    char* ws = (char*)d_ws;
    size_t off = 0;
    auto alloc = [&](size_t bytes) -> void* {
        void* p = ws + off;
        off = (off + bytes + 255) & ~(size_t)255;
        return p;
    };
    int*            flag      = (int*)           alloc(4);
    float*          x32       = (float*)         alloc((size_t)N * F_IN * 4);
    float*          Wh32      = (float*)         alloc((size_t)H_HEADS * F_IN * D_HID * 4);
    float*          ah32      = (float*)         alloc((size_t)H_HEADS * 2 * D_HID * 4);
    float*          Wo32      = (float*)         alloc((size_t)512 * NC * 4);
    float*          ao32      = (float*)         alloc((size_t)2 * NC * 4);
    unsigned short* h_bf      = (unsigned short*)alloc((size_t)N * 512 * 2);   // 51.2 MB
    unsigned short* xcat_bf   = (unsigned short*)alloc((size_t)N * 512 * 2);   // 51.2 MB
    float*          s1s       = (float*)         alloc((size_t)N * 8 * 4);
    float*          s1d       = (float*)         alloc((size_t)N * 8 * 4);
    float*          h2        = (float*)         alloc((size_t)N * NC * 4);
    float*          s2s       = (float*)         alloc((size_t)N * 4);
    float*          s2d       = (float*)         alloc((size_t)N * 4);
    int*            counts    = (int*)           alloc((size_t)N * 4);
    int*            cursor    = (int*)           alloc((size_t)N * 4);
    int*            row_start = (int*)           alloc((size_t)(N + 1) * 4);
    int*            csr_dst   = (int*)           alloc((size_t)E * 4);
    (void)ws_size;

    hipMemsetAsync(flag, 0, 4, stream);
    hipMemsetAsync(counts, 0, (size_t)N * 4, stream);
    hipMemsetAsync(cursor, 0, (size_t)N * 4, stream);

    // dtype detect + canonicalize to f32
    detect_kernel<<<1, 256, 0, stream>>>((const unsigned int*)x_raw, flag);
    long nx = (long)N * F_IN;
    convert_kernel<<<(unsigned)((nx + 255) / 256), 256, 0, stream>>>(x_raw, x32, nx, flag);
    convert_kernel<<<(H_HEADS * F_IN * D_HID + 255) / 256, 256, 0, stream>>>(Wh_raw, Wh32, H_HEADS * F_IN * D_HID, flag);
    convert_kernel<<<(H_HEADS * 2 * D_HID + 255) / 256, 256, 0, stream>>>(ah_raw, ah32, H_HEADS * 2 * D_HID, flag);
    convert_kernel<<<(512 * NC + 255) / 256, 256, 0, stream>>>(Wo_raw, Wo32, 512 * NC, flag);
    convert_kernel<<<1, 256, 0, stream>>>(ao_raw, ao32, 2 * NC, flag);

    // CSR build (shared by both layers)
    hist_kernel<<<(E + 255) / 256, 256, 0, stream>>>(esrc, counts, E);
    scan_kernel<<<1, SCAN_T, 0, stream>>>(counts, row_start, N, E);
    scatter_kernel<<<(E + 255) / 256, 256, 0, stream>>>(esrc, edst, row_start, cursor, csr_dst, E);

    // layer 1
    dim3 g1((N + 63) / 64, H_HEADS);
    gemm1_kernel<<<g1, 256, 0, stream>>>(x32, Wh32, ah32, h_bf, s1s, s1d, N);
    edge_agg1_kernel<<<N, 256, 0, stream>>>(row_start, csr_dst, (const unsigned int*)h_bf,
                                            s1s, s1d, (unsigned int*)xcat_bf, N);

    // layer 2
    gemm2_kernel<<<(N + 255) / 256, 256, 0, stream>>>(xcat_bf, Wo32, ao32, h2, s2s, s2d, N);
    edge_agg2_kernel<<<(N + 3) / 4, 256, 0, stream>>>(row_start, csr_dst, h2, s2s, s2d, d_out, flag, N);
}

// Round 6
// 682.146 us; speedup vs baseline: 4.0951x; 1.1418x over previous
//
#include <hip/hip_runtime.h>
#include <hip/hip_bf16.h>

#define F_IN    256
#define D_HID   64
#define H_HEADS 8
#define NC      10
#define ALPHA   0.2f
#define FLAG_THRESH 64
#define SCAN_T  1024

typedef __attribute__((ext_vector_type(8))) short short8;
typedef __attribute__((ext_vector_type(4))) float f32x4;

// ---------- bf16 helpers ----------
__device__ __forceinline__ float bfu2f(unsigned short u) {
    union { float f; unsigned int i; } c; c.i = ((unsigned int)u) << 16; return c.f;
}
__device__ __forceinline__ unsigned short f2bfu(float f) {
    union { float f; unsigned int i; } c; c.f = f;
    unsigned int x = c.i;
    x += 0x7fffu + ((x >> 16) & 1u);   // round-to-nearest-even
    return (unsigned short)(x >> 16);
}

// ---------- dtype detection (f32 vs bf16 storage) ----------
__global__ void detect_kernel(const unsigned int* __restrict__ x, int* __restrict__ flag) {
    int t = threadIdx.x;
    int cnt = 0;
    for (int i = t; i < 4096; i += 256) {
        unsigned int w = x[i];
        unsigned int e = (w >> 7) & 0xffu;
        if (e >= 140u) cnt++;
    }
    atomicAdd(flag, cnt);
}

// ---------- canonicalize any float tensor to f32 ----------
__global__ __launch_bounds__(256) void convert_kernel(
    const void* __restrict__ src, float* __restrict__ dst, long n,
    const int* __restrict__ flagp)
{
    long i = (long)blockIdx.x * 256 + threadIdx.x;
    if (i >= n) return;
    bool isf32 = (*flagp > FLAG_THRESH);
    dst[i] = isf32 ? ((const float*)src)[i]
                   : bfu2f(((const unsigned short*)src)[i]);
}

// ---------- x -> bf16 (8 elems / thread) ----------
__global__ __launch_bounds__(256) void convert_x_kernel(
    const void* __restrict__ src, unsigned short* __restrict__ dst, long n8,
    const int* __restrict__ flagp)
{
    long i = (long)blockIdx.x * 256 + threadIdx.x;
    if (i >= n8) return;
    bool isf32 = (*flagp > FLAG_THRESH);
    unsigned short o[8];
    if (isf32) {
        const float* s = (const float*)src + i * 8;
        #pragma unroll
        for (int j = 0; j < 8; ++j) o[j] = f2bfu(s[j]);
    } else {
        *(uint4*)o = ((const uint4*)src)[i];
    }
    *(uint4*)(dst + i * 8) = *(uint4*)o;
}

// ---------- W_heads [8][256][64] -> transposed bf16 [8][64][256] ----------
__global__ __launch_bounds__(256) void convert_whT_kernel(
    const void* __restrict__ src, unsigned short* __restrict__ dst,
    const int* __restrict__ flagp)
{
    int i = blockIdx.x * 256 + threadIdx.x;
    if (i >= H_HEADS * F_IN * D_HID) return;
    int d = i & 63, k = (i >> 6) & 255, h = i >> 14;
    bool isf32 = (*flagp > FLAG_THRESH);
    float v = isf32 ? ((const float*)src)[i] : bfu2f(((const unsigned short*)src)[i]);
    dst[(h * 64 + d) * 256 + k] = f2bfu(v);
}

// ---------- CSR build ----------
__global__ __launch_bounds__(256) void hist_kernel(
    const int* __restrict__ src, int* __restrict__ counts, int E)
{
    int e = blockIdx.x * 256 + threadIdx.x;
    if (e < E) atomicAdd(&counts[src[e]], 1);
}

__global__ __launch_bounds__(SCAN_T) void scan_kernel(
    const int* __restrict__ counts, int* __restrict__ row_start, int N, int E)
{
    __shared__ int sums[SCAN_T];
    int t = threadIdx.x;
    int chunk = (N + SCAN_T - 1) / SCAN_T;
    int b = t * chunk, e = min(b + chunk, N);
    int s = 0;
    for (int i = b; i < e; ++i) s += counts[i];
    sums[t] = s;
    __syncthreads();
    for (int off = 1; off < SCAN_T; off <<= 1) {
        int u = (t >= off) ? sums[t - off] : 0;
        __syncthreads();
        sums[t] += u;
        __syncthreads();
    }
    int running = sums[t] - s;
    for (int i = b; i < e; ++i) { row_start[i] = running; running += counts[i]; }
    if (t == SCAN_T - 1) row_start[N] = E;
}

__global__ __launch_bounds__(256) void scatter_kernel(
    const int* __restrict__ src, const int* __restrict__ dst,
    const int* __restrict__ row_start, int* __restrict__ cursor,
    int* __restrict__ csr_dst, int E)
{
    int e = blockIdx.x * 256 + threadIdx.x;
    if (e >= E) return;
    int s = src[e];
    int pos = atomicAdd(&cursor[s], 1);
    csr_dst[row_start[s] + pos] = dst[e];
}

// ---------- layer-1 MFMA GEMM + fused attn1 ----------
// Block = 64 rows x ALL 8 heads. A (x rows, bf16) staged in LDS once, frags
// preloaded to registers and reused across heads. B read per head from L2-hot
// transposed weights. Output staged per-wave via LDS -> coalesced 16B stores.
// mfma_f32_16x16x32_bf16 layouts: A[m=lane&15][k=(lane>>4)*8+j];
// B[k=(lane>>4)*8+j][n=lane&15]; C/D col=lane&15, row=(lane>>4)*4+reg.
__global__ __launch_bounds__(256) void gemm1_kernel(
    const unsigned short* __restrict__ x_bf,   // [N,256] bf16
    const unsigned short* __restrict__ wh_t,   // [8][64][256] bf16 (d-major)
    const float* __restrict__ ah,              // [8,128] f32
    unsigned short* __restrict__ h_bf,         // [N,512] bf16 out
    float* __restrict__ s1s, float* __restrict__ s1d, int N)
{
    __shared__ unsigned short As[64][264];   // 64 rows x 256 k, +8 pad
    __shared__ unsigned short Os[64][72];    // per-wave output staging, 16B-aligned rows
    __shared__ float Ss[64][8];
    __shared__ float Sd[64][8];

    const int t = threadIdx.x;
    const int w = t >> 6, lane = t & 63;
    const int q = lane >> 4, m = lane & 15;
    const int n0 = blockIdx.x * 64;

    // stage A: 64x256 bf16 (2048 chunks of 8)
    for (int cc = t; cc < 2048; cc += 256) {
        int row = cc >> 5, c8 = cc & 31;
        uint4 v = make_uint4(0u, 0u, 0u, 0u);
        if (n0 + row < N) v = *(const uint4*)(x_bf + (long)(n0 + row) * 256 + c8 * 8);
        *(uint4*)&As[row][c8 * 8] = v;
    }
    __syncthreads();

    // preload 8 A-frags (row = 16w+m, k = ks*32 + q*8) — reused for all heads
    short8 afrag[8];
    #pragma unroll
    for (int ks = 0; ks < 8; ++ks)
        afrag[ks] = *(const short8*)&As[16 * w + m][ks * 32 + q * 8];

    for (int h = 0; h < 8; ++h) {
        f32x4 acc[4] = {};
        const unsigned short* Bh = wh_t + (long)h * 64 * 256;
        #pragma unroll
        for (int ks = 0; ks < 8; ++ks) {
            #pragma unroll
            for (int c = 0; c < 4; ++c) {
                short8 b = *(const short8*)(Bh + (c * 16 + m) * 256 + ks * 32 + q * 8);
                acc[c] = __builtin_amdgcn_mfma_f32_16x16x32_bf16(afrag[ks], b, acc[c], 0, 0, 0);
            }
        }

        // fused attn1: per-row dot with a1 halves, reduce over the 16 col-lanes
        const float* a1 = ah + h * 128;
        float a1m = a1[m], a1m16 = a1[16 + m], a1m32 = a1[32 + m], a1m48 = a1[48 + m];
        float a2m = a1[64 + m], a2m16 = a1[80 + m], a2m32 = a1[96 + m], a2m48 = a1[112 + m];
        #pragma unroll
        for (int reg = 0; reg < 4; ++reg) {
            float p1 = acc[0][reg] * a1m + acc[1][reg] * a1m16 + acc[2][reg] * a1m32 + acc[3][reg] * a1m48;
            float p2 = acc[0][reg] * a2m + acc[1][reg] * a2m16 + acc[2][reg] * a2m32 + acc[3][reg] * a2m48;
            #pragma unroll
            for (int off = 1; off < 16; off <<= 1) {
                p1 += __shfl_xor(p1, off);
                p2 += __shfl_xor(p2, off);
            }
            if (m == 0) {
                int row = 16 * w + q * 4 + reg;
                Ss[row][h] = p1;
                Sd[row][h] = p2;
            }
        }

        // stage 16x64 bf16 tile through wave-local LDS region -> coalesced stores
        #pragma unroll
        for (int c = 0; c < 4; ++c)
            #pragma unroll
            for (int reg = 0; reg < 4; ++reg)
                Os[16 * w + q * 4 + reg][c * 16 + m] = f2bfu(acc[c][reg]);
        #pragma unroll
        for (int j = 0; j < 2; ++j) {
            int cc = j * 64 + lane;
            int row = cc >> 3, c8 = cc & 7;     // row 0..15, c8 0..7
            if (n0 + 16 * w + row < N)
                *(uint4*)(h_bf + (long)(n0 + 16 * w + row) * 512 + h * 64 + c8 * 8) =
                    *(const uint4*)&Os[16 * w + row][c8 * 8];
        }
    }

    __syncthreads();
    // coalesced score writes
    for (int i = t; i < 512; i += 256) {
        int row = i >> 3, hh = i & 7;
        if (n0 + row < N) {
            s1s[(n0 + row) * 8 + hh] = Ss[row][hh];
            s1d[(n0 + row) * 8 + hh] = Sd[row][hh];
        }
    }
}

// ---------- layer-1 CSR gather: block per node, wave per head-pair ----------
// Every lane accumulates the FULL rowsum itself (loop not lane-split) -> no
// cross-lane reduction of rs.
__global__ __launch_bounds__(256) void edge_agg1_kernel(
    const int* __restrict__ row_start, const int* __restrict__ csr_dst,
    const unsigned int* __restrict__ h_u,   // [N,256] uint (=512 bf16)
    const float* __restrict__ s1s, const float* __restrict__ s1d,
    unsigned int* __restrict__ xcat_u,      // [N,256] uint (=512 bf16)
    int N)
{
    int lane = threadIdx.x & 63;
    int pair = threadIdx.x >> 6;           // 0..3
    int n = blockIdx.x;
    int beg = row_start[n], end = row_start[n + 1];
    int myh = pair * 2 + (lane >> 5);
    float ss = s1s[n * 8 + myh];
    int uoff = pair * 64 + lane;

    float acc0 = 0.f, acc1 = 0.f, rs = 0.f;
    int dnext = csr_dst[beg];              // end > beg guaranteed (self-loop)
    for (int i = beg; i < end; ++i) {
        int d = dnext;
        if (i + 1 < end) dnext = csr_dst[i + 1];
        float sd = s1d[d * 8 + myh];
        unsigned int w = h_u[(long)d * 256 + uoff];
        float sc = ss + sd;
        float lr = sc > 0.f ? sc : ALPHA * sc;
        float ev = __expf(-lr);
        rs += ev;
        acc0 += ev * bfu2f((unsigned short)(w & 0xffffu));
        acc1 += ev * bfu2f((unsigned short)(w >> 16));
    }
    float inv = 1.f / rs;
    float v0 = acc0 * inv; v0 = v0 > 0.f ? v0 : __expf(v0) - 1.f;
    float v1 = acc1 * inv; v1 = v1 > 0.f ? v1 : __expf(v1) - 1.f;
    xcat_u[(long)n * 256 + uoff] = (unsigned int)f2bfu(v0) | ((unsigned int)f2bfu(v1) << 16);
}

// ---------- layer-2 GEMM + fused attn2: thread per node, all 10 logits ----------
__global__ __launch_bounds__(256) void gemm2_kernel(
    const unsigned short* __restrict__ xcat_bf, // [N,512] bf16
    const float* __restrict__ Wo,               // [512,10] f32
    const float* __restrict__ ao,               // [20] f32
    float* __restrict__ h2, float* __restrict__ s2s, float* __restrict__ s2d, int N)
{
    int n = blockIdx.x * 256 + threadIdx.x;
    if (n >= N) return;
    float acc[NC];
    #pragma unroll
    for (int c = 0; c < NC; ++c) acc[c] = 0.f;
    const uint4* xp = (const uint4*)(xcat_bf + (long)n * 512);
    for (int k8 = 0; k8 < 64; ++k8) {
        uint4 w = xp[k8];
        float f[8];
        f[0] = bfu2f((unsigned short)(w.x & 0xffffu)); f[1] = bfu2f((unsigned short)(w.x >> 16));
        f[2] = bfu2f((unsigned short)(w.y & 0xffffu)); f[3] = bfu2f((unsigned short)(w.y >> 16));
        f[4] = bfu2f((unsigned short)(w.z & 0xffffu)); f[5] = bfu2f((unsigned short)(w.z >> 16));
        f[6] = bfu2f((unsigned short)(w.w & 0xffffu)); f[7] = bfu2f((unsigned short)(w.w >> 16));
        #pragma unroll
        for (int u = 0; u < 8; ++u) {
            const float* wr = Wo + (k8 * 8 + u) * NC;   // uniform -> scalar loads
            #pragma unroll
            for (int c = 0; c < NC; ++c) acc[c] += f[u] * wr[c];
        }
    }
    float s1 = 0.f, s2 = 0.f;
    #pragma unroll
    for (int c = 0; c < NC; ++c) {
        h2[(long)n * NC + c] = acc[c];
        s1 += acc[c] * ao[c];
        s2 += acc[c] * ao[NC + c];
    }
    s2s[n] = s1;
    s2d[n] = s2;
}

// ---------- layer-2 CSR gather + ELU + log_softmax -> out ----------
__global__ __launch_bounds__(256) void edge_agg2_kernel(
    const int* __restrict__ row_start, const int* __restrict__ csr_dst,
    const float* __restrict__ h2,
    const float* __restrict__ s_src2, const float* __restrict__ s_dst2,
    void* __restrict__ out, const int* __restrict__ flagp, int N)
{
    int lane = threadIdx.x & 63;
    int n = blockIdx.x * 4 + (threadIdx.x >> 6);
    if (n >= N) return;
    int beg = row_start[n], end = row_start[n + 1];
    float ss = s_src2[n];
    float rs = 0.f, acc[NC];
    #pragma unroll
    for (int c = 0; c < NC; ++c) acc[c] = 0.f;
    for (int i = beg + lane; i < end; i += 64) {
        int d = csr_dst[i];
        float sc = ss + s_dst2[d];
        float lr = sc > 0.f ? sc : ALPHA * sc;
        float ev = __expf(-lr);
        rs += ev;
        const float* hp = h2 + (long)d * NC;
        #pragma unroll
        for (int c = 0; c < NC; ++c) acc[c] += ev * hp[c];
    }
    #pragma unroll
    for (int off = 32; off >= 1; off >>= 1) {
        rs += __shfl_xor(rs, off, 64);
        #pragma unroll
        for (int c = 0; c < NC; ++c) acc[c] += __shfl_xor(acc[c], off, 64);
    }
    if (lane == 0) {
        float inv = 1.f / rs;
        float o[NC], m = -1e30f;
        #pragma unroll
        for (int c = 0; c < NC; ++c) {
            float v = acc[c] * inv;
            v = v > 0.f ? v : __expf(v) - 1.f;
            o[c] = v;
            m = fmaxf(m, v);
        }
        float sum = 0.f;
        #pragma unroll
        for (int c = 0; c < NC; ++c) sum += __expf(o[c] - m);
        float lse = m + logf(sum);
        bool isf32 = (*flagp > FLAG_THRESH);
        if (isf32) {
            float* op = (float*)out;
            #pragma unroll
            for (int c = 0; c < NC; ++c) op[n * NC + c] = o[c] - lse;
        } else {
            unsigned short* op = (unsigned short*)out;
            #pragma unroll
            for (int c = 0; c < NC; ++c) op[n * NC + c] = f2bfu(o[c] - lse);
        }
    }
}

extern "C" void kernel_launch(void* const* d_in, const int* in_sizes, int n_in,
                              void* d_out, int out_size, void* d_ws, size_t ws_size,
                              hipStream_t stream)
{
    const void* x_raw  = d_in[0];
    const int*  esrc   = (const int*)d_in[1];
    const int*  edst   = (const int*)d_in[2];
    const void* Wh_raw = d_in[3];
    const void* ah_raw = d_in[4];
    const void* Wo_raw = d_in[5];
    const void* ao_raw = d_in[6];

    const int N = in_sizes[0] / F_IN;
    const int E = in_sizes[1];

    char* ws = (char*)d_ws;
    size_t off = 0;
    auto alloc = [&](size_t bytes) -> void* {
        void* p = ws + off;
        off = (off + bytes + 255) & ~(size_t)255;
        return p;
    };
    int*            flag      = (int*)           alloc(4);
    unsigned short* x_bf      = (unsigned short*)alloc((size_t)N * F_IN * 2);      // 25.6 MB
    unsigned short* wh_t      = (unsigned short*)alloc((size_t)H_HEADS * D_HID * F_IN * 2);
    float*          ah32      = (float*)         alloc((size_t)H_HEADS * 2 * D_HID * 4);
    float*          Wo32      = (float*)         alloc((size_t)512 * NC * 4);
    float*          ao32      = (float*)         alloc((size_t)2 * NC * 4);
    unsigned short* h_bf      = (unsigned short*)alloc((size_t)N * 512 * 2);       // 51.2 MB
    unsigned short* xcat_bf   = (unsigned short*)alloc((size_t)N * 512 * 2);       // 51.2 MB
    float*          s1s       = (float*)         alloc((size_t)N * 8 * 4);
    float*          s1d       = (float*)         alloc((size_t)N * 8 * 4);
    float*          h2        = (float*)         alloc((size_t)N * NC * 4);
    float*          s2s       = (float*)         alloc((size_t)N * 4);
    float*          s2d       = (float*)         alloc((size_t)N * 4);
    int*            counts    = (int*)           alloc((size_t)N * 4);
    int*            cursor    = (int*)           alloc((size_t)N * 4);
    int*            row_start = (int*)           alloc((size_t)(N + 1) * 4);
    int*            csr_dst   = (int*)           alloc((size_t)E * 4);
    (void)ws_size;

    hipMemsetAsync(flag, 0, 4, stream);
    hipMemsetAsync(counts, 0, (size_t)N * 4, stream);
    hipMemsetAsync(cursor, 0, (size_t)N * 4, stream);

    // dtype detect + canonicalize
    detect_kernel<<<1, 256, 0, stream>>>((const unsigned int*)x_raw, flag);
    long n8 = (long)N * F_IN / 8;
    convert_x_kernel<<<(unsigned)((n8 + 255) / 256), 256, 0, stream>>>(x_raw, x_bf, n8, flag);
    convert_whT_kernel<<<(H_HEADS * F_IN * D_HID + 255) / 256, 256, 0, stream>>>(Wh_raw, wh_t, flag);
    convert_kernel<<<(H_HEADS * 2 * D_HID + 255) / 256, 256, 0, stream>>>(ah_raw, ah32, H_HEADS * 2 * D_HID, flag);
    convert_kernel<<<(512 * NC + 255) / 256, 256, 0, stream>>>(Wo_raw, Wo32, 512 * NC, flag);
    convert_kernel<<<1, 256, 0, stream>>>(ao_raw, ao32, 2 * NC, flag);

    // CSR build (shared by both layers)
    hist_kernel<<<(E + 255) / 256, 256, 0, stream>>>(esrc, counts, E);
    scan_kernel<<<1, SCAN_T, 0, stream>>>(counts, row_start, N, E);
    scatter_kernel<<<(E + 255) / 256, 256, 0, stream>>>(esrc, edst, row_start, cursor, csr_dst, E);

    // layer 1
    gemm1_kernel<<<(N + 63) / 64, 256, 0, stream>>>(x_bf, wh_t, ah32, h_bf, s1s, s1d, N);
    edge_agg1_kernel<<<N, 256, 0, stream>>>(row_start, csr_dst, (const unsigned int*)h_bf,
                                            s1s, s1d, (unsigned int*)xcat_bf, N);

    // layer 2
    gemm2_kernel<<<(N + 255) / 256, 256, 0, stream>>>(xcat_bf, Wo32, ao32, h2, s2s, s2d, N);
    edge_agg2_kernel<<<(N + 3) / 4, 256, 0, stream>>>(row_start, csr_dst, h2, s2s, s2d, d_out, flag, N);
}

// Round 7
// 618.556 us; speedup vs baseline: 4.5161x; 1.1028x over previous
//
#include <hip/hip_runtime.h>
#include <hip/hip_bf16.h>

#define F_IN    256
#define D_HID   64
#define H_HEADS 8
#define NC      10
#define ALPHA   0.2f
#define FLAG_THRESH 64
#define SCAN_T  1024

typedef __attribute__((ext_vector_type(8))) short short8;
typedef __attribute__((ext_vector_type(4))) float f32x4;

// ---------- bf16 helpers ----------
__device__ __forceinline__ float bfu2f(unsigned short u) {
    union { float f; unsigned int i; } c; c.i = ((unsigned int)u) << 16; return c.f;
}
__device__ __forceinline__ unsigned short f2bfu(float f) {
    union { float f; unsigned int i; } c; c.f = f;
    unsigned int x = c.i;
    x += 0x7fffu + ((x >> 16) & 1u);   // round-to-nearest-even
    return (unsigned short)(x >> 16);
}

// ---------- dtype detection (f32 vs bf16 storage) ----------
__global__ void detect_kernel(const unsigned int* __restrict__ x, int* __restrict__ flag) {
    int t = threadIdx.x;
    int cnt = 0;
    for (int i = t; i < 4096; i += 256) {
        unsigned int w = x[i];
        unsigned int e = (w >> 7) & 0xffu;
        if (e >= 140u) cnt++;
    }
    atomicAdd(flag, cnt);
}

// ---------- canonicalize any float tensor to f32 ----------
__global__ __launch_bounds__(256) void convert_kernel(
    const void* __restrict__ src, float* __restrict__ dst, long n,
    const int* __restrict__ flagp)
{
    long i = (long)blockIdx.x * 256 + threadIdx.x;
    if (i >= n) return;
    bool isf32 = (*flagp > FLAG_THRESH);
    dst[i] = isf32 ? ((const float*)src)[i]
                   : bfu2f(((const unsigned short*)src)[i]);
}

// ---------- x -> bf16 (8 elems / thread) ----------
__global__ __launch_bounds__(256) void convert_x_kernel(
    const void* __restrict__ src, unsigned short* __restrict__ dst, long n8,
    const int* __restrict__ flagp)
{
    long i = (long)blockIdx.x * 256 + threadIdx.x;
    if (i >= n8) return;
    bool isf32 = (*flagp > FLAG_THRESH);
    unsigned short o[8];
    if (isf32) {
        const float* s = (const float*)src + i * 8;
        #pragma unroll
        for (int j = 0; j < 8; ++j) o[j] = f2bfu(s[j]);
    } else {
        *(uint4*)o = ((const uint4*)src)[i];
    }
    *(uint4*)(dst + i * 8) = *(uint4*)o;
}

// ---------- W_heads [8][256][64] -> transposed bf16 [8][64][256] ----------
__global__ __launch_bounds__(256) void convert_whT_kernel(
    const void* __restrict__ src, unsigned short* __restrict__ dst,
    const int* __restrict__ flagp)
{
    int i = blockIdx.x * 256 + threadIdx.x;
    if (i >= H_HEADS * F_IN * D_HID) return;
    int d = i & 63, k = (i >> 6) & 255, h = i >> 14;
    bool isf32 = (*flagp > FLAG_THRESH);
    float v = isf32 ? ((const float*)src)[i] : bfu2f(((const unsigned short*)src)[i]);
    dst[(h * 64 + d) * 256 + k] = f2bfu(v);
}

// ---------- CSR build ----------
__global__ __launch_bounds__(256) void hist_kernel(
    const int* __restrict__ src, int* __restrict__ counts, int E)
{
    int e = blockIdx.x * 256 + threadIdx.x;
    if (e < E) atomicAdd(&counts[src[e]], 1);
}

__global__ __launch_bounds__(SCAN_T) void scan_kernel(
    const int* __restrict__ counts, int* __restrict__ row_start, int N, int E)
{
    __shared__ int sums[SCAN_T];
    int t = threadIdx.x;
    int chunk = (N + SCAN_T - 1) / SCAN_T;
    int b = t * chunk, e = min(b + chunk, N);
    int s = 0;
    for (int i = b; i < e; ++i) s += counts[i];
    sums[t] = s;
    __syncthreads();
    for (int off = 1; off < SCAN_T; off <<= 1) {
        int u = (t >= off) ? sums[t - off] : 0;
        __syncthreads();
        sums[t] += u;
        __syncthreads();
    }
    int running = sums[t] - s;
    for (int i = b; i < e; ++i) { row_start[i] = running; running += counts[i]; }
    if (t == SCAN_T - 1) row_start[N] = E;
}

// ---------- CSR scatter + fused layer-1 edge coefficients ----------
// Runs AFTER gemm1 (needs s1s/s1d). Per edge: write csr_dst and the 8 head
// attention coefficients exp(-leaky_relu(score)) in CSR order.
__global__ __launch_bounds__(256) void scatter_ev_kernel(
    const int* __restrict__ src, const int* __restrict__ dst,
    const int* __restrict__ row_start, int* __restrict__ cursor,
    const float* __restrict__ s1s, const float* __restrict__ s1d,
    int* __restrict__ csr_dst, float* __restrict__ ev_csr, int E)
{
    int e = blockIdx.x * 256 + threadIdx.x;
    if (e >= E) return;
    int s = src[e], d = dst[e];
    int pos = atomicAdd(&cursor[s], 1);
    int i = row_start[s] + pos;
    csr_dst[i] = d;
    float4 ss0 = *(const float4*)(s1s + s * 8);
    float4 ss1 = *(const float4*)(s1s + s * 8 + 4);
    float4 sd0 = *(const float4*)(s1d + d * 8);
    float4 sd1 = *(const float4*)(s1d + d * 8 + 4);
    float sc[8] = { ss0.x + sd0.x, ss0.y + sd0.y, ss0.z + sd0.z, ss0.w + sd0.w,
                    ss1.x + sd1.x, ss1.y + sd1.y, ss1.z + sd1.z, ss1.w + sd1.w };
    float ev[8];
    #pragma unroll
    for (int h = 0; h < 8; ++h) {
        float lr = sc[h] > 0.f ? sc[h] : ALPHA * sc[h];
        ev[h] = __expf(-lr);
    }
    *(float4*)(ev_csr + (long)i * 8)     = make_float4(ev[0], ev[1], ev[2], ev[3]);
    *(float4*)(ev_csr + (long)i * 8 + 4) = make_float4(ev[4], ev[5], ev[6], ev[7]);
}

// ---------- layer-1 MFMA GEMM + fused attn1 ----------
__global__ __launch_bounds__(256) void gemm1_kernel(
    const unsigned short* __restrict__ x_bf,   // [N,256] bf16
    const unsigned short* __restrict__ wh_t,   // [8][64][256] bf16 (d-major)
    const float* __restrict__ ah,              // [8,128] f32
    unsigned short* __restrict__ h_bf,         // [N,512] bf16 out
    float* __restrict__ s1s, float* __restrict__ s1d, int N)
{
    __shared__ unsigned short As[64][264];
    __shared__ unsigned short Os[64][72];
    __shared__ float Ss[64][8];
    __shared__ float Sd[64][8];

    const int t = threadIdx.x;
    const int w = t >> 6, lane = t & 63;
    const int q = lane >> 4, m = lane & 15;
    const int n0 = blockIdx.x * 64;

    for (int cc = t; cc < 2048; cc += 256) {
        int row = cc >> 5, c8 = cc & 31;
        uint4 v = make_uint4(0u, 0u, 0u, 0u);
        if (n0 + row < N) v = *(const uint4*)(x_bf + (long)(n0 + row) * 256 + c8 * 8);
        *(uint4*)&As[row][c8 * 8] = v;
    }
    __syncthreads();

    short8 afrag[8];
    #pragma unroll
    for (int ks = 0; ks < 8; ++ks)
        afrag[ks] = *(const short8*)&As[16 * w + m][ks * 32 + q * 8];

    for (int h = 0; h < 8; ++h) {
        f32x4 acc[4] = {};
        const unsigned short* Bh = wh_t + (long)h * 64 * 256;
        #pragma unroll
        for (int ks = 0; ks < 8; ++ks) {
            #pragma unroll
            for (int c = 0; c < 4; ++c) {
                short8 b = *(const short8*)(Bh + (c * 16 + m) * 256 + ks * 32 + q * 8);
                acc[c] = __builtin_amdgcn_mfma_f32_16x16x32_bf16(afrag[ks], b, acc[c], 0, 0, 0);
            }
        }

        const float* a1 = ah + h * 128;
        float a1m = a1[m], a1m16 = a1[16 + m], a1m32 = a1[32 + m], a1m48 = a1[48 + m];
        float a2m = a1[64 + m], a2m16 = a1[80 + m], a2m32 = a1[96 + m], a2m48 = a1[112 + m];
        #pragma unroll
        for (int reg = 0; reg < 4; ++reg) {
            float p1 = acc[0][reg] * a1m + acc[1][reg] * a1m16 + acc[2][reg] * a1m32 + acc[3][reg] * a1m48;
            float p2 = acc[0][reg] * a2m + acc[1][reg] * a2m16 + acc[2][reg] * a2m32 + acc[3][reg] * a2m48;
            #pragma unroll
            for (int off = 1; off < 16; off <<= 1) {
                p1 += __shfl_xor(p1, off);
                p2 += __shfl_xor(p2, off);
            }
            if (m == 0) {
                int row = 16 * w + q * 4 + reg;
                Ss[row][h] = p1;
                Sd[row][h] = p2;
            }
        }

        #pragma unroll
        for (int c = 0; c < 4; ++c)
            #pragma unroll
            for (int reg = 0; reg < 4; ++reg)
                Os[16 * w + q * 4 + reg][c * 16 + m] = f2bfu(acc[c][reg]);
        #pragma unroll
        for (int j = 0; j < 2; ++j) {
            int cc = j * 64 + lane;
            int row = cc >> 3, c8 = cc & 7;
            if (n0 + 16 * w + row < N)
                *(uint4*)(h_bf + (long)(n0 + 16 * w + row) * 512 + h * 64 + c8 * 8) =
                    *(const uint4*)&Os[16 * w + row][c8 * 8];
        }
    }

    __syncthreads();
    for (int i = t; i < 512; i += 256) {
        int row = i >> 3, hh = i & 7;
        if (n0 + row < N) {
            s1s[(n0 + row) * 8 + hh] = Ss[row][hh];
            s1d[(n0 + row) * 8 + hh] = Sd[row][hh];
        }
    }
}

// ---------- layer-1 CSR gather v3: ONE WAVE per node, all 8 heads ----------
// Lane l holds uint4 = 8 bf16 of the row (head = l>>3); ev precomputed in CSR
// order (32B broadcast per iter). Every lane accumulates the full rowsum of
// its own head (loop not lane-split) -> no cross-lane reduction.
__global__ __launch_bounds__(256) void edge_agg1_kernel(
    const int* __restrict__ row_start, const int* __restrict__ csr_dst,
    const float* __restrict__ ev_csr,      // [E*8]
    const uint4* __restrict__ h_q,         // [N*64] uint4 (= [N,512] bf16)
    uint4* __restrict__ xcat_q,            // [N*64]
    int N)
{
    int lane = threadIdx.x & 63;
    int n = blockIdx.x * 4 + (threadIdx.x >> 6);
    if (n >= N) return;
    int h = lane >> 3;
    int beg = row_start[n], end = row_start[n + 1];

    float acc[8] = {0.f, 0.f, 0.f, 0.f, 0.f, 0.f, 0.f, 0.f};
    float rs = 0.f;
    int dnext = csr_dst[beg];              // end > beg guaranteed (self-loop)
    for (int i = beg; i < end; ++i) {
        int d = dnext;
        if (i + 1 < end) dnext = csr_dst[i + 1];
        float ev = ev_csr[(long)i * 8 + h];
        uint4 wv = h_q[(long)d * 64 + lane];
        rs += ev;
        acc[0] += ev * bfu2f((unsigned short)(wv.x & 0xffffu));
        acc[1] += ev * bfu2f((unsigned short)(wv.x >> 16));
        acc[2] += ev * bfu2f((unsigned short)(wv.y & 0xffffu));
        acc[3] += ev * bfu2f((unsigned short)(wv.y >> 16));
        acc[4] += ev * bfu2f((unsigned short)(wv.z & 0xffffu));
        acc[5] += ev * bfu2f((unsigned short)(wv.z >> 16));
        acc[6] += ev * bfu2f((unsigned short)(wv.w & 0xffffu));
        acc[7] += ev * bfu2f((unsigned short)(wv.w >> 16));
    }
    float inv = 1.f / rs;
    unsigned short o[8];
    #pragma unroll
    for (int j = 0; j < 8; ++j) {
        float v = acc[j] * inv;
        v = v > 0.f ? v : __expf(v) - 1.f;   // elu
        o[j] = f2bfu(v);
    }
    xcat_q[(long)n * 64 + lane] = *(const uint4*)o;
}

// ---------- layer-2 GEMM + fused attn2: thread per node; h2 padded [N,16] ----------
__global__ __launch_bounds__(256) void gemm2_kernel(
    const unsigned short* __restrict__ xcat_bf, // [N,512] bf16
    const float* __restrict__ Wo,               // [512,10] f32
    const float* __restrict__ ao,               // [20] f32
    float* __restrict__ h2p,                    // [N,16] f32, pad=0
    float* __restrict__ s2s, float* __restrict__ s2d, int N)
{
    int n = blockIdx.x * 256 + threadIdx.x;
    if (n >= N) return;
    float acc[NC];
    #pragma unroll
    for (int c = 0; c < NC; ++c) acc[c] = 0.f;
    const uint4* xp = (const uint4*)(xcat_bf + (long)n * 512);
    for (int k8 = 0; k8 < 64; ++k8) {
        uint4 w = xp[k8];
        float f[8];
        f[0] = bfu2f((unsigned short)(w.x & 0xffffu)); f[1] = bfu2f((unsigned short)(w.x >> 16));
        f[2] = bfu2f((unsigned short)(w.y & 0xffffu)); f[3] = bfu2f((unsigned short)(w.y >> 16));
        f[4] = bfu2f((unsigned short)(w.z & 0xffffu)); f[5] = bfu2f((unsigned short)(w.z >> 16));
        f[6] = bfu2f((unsigned short)(w.w & 0xffffu)); f[7] = bfu2f((unsigned short)(w.w >> 16));
        #pragma unroll
        for (int u = 0; u < 8; ++u) {
            const float* wr = Wo + (k8 * 8 + u) * NC;
            #pragma unroll
            for (int c = 0; c < NC; ++c) acc[c] += f[u] * wr[c];
        }
    }
    float s1 = 0.f, s2 = 0.f;
    float4 o0 = make_float4(acc[0], acc[1], acc[2], acc[3]);
    float4 o1 = make_float4(acc[4], acc[5], acc[6], acc[7]);
    float4 o2 = make_float4(acc[8], acc[9], 0.f, 0.f);
    *(float4*)(h2p + (long)n * 16)      = o0;
    *(float4*)(h2p + (long)n * 16 + 4)  = o1;
    *(float4*)(h2p + (long)n * 16 + 8)  = o2;
    *(float4*)(h2p + (long)n * 16 + 12) = make_float4(0.f, 0.f, 0.f, 0.f);
    #pragma unroll
    for (int c = 0; c < NC; ++c) {
        s1 += acc[c] * ao[c];
        s2 += acc[c] * ao[NC + c];
    }
    s2s[n] = s1;
    s2d[n] = s2;
}

// ---------- layer-2 CSR gather v2: wave per node, lane=(edge-slot j, class c) ----------
__global__ __launch_bounds__(256) void edge_agg2_kernel(
    const int* __restrict__ row_start, const int* __restrict__ csr_dst,
    const float* __restrict__ h2p,             // [N,16] f32, pad=0
    const float* __restrict__ s_src2, const float* __restrict__ s_dst2,
    void* __restrict__ out, const int* __restrict__ flagp, int N)
{
    int lane = threadIdx.x & 63;
    int n = blockIdx.x * 4 + (threadIdx.x >> 6);
    if (n >= N) return;
    int c = lane & 15, j = lane >> 4;   // 4 edge slots x 16 classes(padded)
    int beg = row_start[n], end = row_start[n + 1];
    float ss = s_src2[n];
    float rs = 0.f, acc = 0.f;
    for (int i0 = beg; i0 < end; i0 += 4) {
        int i = i0 + j;
        if (i < end) {
            int d = csr_dst[i];
            float sc = ss + s_dst2[d];
            float lr = sc > 0.f ? sc : ALPHA * sc;
            float ev = __expf(-lr);
            rs += ev;
            acc += ev * h2p[(long)d * 16 + c];
        }
    }
    // reduce over edge slots j (lanes ^16, ^32); c stays fixed per lane
    rs  += __shfl_xor(rs, 16, 64);  rs  += __shfl_xor(rs, 32, 64);
    acc += __shfl_xor(acc, 16, 64); acc += __shfl_xor(acc, 32, 64);
    float v = acc / rs;
    v = v > 0.f ? v : __expf(v) - 1.f;           // elu (pad lanes give elu(0)=0, masked below)
    float vm = (c < NC) ? v : -1e30f;
    #pragma unroll
    for (int off = 1; off < 16; off <<= 1) vm = fmaxf(vm, __shfl_xor(vm, off, 64));
    float ex = (c < NC) ? __expf(v - vm) : 0.f;
    #pragma unroll
    for (int off = 1; off < 16; off <<= 1) ex += __shfl_xor(ex, off, 64);
    float lse = vm + logf(ex);
    if (c < NC && j == 0) {
        bool isf32 = (*flagp > FLAG_THRESH);
        if (isf32) ((float*)out)[(long)n * NC + c] = v - lse;
        else       ((unsigned short*)out)[(long)n * NC + c] = f2bfu(v - lse);
    }
}

extern "C" void kernel_launch(void* const* d_in, const int* in_sizes, int n_in,
                              void* d_out, int out_size, void* d_ws, size_t ws_size,
                              hipStream_t stream)
{
    const void* x_raw  = d_in[0];
    const int*  esrc   = (const int*)d_in[1];
    const int*  edst   = (const int*)d_in[2];
    const void* Wh_raw = d_in[3];
    const void* ah_raw = d_in[4];
    const void* Wo_raw = d_in[5];
    const void* ao_raw = d_in[6];

    const int N = in_sizes[0] / F_IN;
    const int E = in_sizes[1];

    char* ws = (char*)d_ws;
    size_t off = 0;
    auto alloc = [&](size_t bytes) -> void* {
        void* p = ws + off;
        off = (off + bytes + 255) & ~(size_t)255;
        return p;
    };
    int*            flag      = (int*)           alloc(4);
    unsigned short* x_bf      = (unsigned short*)alloc((size_t)N * F_IN * 2);
    unsigned short* wh_t      = (unsigned short*)alloc((size_t)H_HEADS * D_HID * F_IN * 2);
    float*          ah32      = (float*)         alloc((size_t)H_HEADS * 2 * D_HID * 4);
    float*          Wo32      = (float*)         alloc((size_t)512 * NC * 4);
    float*          ao32      = (float*)         alloc((size_t)2 * NC * 4);
    unsigned short* h_bf      = (unsigned short*)alloc((size_t)N * 512 * 2);
    unsigned short* xcat_bf   = (unsigned short*)alloc((size_t)N * 512 * 2);
    float*          s1s       = (float*)         alloc((size_t)N * 8 * 4);
    float*          s1d       = (float*)         alloc((size_t)N * 8 * 4);
    float*          h2p       = (float*)         alloc((size_t)N * 16 * 4);
    float*          s2s       = (float*)         alloc((size_t)N * 4);
    float*          s2d       = (float*)         alloc((size_t)N * 4);
    int*            counts    = (int*)           alloc((size_t)N * 4);
    int*            cursor    = (int*)           alloc((size_t)N * 4);
    int*            row_start = (int*)           alloc((size_t)(N + 1) * 4);
    int*            csr_dst   = (int*)           alloc((size_t)E * 4);
    float*          ev_csr    = (float*)         alloc((size_t)E * 8 * 4);   // 27.2 MB
    (void)ws_size;

    hipMemsetAsync(flag, 0, 4, stream);
    hipMemsetAsync(counts, 0, (size_t)N * 4, stream);
    hipMemsetAsync(cursor, 0, (size_t)N * 4, stream);

    // dtype detect + canonicalize
    detect_kernel<<<1, 256, 0, stream>>>((const unsigned int*)x_raw, flag);
    long n8 = (long)N * F_IN / 8;
    convert_x_kernel<<<(unsigned)((n8 + 255) / 256), 256, 0, stream>>>(x_raw, x_bf, n8, flag);
    convert_whT_kernel<<<(H_HEADS * F_IN * D_HID + 255) / 256, 256, 0, stream>>>(Wh_raw, wh_t, flag);
    convert_kernel<<<(H_HEADS * 2 * D_HID + 255) / 256, 256, 0, stream>>>(ah_raw, ah32, H_HEADS * 2 * D_HID, flag);
    convert_kernel<<<(512 * NC + 255) / 256, 256, 0, stream>>>(Wo_raw, Wo32, 512 * NC, flag);
    convert_kernel<<<1, 256, 0, stream>>>(ao_raw, ao32, 2 * NC, flag);

    // CSR histogram + scan (independent of gemm1)
    hist_kernel<<<(E + 255) / 256, 256, 0, stream>>>(esrc, counts, E);
    scan_kernel<<<1, SCAN_T, 0, stream>>>(counts, row_start, N, E);

    // layer 1
    gemm1_kernel<<<(N + 63) / 64, 256, 0, stream>>>(x_bf, wh_t, ah32, h_bf, s1s, s1d, N);
    scatter_ev_kernel<<<(E + 255) / 256, 256, 0, stream>>>(esrc, edst, row_start, cursor,
                                                           s1s, s1d, csr_dst, ev_csr, E);
    edge_agg1_kernel<<<(N + 3) / 4, 256, 0, stream>>>(row_start, csr_dst, ev_csr,
                                                      (const uint4*)h_bf, (uint4*)xcat_bf, N);

    // layer 2
    gemm2_kernel<<<(N + 255) / 256, 256, 0, stream>>>(xcat_bf, Wo32, ao32, h2p, s2s, s2d, N);
    edge_agg2_kernel<<<(N + 3) / 4, 256, 0, stream>>>(row_start, csr_dst, h2p, s2s, s2d, d_out, flag, N);
}

// Round 8
// 611.945 us; speedup vs baseline: 4.5649x; 1.0108x over previous
//
#include <hip/hip_runtime.h>
#include <hip/hip_bf16.h>

#define F_IN    256
#define D_HID   64
#define H_HEADS 8
#define NC      10
#define ALPHA   0.2f
#define FLAG_THRESH 64
#define SCAN_T  1024

typedef __attribute__((ext_vector_type(8))) short short8;
typedef __attribute__((ext_vector_type(4))) float f32x4;

// ---------- bf16 helpers ----------
__device__ __forceinline__ float bfu2f(unsigned short u) {
    union { float f; unsigned int i; } c; c.i = ((unsigned int)u) << 16; return c.f;
}
__device__ __forceinline__ unsigned short f2bfu(float f) {
    union { float f; unsigned int i; } c; c.f = f;
    unsigned int x = c.i;
    x += 0x7fffu + ((x >> 16) & 1u);   // round-to-nearest-even
    return (unsigned short)(x >> 16);
}

// ---------- dtype detection (f32 vs bf16 storage) ----------
__global__ void detect_kernel(const unsigned int* __restrict__ x, int* __restrict__ flag) {
    int t = threadIdx.x;
    int cnt = 0;
    for (int i = t; i < 4096; i += 256) {
        unsigned int w = x[i];
        unsigned int e = (w >> 7) & 0xffu;
        if (e >= 140u) cnt++;
    }
    atomicAdd(flag, cnt);
}

// ---------- canonicalize any float tensor to f32 ----------
__global__ __launch_bounds__(256) void convert_kernel(
    const void* __restrict__ src, float* __restrict__ dst, long n,
    const int* __restrict__ flagp)
{
    long i = (long)blockIdx.x * 256 + threadIdx.x;
    if (i >= n) return;
    bool isf32 = (*flagp > FLAG_THRESH);
    dst[i] = isf32 ? ((const float*)src)[i]
                   : bfu2f(((const unsigned short*)src)[i]);
}

// ---------- x -> bf16 (8 elems / thread) ----------
__global__ __launch_bounds__(256) void convert_x_kernel(
    const void* __restrict__ src, unsigned short* __restrict__ dst, long n8,
    const int* __restrict__ flagp)
{
    long i = (long)blockIdx.x * 256 + threadIdx.x;
    if (i >= n8) return;
    bool isf32 = (*flagp > FLAG_THRESH);
    unsigned short o[8];
    if (isf32) {
        const float* s = (const float*)src + i * 8;
        #pragma unroll
        for (int j = 0; j < 8; ++j) o[j] = f2bfu(s[j]);
    } else {
        *(uint4*)o = ((const uint4*)src)[i];
    }
    *(uint4*)(dst + i * 8) = *(uint4*)o;
}

// ---------- W_heads [8][256][64] -> transposed bf16 [8][64][256] ----------
__global__ __launch_bounds__(256) void convert_whT_kernel(
    const void* __restrict__ src, unsigned short* __restrict__ dst,
    const int* __restrict__ flagp)
{
    int i = blockIdx.x * 256 + threadIdx.x;
    if (i >= H_HEADS * F_IN * D_HID) return;
    int d = i & 63, k = (i >> 6) & 255, h = i >> 14;
    bool isf32 = (*flagp > FLAG_THRESH);
    float v = isf32 ? ((const float*)src)[i] : bfu2f(((const unsigned short*)src)[i]);
    dst[(h * 64 + d) * 256 + k] = f2bfu(v);
}

// ---------- CSR build ----------
__global__ __launch_bounds__(256) void hist_kernel(
    const int* __restrict__ src, int* __restrict__ counts, int E)
{
    int e = blockIdx.x * 256 + threadIdx.x;
    if (e < E) atomicAdd(&counts[src[e]], 1);
}

__global__ __launch_bounds__(SCAN_T) void scan_kernel(
    const int* __restrict__ counts, int* __restrict__ row_start, int N, int E)
{
    __shared__ int sums[SCAN_T];
    int t = threadIdx.x;
    int chunk = (N + SCAN_T - 1) / SCAN_T;
    int b = t * chunk, e = min(b + chunk, N);
    int s = 0;
    for (int i = b; i < e; ++i) s += counts[i];
    sums[t] = s;
    __syncthreads();
    for (int off = 1; off < SCAN_T; off <<= 1) {
        int u = (t >= off) ? sums[t - off] : 0;
        __syncthreads();
        sums[t] += u;
        __syncthreads();
    }
    int running = sums[t] - s;
    for (int i = b; i < e; ++i) { row_start[i] = running; running += counts[i]; }
    if (t == SCAN_T - 1) row_start[N] = E;
}

// ---------- CSR scatter + fused layer-1 edge coefficients ----------
__global__ __launch_bounds__(256) void scatter_ev_kernel(
    const int* __restrict__ src, const int* __restrict__ dst,
    const int* __restrict__ row_start, int* __restrict__ cursor,
    const float* __restrict__ s1s, const float* __restrict__ s1d,
    int* __restrict__ csr_dst, float* __restrict__ ev_csr, int E)
{
    int e = blockIdx.x * 256 + threadIdx.x;
    if (e >= E) return;
    int s = src[e], d = dst[e];
    int pos = atomicAdd(&cursor[s], 1);
    int i = row_start[s] + pos;
    csr_dst[i] = d;
    float4 ss0 = *(const float4*)(s1s + s * 8);
    float4 ss1 = *(const float4*)(s1s + s * 8 + 4);
    float4 sd0 = *(const float4*)(s1d + d * 8);
    float4 sd1 = *(const float4*)(s1d + d * 8 + 4);
    float sc[8] = { ss0.x + sd0.x, ss0.y + sd0.y, ss0.z + sd0.z, ss0.w + sd0.w,
                    ss1.x + sd1.x, ss1.y + sd1.y, ss1.z + sd1.z, ss1.w + sd1.w };
    float ev[8];
    #pragma unroll
    for (int h = 0; h < 8; ++h) {
        float lr = sc[h] > 0.f ? sc[h] : ALPHA * sc[h];
        ev[h] = __expf(-lr);
    }
    *(float4*)(ev_csr + (long)i * 8)     = make_float4(ev[0], ev[1], ev[2], ev[3]);
    *(float4*)(ev_csr + (long)i * 8 + 4) = make_float4(ev[4], ev[5], ev[6], ev[7]);
}

// ---------- layer-1 MFMA GEMM + fused attn1 (v3: no A staging, 13 KB LDS) ----------
// A-frags loaded directly from global (L3-hot x_bf); row clamped to N-1 —
// garbage confined to C rows >= N which all stores guard.
__global__ __launch_bounds__(256) void gemm1_kernel(
    const unsigned short* __restrict__ x_bf,   // [N,256] bf16
    const unsigned short* __restrict__ wh_t,   // [8][64][256] bf16 (d-major)
    const float* __restrict__ ah,              // [8,128] f32
    unsigned short* __restrict__ h_bf,         // [N,512] bf16 out
    float* __restrict__ s1s, float* __restrict__ s1d, int N)
{
    __shared__ unsigned short Os[64][72];
    __shared__ float Ss[64][8];
    __shared__ float Sd[64][8];

    const int t = threadIdx.x;
    const int w = t >> 6, lane = t & 63;
    const int q = lane >> 4, m = lane & 15;
    const int n0 = blockIdx.x * 64;

    // direct global A-frag loads: row = 16w+m (clamped), k = ks*32 + q*8
    int r = n0 + 16 * w + m;
    const unsigned short* xr = x_bf + (long)(r < N ? r : N - 1) * 256;
    short8 afrag[8];
    #pragma unroll
    for (int ks = 0; ks < 8; ++ks)
        afrag[ks] = *(const short8*)(xr + ks * 32 + q * 8);

    for (int h = 0; h < 8; ++h) {
        f32x4 acc[4] = {};
        const unsigned short* Bh = wh_t + (long)h * 64 * 256;
        #pragma unroll
        for (int ks = 0; ks < 8; ++ks) {
            #pragma unroll
            for (int c = 0; c < 4; ++c) {
                short8 b = *(const short8*)(Bh + (c * 16 + m) * 256 + ks * 32 + q * 8);
                acc[c] = __builtin_amdgcn_mfma_f32_16x16x32_bf16(afrag[ks], b, acc[c], 0, 0, 0);
            }
        }

        const float* a1 = ah + h * 128;
        float a1m = a1[m], a1m16 = a1[16 + m], a1m32 = a1[32 + m], a1m48 = a1[48 + m];
        float a2m = a1[64 + m], a2m16 = a1[80 + m], a2m32 = a1[96 + m], a2m48 = a1[112 + m];
        #pragma unroll
        for (int reg = 0; reg < 4; ++reg) {
            float p1 = acc[0][reg] * a1m + acc[1][reg] * a1m16 + acc[2][reg] * a1m32 + acc[3][reg] * a1m48;
            float p2 = acc[0][reg] * a2m + acc[1][reg] * a2m16 + acc[2][reg] * a2m32 + acc[3][reg] * a2m48;
            #pragma unroll
            for (int off = 1; off < 16; off <<= 1) {
                p1 += __shfl_xor(p1, off);
                p2 += __shfl_xor(p2, off);
            }
            if (m == 0) {
                int row = 16 * w + q * 4 + reg;
                Ss[row][h] = p1;
                Sd[row][h] = p2;
            }
        }

        #pragma unroll
        for (int c = 0; c < 4; ++c)
            #pragma unroll
            for (int reg = 0; reg < 4; ++reg)
                Os[16 * w + q * 4 + reg][c * 16 + m] = f2bfu(acc[c][reg]);
        #pragma unroll
        for (int j = 0; j < 2; ++j) {
            int cc = j * 64 + lane;
            int row = cc >> 3, c8 = cc & 7;
            if (n0 + 16 * w + row < N)
                *(uint4*)(h_bf + (long)(n0 + 16 * w + row) * 512 + h * 64 + c8 * 8) =
                    *(const uint4*)&Os[16 * w + row][c8 * 8];
        }
    }

    __syncthreads();
    for (int i = t; i < 512; i += 256) {
        int row = i >> 3, hh = i & 7;
        if (n0 + row < N) {
            s1s[(n0 + row) * 8 + hh] = Ss[row][hh];
            s1d[(n0 + row) * 8 + hh] = Sd[row][hh];
        }
    }
}

// ---------- layer-1 CSR gather v3: ONE WAVE per node, all 8 heads ----------
__global__ __launch_bounds__(256) void edge_agg1_kernel(
    const int* __restrict__ row_start, const int* __restrict__ csr_dst,
    const float* __restrict__ ev_csr,      // [E*8]
    const uint4* __restrict__ h_q,         // [N*64] uint4 (= [N,512] bf16)
    uint4* __restrict__ xcat_q,            // [N*64]
    int N)
{
    int lane = threadIdx.x & 63;
    int n = blockIdx.x * 4 + (threadIdx.x >> 6);
    if (n >= N) return;
    int h = lane >> 3;
    int beg = row_start[n], end = row_start[n + 1];

    float acc[8] = {0.f, 0.f, 0.f, 0.f, 0.f, 0.f, 0.f, 0.f};
    float rs = 0.f;
    int dnext = csr_dst[beg];              // end > beg guaranteed (self-loop)
    for (int i = beg; i < end; ++i) {
        int d = dnext;
        if (i + 1 < end) dnext = csr_dst[i + 1];
        float ev = ev_csr[(long)i * 8 + h];
        uint4 wv = h_q[(long)d * 64 + lane];
        rs += ev;
        acc[0] += ev * bfu2f((unsigned short)(wv.x & 0xffffu));
        acc[1] += ev * bfu2f((unsigned short)(wv.x >> 16));
        acc[2] += ev * bfu2f((unsigned short)(wv.y & 0xffffu));
        acc[3] += ev * bfu2f((unsigned short)(wv.y >> 16));
        acc[4] += ev * bfu2f((unsigned short)(wv.z & 0xffffu));
        acc[5] += ev * bfu2f((unsigned short)(wv.z >> 16));
        acc[6] += ev * bfu2f((unsigned short)(wv.w & 0xffffu));
        acc[7] += ev * bfu2f((unsigned short)(wv.w >> 16));
    }
    float inv = 1.f / rs;
    unsigned short o[8];
    #pragma unroll
    for (int j = 0; j < 8; ++j) {
        float v = acc[j] * inv;
        v = v > 0.f ? v : __expf(v) - 1.f;   // elu
        o[j] = f2bfu(v);
    }
    xcat_q[(long)n * 64 + lane] = *(const uint4*)o;
}

// ---------- layer-2 GEMM + fused attn2: thread per node; h2 padded [N,16] ----------
__global__ __launch_bounds__(256) void gemm2_kernel(
    const unsigned short* __restrict__ xcat_bf, // [N,512] bf16
    const float* __restrict__ Wo,               // [512,10] f32
    const float* __restrict__ ao,               // [20] f32
    float* __restrict__ h2p,                    // [N,16] f32, pad=0
    float* __restrict__ s2s, float* __restrict__ s2d, int N)
{
    int n = blockIdx.x * 256 + threadIdx.x;
    if (n >= N) return;
    float acc[NC];
    #pragma unroll
    for (int c = 0; c < NC; ++c) acc[c] = 0.f;
    const uint4* xp = (const uint4*)(xcat_bf + (long)n * 512);
    for (int k8 = 0; k8 < 64; ++k8) {
        uint4 w = xp[k8];
        float f[8];
        f[0] = bfu2f((unsigned short)(w.x & 0xffffu)); f[1] = bfu2f((unsigned short)(w.x >> 16));
        f[2] = bfu2f((unsigned short)(w.y & 0xffffu)); f[3] = bfu2f((unsigned short)(w.y >> 16));
        f[4] = bfu2f((unsigned short)(w.z & 0xffffu)); f[5] = bfu2f((unsigned short)(w.z >> 16));
        f[6] = bfu2f((unsigned short)(w.w & 0xffffu)); f[7] = bfu2f((unsigned short)(w.w >> 16));
        #pragma unroll
        for (int u = 0; u < 8; ++u) {
            const float* wr = Wo + (k8 * 8 + u) * NC;
            #pragma unroll
            for (int c = 0; c < NC; ++c) acc[c] += f[u] * wr[c];
        }
    }
    float s1 = 0.f, s2 = 0.f;
    *(float4*)(h2p + (long)n * 16)      = make_float4(acc[0], acc[1], acc[2], acc[3]);
    *(float4*)(h2p + (long)n * 16 + 4)  = make_float4(acc[4], acc[5], acc[6], acc[7]);
    *(float4*)(h2p + (long)n * 16 + 8)  = make_float4(acc[8], acc[9], 0.f, 0.f);
    *(float4*)(h2p + (long)n * 16 + 12) = make_float4(0.f, 0.f, 0.f, 0.f);
    #pragma unroll
    for (int c = 0; c < NC; ++c) {
        s1 += acc[c] * ao[c];
        s2 += acc[c] * ao[NC + c];
    }
    s2s[n] = s1;
    s2d[n] = s2;
}

// ---------- layer-2 CSR gather v2: wave per node, lane=(edge-slot j, class c) ----------
__global__ __launch_bounds__(256) void edge_agg2_kernel(
    const int* __restrict__ row_start, const int* __restrict__ csr_dst,
    const float* __restrict__ h2p,             // [N,16] f32, pad=0
    const float* __restrict__ s_src2, const float* __restrict__ s_dst2,
    void* __restrict__ out, const int* __restrict__ flagp, int N)
{
    int lane = threadIdx.x & 63;
    int n = blockIdx.x * 4 + (threadIdx.x >> 6);
    if (n >= N) return;
    int c = lane & 15, j = lane >> 4;   // 4 edge slots x 16 classes(padded)
    int beg = row_start[n], end = row_start[n + 1];
    float ss = s_src2[n];
    float rs = 0.f, acc = 0.f;
    for (int i0 = beg; i0 < end; i0 += 4) {
        int i = i0 + j;
        if (i < end) {
            int d = csr_dst[i];
            float sc = ss + s_dst2[d];
            float lr = sc > 0.f ? sc : ALPHA * sc;
            float ev = __expf(-lr);
            rs += ev;
            acc += ev * h2p[(long)d * 16 + c];
        }
    }
    rs  += __shfl_xor(rs, 16, 64);  rs  += __shfl_xor(rs, 32, 64);
    acc += __shfl_xor(acc, 16, 64); acc += __shfl_xor(acc, 32, 64);
    float v = acc / rs;
    v = v > 0.f ? v : __expf(v) - 1.f;           // elu
    float vm = (c < NC) ? v : -1e30f;
    #pragma unroll
    for (int off = 1; off < 16; off <<= 1) vm = fmaxf(vm, __shfl_xor(vm, off, 64));
    float ex = (c < NC) ? __expf(v - vm) : 0.f;
    #pragma unroll
    for (int off = 1; off < 16; off <<= 1) ex += __shfl_xor(ex, off, 64);
    float lse = vm + logf(ex);
    if (c < NC && j == 0) {
        bool isf32 = (*flagp > FLAG_THRESH);
        if (isf32) ((float*)out)[(long)n * NC + c] = v - lse;
        else       ((unsigned short*)out)[(long)n * NC + c] = f2bfu(v - lse);
    }
}

extern "C" void kernel_launch(void* const* d_in, const int* in_sizes, int n_in,
                              void* d_out, int out_size, void* d_ws, size_t ws_size,
                              hipStream_t stream)
{
    const void* x_raw  = d_in[0];
    const int*  esrc   = (const int*)d_in[1];
    const int*  edst   = (const int*)d_in[2];
    const void* Wh_raw = d_in[3];
    const void* ah_raw = d_in[4];
    const void* Wo_raw = d_in[5];
    const void* ao_raw = d_in[6];

    const int N = in_sizes[0] / F_IN;
    const int E = in_sizes[1];

    char* ws = (char*)d_ws;
    size_t off = 0;
    auto alloc = [&](size_t bytes) -> void* {
        void* p = ws + off;
        off = (off + bytes + 255) & ~(size_t)255;
        return p;
    };
    int*            flag      = (int*)           alloc(4);
    unsigned short* x_bf      = (unsigned short*)alloc((size_t)N * F_IN * 2);
    unsigned short* wh_t      = (unsigned short*)alloc((size_t)H_HEADS * D_HID * F_IN * 2);
    float*          ah32      = (float*)         alloc((size_t)H_HEADS * 2 * D_HID * 4);
    float*          Wo32      = (float*)         alloc((size_t)512 * NC * 4);
    float*          ao32      = (float*)         alloc((size_t)2 * NC * 4);
    unsigned short* h_bf      = (unsigned short*)alloc((size_t)N * 512 * 2);
    unsigned short* xcat_bf   = (unsigned short*)alloc((size_t)N * 512 * 2);
    float*          s1s       = (float*)         alloc((size_t)N * 8 * 4);
    float*          s1d       = (float*)         alloc((size_t)N * 8 * 4);
    float*          h2p       = (float*)         alloc((size_t)N * 16 * 4);
    float*          s2s       = (float*)         alloc((size_t)N * 4);
    float*          s2d       = (float*)         alloc((size_t)N * 4);
    int*            counts    = (int*)           alloc((size_t)N * 4);
    int*            cursor    = (int*)           alloc((size_t)N * 4);
    int*            row_start = (int*)           alloc((size_t)(N + 1) * 4);
    int*            csr_dst   = (int*)           alloc((size_t)E * 4);
    float*          ev_csr    = (float*)         alloc((size_t)E * 8 * 4);
    (void)ws_size;

    hipMemsetAsync(flag, 0, 4, stream);
    hipMemsetAsync(counts, 0, (size_t)N * 4, stream);
    hipMemsetAsync(cursor, 0, (size_t)N * 4, stream);

    // dtype detect + canonicalize
    detect_kernel<<<1, 256, 0, stream>>>((const unsigned int*)x_raw, flag);
    long n8 = (long)N * F_IN / 8;
    convert_x_kernel<<<(unsigned)((n8 + 255) / 256), 256, 0, stream>>>(x_raw, x_bf, n8, flag);
    convert_whT_kernel<<<(H_HEADS * F_IN * D_HID + 255) / 256, 256, 0, stream>>>(Wh_raw, wh_t, flag);
    convert_kernel<<<(H_HEADS * 2 * D_HID + 255) / 256, 256, 0, stream>>>(ah_raw, ah32, H_HEADS * 2 * D_HID, flag);
    convert_kernel<<<(512 * NC + 255) / 256, 256, 0, stream>>>(Wo_raw, Wo32, 512 * NC, flag);
    convert_kernel<<<1, 256, 0, stream>>>(ao_raw, ao32, 2 * NC, flag);

    // CSR histogram + scan (independent of gemm1)
    hist_kernel<<<(E + 255) / 256, 256, 0, stream>>>(esrc, counts, E);
    scan_kernel<<<1, SCAN_T, 0, stream>>>(counts, row_start, N, E);

    // layer 1
    gemm1_kernel<<<(N + 63) / 64, 256, 0, stream>>>(x_bf, wh_t, ah32, h_bf, s1s, s1d, N);
    scatter_ev_kernel<<<(E + 255) / 256, 256, 0, stream>>>(esrc, edst, row_start, cursor,
                                                           s1s, s1d, csr_dst, ev_csr, E);
    edge_agg1_kernel<<<(N + 3) / 4, 256, 0, stream>>>(row_start, csr_dst, ev_csr,
                                                      (const uint4*)h_bf, (uint4*)xcat_bf, N);

    // layer 2
    gemm2_kernel<<<(N + 255) / 256, 256, 0, stream>>>(xcat_bf, Wo32, ao32, h2p, s2s, s2d, N);
    edge_agg2_kernel<<<(N + 3) / 4, 256, 0, stream>>>(row_start, csr_dst, h2p, s2s, s2d, d_out, flag, N);
}

// Round 9
// 598.479 us; speedup vs baseline: 4.6676x; 1.0225x over previous
//
#include <hip/hip_runtime.h>
#include <hip/hip_bf16.h>

#define F_IN    256
#define D_HID   64
#define H_HEADS 8
#define NC      10
#define ALPHA   0.2f
#define FLAG_THRESH 64
#define SCAN_T  1024

typedef __attribute__((ext_vector_type(8))) short short8;
typedef __attribute__((ext_vector_type(4))) float f32x4;

// ---------- bf16 helpers ----------
__device__ __forceinline__ float bfu2f(unsigned short u) {
    union { float f; unsigned int i; } c; c.i = ((unsigned int)u) << 16; return c.f;
}
__device__ __forceinline__ unsigned short f2bfu(float f) {
    union { float f; unsigned int i; } c; c.f = f;
    unsigned int x = c.i;
    x += 0x7fffu + ((x >> 16) & 1u);   // round-to-nearest-even
    return (unsigned short)(x >> 16);
}

// ---------- dtype detection (f32 vs bf16 storage) ----------
__global__ void detect_kernel(const unsigned int* __restrict__ x, int* __restrict__ flag) {
    int t = threadIdx.x;
    int cnt = 0;
    for (int i = t; i < 4096; i += 256) {
        unsigned int w = x[i];
        unsigned int e = (w >> 7) & 0xffu;
        if (e >= 140u) cnt++;
    }
    atomicAdd(flag, cnt);
}

// ---------- canonicalize any float tensor to f32 ----------
__global__ __launch_bounds__(256) void convert_kernel(
    const void* __restrict__ src, float* __restrict__ dst, long n,
    const int* __restrict__ flagp)
{
    long i = (long)blockIdx.x * 256 + threadIdx.x;
    if (i >= n) return;
    bool isf32 = (*flagp > FLAG_THRESH);
    dst[i] = isf32 ? ((const float*)src)[i]
                   : bfu2f(((const unsigned short*)src)[i]);
}

// ---------- x -> bf16 (8 elems / thread) ----------
__global__ __launch_bounds__(256) void convert_x_kernel(
    const void* __restrict__ src, unsigned short* __restrict__ dst, long n8,
    const int* __restrict__ flagp)
{
    long i = (long)blockIdx.x * 256 + threadIdx.x;
    if (i >= n8) return;
    bool isf32 = (*flagp > FLAG_THRESH);
    unsigned short o[8];
    if (isf32) {
        const float* s = (const float*)src + i * 8;
        #pragma unroll
        for (int j = 0; j < 8; ++j) o[j] = f2bfu(s[j]);
    } else {
        *(uint4*)o = ((const uint4*)src)[i];
    }
    *(uint4*)(dst + i * 8) = *(uint4*)o;
}

// ---------- W_heads [8][256][64] -> transposed bf16 [8][64][256] ----------
__global__ __launch_bounds__(256) void convert_whT_kernel(
    const void* __restrict__ src, unsigned short* __restrict__ dst,
    const int* __restrict__ flagp)
{
    int i = blockIdx.x * 256 + threadIdx.x;
    if (i >= H_HEADS * F_IN * D_HID) return;
    int d = i & 63, k = (i >> 6) & 255, h = i >> 14;
    bool isf32 = (*flagp > FLAG_THRESH);
    float v = isf32 ? ((const float*)src)[i] : bfu2f(((const unsigned short*)src)[i]);
    dst[(h * 64 + d) * 256 + k] = f2bfu(v);
}

// ---------- CSR build ----------
__global__ __launch_bounds__(256) void hist_kernel(
    const int* __restrict__ src, int* __restrict__ counts, int E)
{
    int e = blockIdx.x * 256 + threadIdx.x;
    if (e < E) atomicAdd(&counts[src[e]], 1);
}

__global__ __launch_bounds__(SCAN_T) void scan_kernel(
    const int* __restrict__ counts, int* __restrict__ row_start, int N, int E)
{
    __shared__ int sums[SCAN_T];
    int t = threadIdx.x;
    int chunk = (N + SCAN_T - 1) / SCAN_T;
    int b = t * chunk, e = min(b + chunk, N);
    int s = 0;
    for (int i = b; i < e; ++i) s += counts[i];
    sums[t] = s;
    __syncthreads();
    for (int off = 1; off < SCAN_T; off <<= 1) {
        int u = (t >= off) ? sums[t - off] : 0;
        __syncthreads();
        sums[t] += u;
        __syncthreads();
    }
    int running = sums[t] - s;
    for (int i = b; i < e; ++i) { row_start[i] = running; running += counts[i]; }
    if (t == SCAN_T - 1) row_start[N] = E;
}

// ---------- CSR scatter + fused layer-1 edge coefficients ----------
__global__ __launch_bounds__(256) void scatter_ev_kernel(
    const int* __restrict__ src, const int* __restrict__ dst,
    const int* __restrict__ row_start, int* __restrict__ cursor,
    const float* __restrict__ s1s, const float* __restrict__ s1d,
    int* __restrict__ csr_dst, float* __restrict__ ev_csr, int E)
{
    int e = blockIdx.x * 256 + threadIdx.x;
    if (e >= E) return;
    int s = src[e], d = dst[e];
    int pos = atomicAdd(&cursor[s], 1);
    int i = row_start[s] + pos;
    csr_dst[i] = d;
    float4 ss0 = *(const float4*)(s1s + s * 8);
    float4 ss1 = *(const float4*)(s1s + s * 8 + 4);
    float4 sd0 = *(const float4*)(s1d + d * 8);
    float4 sd1 = *(const float4*)(s1d + d * 8 + 4);
    float sc[8] = { ss0.x + sd0.x, ss0.y + sd0.y, ss0.z + sd0.z, ss0.w + sd0.w,
                    ss1.x + sd1.x, ss1.y + sd1.y, ss1.z + sd1.z, ss1.w + sd1.w };
    float ev[8];
    #pragma unroll
    for (int h = 0; h < 8; ++h) {
        float lr = sc[h] > 0.f ? sc[h] : ALPHA * sc[h];
        ev[h] = __expf(-lr);
    }
    *(float4*)(ev_csr + (long)i * 8)     = make_float4(ev[0], ev[1], ev[2], ev[3]);
    *(float4*)(ev_csr + (long)i * 8 + 4) = make_float4(ev[4], ev[5], ev[6], ev[7]);
}

// ---------- layer-1 MFMA GEMM + fused attn1 (v4: head-split grid) ----------
// grid (ceil(N/64), 8): block = 64 rows x ONE head -> 6256 blocks (24/CU),
// latency hidden by cross-block interleave (v3 was grid-capped at 3 blocks/CU).
// A-frags direct from global (L3-hot); row clamped to N-1, stores guarded.
__global__ __launch_bounds__(256) void gemm1_kernel(
    const unsigned short* __restrict__ x_bf,   // [N,256] bf16
    const unsigned short* __restrict__ wh_t,   // [8][64][256] bf16 (d-major)
    const float* __restrict__ ah,              // [8,128] f32
    unsigned short* __restrict__ h_bf,         // [N,512] bf16 out
    float* __restrict__ s1s, float* __restrict__ s1d, int N)
{
    __shared__ unsigned short Os[64][72];

    const int t = threadIdx.x;
    const int w = t >> 6, lane = t & 63;
    const int q = lane >> 4, m = lane & 15;
    const int n0 = blockIdx.x * 64;
    const int h = blockIdx.y;

    int r = n0 + 16 * w + m;
    const unsigned short* xr = x_bf + (long)(r < N ? r : N - 1) * 256;
    short8 afrag[8];
    #pragma unroll
    for (int ks = 0; ks < 8; ++ks)
        afrag[ks] = *(const short8*)(xr + ks * 32 + q * 8);

    f32x4 acc[4] = {};
    const unsigned short* Bh = wh_t + (long)h * 64 * 256;
    #pragma unroll
    for (int ks = 0; ks < 8; ++ks) {
        #pragma unroll
        for (int c = 0; c < 4; ++c) {
            short8 b = *(const short8*)(Bh + (c * 16 + m) * 256 + ks * 32 + q * 8);
            acc[c] = __builtin_amdgcn_mfma_f32_16x16x32_bf16(afrag[ks], b, acc[c], 0, 0, 0);
        }
    }

    // fused attn1: per-row dots with a-vector halves, reduce over 16 col-lanes
    const float* a1 = ah + h * 128;
    float a1m = a1[m], a1m16 = a1[16 + m], a1m32 = a1[32 + m], a1m48 = a1[48 + m];
    float a2m = a1[64 + m], a2m16 = a1[80 + m], a2m32 = a1[96 + m], a2m48 = a1[112 + m];
    #pragma unroll
    for (int reg = 0; reg < 4; ++reg) {
        float p1 = acc[0][reg] * a1m + acc[1][reg] * a1m16 + acc[2][reg] * a1m32 + acc[3][reg] * a1m48;
        float p2 = acc[0][reg] * a2m + acc[1][reg] * a2m16 + acc[2][reg] * a2m32 + acc[3][reg] * a2m48;
        #pragma unroll
        for (int off = 1; off < 16; off <<= 1) {
            p1 += __shfl_xor(p1, off);
            p2 += __shfl_xor(p2, off);
        }
        int row = n0 + 16 * w + q * 4 + reg;
        if (m == 0 && row < N) {
            s1s[row * 8 + h] = p1;
            s1d[row * 8 + h] = p2;
        }
    }

    // stage 16x64 bf16 tile via wave-local LDS -> coalesced 16B stores
    #pragma unroll
    for (int c = 0; c < 4; ++c)
        #pragma unroll
        for (int reg = 0; reg < 4; ++reg)
            Os[16 * w + q * 4 + reg][c * 16 + m] = f2bfu(acc[c][reg]);
    #pragma unroll
    for (int j = 0; j < 2; ++j) {
        int cc = j * 64 + lane;
        int row = cc >> 3, c8 = cc & 7;
        if (n0 + 16 * w + row < N)
            *(uint4*)(h_bf + (long)(n0 + 16 * w + row) * 512 + h * 64 + c8 * 8) =
                *(const uint4*)&Os[16 * w + row][c8 * 8];
    }
}

// ---------- layer-1 CSR gather v3: ONE WAVE per node, all 8 heads ----------
__global__ __launch_bounds__(256) void edge_agg1_kernel(
    const int* __restrict__ row_start, const int* __restrict__ csr_dst,
    const float* __restrict__ ev_csr,      // [E*8]
    const uint4* __restrict__ h_q,         // [N*64] uint4 (= [N,512] bf16)
    uint4* __restrict__ xcat_q,            // [N*64]
    int N)
{
    int lane = threadIdx.x & 63;
    int n = blockIdx.x * 4 + (threadIdx.x >> 6);
    if (n >= N) return;
    int h = lane >> 3;
    int beg = row_start[n], end = row_start[n + 1];

    float acc[8] = {0.f, 0.f, 0.f, 0.f, 0.f, 0.f, 0.f, 0.f};
    float rs = 0.f;
    int dnext = csr_dst[beg];              // end > beg guaranteed (self-loop)
    for (int i = beg; i < end; ++i) {
        int d = dnext;
        if (i + 1 < end) dnext = csr_dst[i + 1];
        float ev = ev_csr[(long)i * 8 + h];
        uint4 wv = h_q[(long)d * 64 + lane];
        rs += ev;
        acc[0] += ev * bfu2f((unsigned short)(wv.x & 0xffffu));
        acc[1] += ev * bfu2f((unsigned short)(wv.x >> 16));
        acc[2] += ev * bfu2f((unsigned short)(wv.y & 0xffffu));
        acc[3] += ev * bfu2f((unsigned short)(wv.y >> 16));
        acc[4] += ev * bfu2f((unsigned short)(wv.z & 0xffffu));
        acc[5] += ev * bfu2f((unsigned short)(wv.z >> 16));
        acc[6] += ev * bfu2f((unsigned short)(wv.w & 0xffffu));
        acc[7] += ev * bfu2f((unsigned short)(wv.w >> 16));
    }
    float inv = 1.f / rs;
    unsigned short o[8];
    #pragma unroll
    for (int j = 0; j < 8; ++j) {
        float v = acc[j] * inv;
        v = v > 0.f ? v : __expf(v) - 1.f;   // elu
        o[j] = f2bfu(v);
    }
    xcat_q[(long)n * 64 + lane] = *(const uint4*)o;
}

// ---------- layer-2 GEMM + fused attn2: thread per node; h2 padded [N,16] ----------
__global__ __launch_bounds__(256) void gemm2_kernel(
    const unsigned short* __restrict__ xcat_bf, // [N,512] bf16
    const float* __restrict__ Wo,               // [512,10] f32
    const float* __restrict__ ao,               // [20] f32
    float* __restrict__ h2p,                    // [N,16] f32, pad=0
    float* __restrict__ s2s, float* __restrict__ s2d, int N)
{
    int n = blockIdx.x * 256 + threadIdx.x;
    if (n >= N) return;
    float acc[NC];
    #pragma unroll
    for (int c = 0; c < NC; ++c) acc[c] = 0.f;
    const uint4* xp = (const uint4*)(xcat_bf + (long)n * 512);
    for (int k8 = 0; k8 < 64; ++k8) {
        uint4 w = xp[k8];
        float f[8];
        f[0] = bfu2f((unsigned short)(w.x & 0xffffu)); f[1] = bfu2f((unsigned short)(w.x >> 16));
        f[2] = bfu2f((unsigned short)(w.y & 0xffffu)); f[3] = bfu2f((unsigned short)(w.y >> 16));
        f[4] = bfu2f((unsigned short)(w.z & 0xffffu)); f[5] = bfu2f((unsigned short)(w.z >> 16));
        f[6] = bfu2f((unsigned short)(w.w & 0xffffu)); f[7] = bfu2f((unsigned short)(w.w >> 16));
        #pragma unroll
        for (int u = 0; u < 8; ++u) {
            const float* wr = Wo + (k8 * 8 + u) * NC;
            #pragma unroll
            for (int c = 0; c < NC; ++c) acc[c] += f[u] * wr[c];
        }
    }
    float s1 = 0.f, s2 = 0.f;
    *(float4*)(h2p + (long)n * 16)      = make_float4(acc[0], acc[1], acc[2], acc[3]);
    *(float4*)(h2p + (long)n * 16 + 4)  = make_float4(acc[4], acc[5], acc[6], acc[7]);
    *(float4*)(h2p + (long)n * 16 + 8)  = make_float4(acc[8], acc[9], 0.f, 0.f);
    *(float4*)(h2p + (long)n * 16 + 12) = make_float4(0.f, 0.f, 0.f, 0.f);
    #pragma unroll
    for (int c = 0; c < NC; ++c) {
        s1 += acc[c] * ao[c];
        s2 += acc[c] * ao[NC + c];
    }
    s2s[n] = s1;
    s2d[n] = s2;
}

// ---------- layer-2 CSR gather v2: wave per node, lane=(edge-slot j, class c) ----------
__global__ __launch_bounds__(256) void edge_agg2_kernel(
    const int* __restrict__ row_start, const int* __restrict__ csr_dst,
    const float* __restrict__ h2p,             // [N,16] f32, pad=0
    const float* __restrict__ s_src2, const float* __restrict__ s_dst2,
    void* __restrict__ out, const int* __restrict__ flagp, int N)
{
    int lane = threadIdx.x & 63;
    int n = blockIdx.x * 4 + (threadIdx.x >> 6);
    if (n >= N) return;
    int c = lane & 15, j = lane >> 4;   // 4 edge slots x 16 classes(padded)
    int beg = row_start[n], end = row_start[n + 1];
    float ss = s_src2[n];
    float rs = 0.f, acc = 0.f;
    for (int i0 = beg; i0 < end; i0 += 4) {
        int i = i0 + j;
        if (i < end) {
            int d = csr_dst[i];
            float sc = ss + s_dst2[d];
            float lr = sc > 0.f ? sc : ALPHA * sc;
            float ev = __expf(-lr);
            rs += ev;
            acc += ev * h2p[(long)d * 16 + c];
        }
    }
    rs  += __shfl_xor(rs, 16, 64);  rs  += __shfl_xor(rs, 32, 64);
    acc += __shfl_xor(acc, 16, 64); acc += __shfl_xor(acc, 32, 64);
    float v = acc / rs;
    v = v > 0.f ? v : __expf(v) - 1.f;           // elu
    float vm = (c < NC) ? v : -1e30f;
    #pragma unroll
    for (int off = 1; off < 16; off <<= 1) vm = fmaxf(vm, __shfl_xor(vm, off, 64));
    float ex = (c < NC) ? __expf(v - vm) : 0.f;
    #pragma unroll
    for (int off = 1; off < 16; off <<= 1) ex += __shfl_xor(ex, off, 64);
    float lse = vm + logf(ex);
    if (c < NC && j == 0) {
        bool isf32 = (*flagp > FLAG_THRESH);
        if (isf32) ((float*)out)[(long)n * NC + c] = v - lse;
        else       ((unsigned short*)out)[(long)n * NC + c] = f2bfu(v - lse);
    }
}

extern "C" void kernel_launch(void* const* d_in, const int* in_sizes, int n_in,
                              void* d_out, int out_size, void* d_ws, size_t ws_size,
                              hipStream_t stream)
{
    const void* x_raw  = d_in[0];
    const int*  esrc   = (const int*)d_in[1];
    const int*  edst   = (const int*)d_in[2];
    const void* Wh_raw = d_in[3];
    const void* ah_raw = d_in[4];
    const void* Wo_raw = d_in[5];
    const void* ao_raw = d_in[6];

    const int N = in_sizes[0] / F_IN;
    const int E = in_sizes[1];

    char* ws = (char*)d_ws;
    size_t off = 0;
    auto alloc = [&](size_t bytes) -> void* {
        void* p = ws + off;
        off = (off + bytes + 255) & ~(size_t)255;
        return p;
    };
    int*            flag      = (int*)           alloc(4);
    unsigned short* x_bf      = (unsigned short*)alloc((size_t)N * F_IN * 2);
    unsigned short* wh_t      = (unsigned short*)alloc((size_t)H_HEADS * D_HID * F_IN * 2);
    float*          ah32      = (float*)         alloc((size_t)H_HEADS * 2 * D_HID * 4);
    float*          Wo32      = (float*)         alloc((size_t)512 * NC * 4);
    float*          ao32      = (float*)         alloc((size_t)2 * NC * 4);
    unsigned short* h_bf      = (unsigned short*)alloc((size_t)N * 512 * 2);
    unsigned short* xcat_bf   = (unsigned short*)alloc((size_t)N * 512 * 2);
    float*          s1s       = (float*)         alloc((size_t)N * 8 * 4);
    float*          s1d       = (float*)         alloc((size_t)N * 8 * 4);
    float*          h2p       = (float*)         alloc((size_t)N * 16 * 4);
    float*          s2s       = (float*)         alloc((size_t)N * 4);
    float*          s2d       = (float*)         alloc((size_t)N * 4);
    int*            counts    = (int*)           alloc((size_t)N * 4);
    int*            cursor    = (int*)           alloc((size_t)N * 4);
    int*            row_start = (int*)           alloc((size_t)(N + 1) * 4);
    int*            csr_dst   = (int*)           alloc((size_t)E * 4);
    float*          ev_csr    = (float*)         alloc((size_t)E * 8 * 4);
    (void)ws_size;

    hipMemsetAsync(flag, 0, 4, stream);
    hipMemsetAsync(counts, 0, (size_t)N * 4, stream);
    hipMemsetAsync(cursor, 0, (size_t)N * 4, stream);

    // dtype detect + canonicalize
    detect_kernel<<<1, 256, 0, stream>>>((const unsigned int*)x_raw, flag);
    long n8 = (long)N * F_IN / 8;
    convert_x_kernel<<<(unsigned)((n8 + 255) / 256), 256, 0, stream>>>(x_raw, x_bf, n8, flag);
    convert_whT_kernel<<<(H_HEADS * F_IN * D_HID + 255) / 256, 256, 0, stream>>>(Wh_raw, wh_t, flag);
    convert_kernel<<<(H_HEADS * 2 * D_HID + 255) / 256, 256, 0, stream>>>(ah_raw, ah32, H_HEADS * 2 * D_HID, flag);
    convert_kernel<<<(512 * NC + 255) / 256, 256, 0, stream>>>(Wo_raw, Wo32, 512 * NC, flag);
    convert_kernel<<<1, 256, 0, stream>>>(ao_raw, ao32, 2 * NC, flag);

    // CSR histogram + scan (independent of gemm1)
    hist_kernel<<<(E + 255) / 256, 256, 0, stream>>>(esrc, counts, E);
    scan_kernel<<<1, SCAN_T, 0, stream>>>(counts, row_start, N, E);

    // layer 1
    dim3 g1((N + 63) / 64, H_HEADS);
    gemm1_kernel<<<g1, 256, 0, stream>>>(x_bf, wh_t, ah32, h_bf, s1s, s1d, N);
    scatter_ev_kernel<<<(E + 255) / 256, 256, 0, stream>>>(esrc, edst, row_start, cursor,
                                                           s1s, s1d, csr_dst, ev_csr, E);
    edge_agg1_kernel<<<(N + 3) / 4, 256, 0, stream>>>(row_start, csr_dst, ev_csr,
                                                      (const uint4*)h_bf, (uint4*)xcat_bf, N);

    // layer 2
    gemm2_kernel<<<(N + 255) / 256, 256, 0, stream>>>(xcat_bf, Wo32, ao32, h2p, s2s, s2d, N);
    edge_agg2_kernel<<<(N + 3) / 4, 256, 0, stream>>>(row_start, csr_dst, h2p, s2s, s2d, d_out, flag, N);
}

// Round 10
// 585.143 us; speedup vs baseline: 4.7740x; 1.0228x over previous
//
#include <hip/hip_runtime.h>
#include <hip/hip_bf16.h>

#define F_IN    256
#define D_HID   64
#define H_HEADS 8
#define NC      10
#define ALPHA   0.2f
#define FLAG_THRESH 64
#define SCAN_T  1024

typedef __attribute__((ext_vector_type(8))) short short8;
typedef __attribute__((ext_vector_type(4))) float f32x4;

// ---------- bf16 helpers ----------
__device__ __forceinline__ float bfu2f(unsigned short u) {
    union { float f; unsigned int i; } c; c.i = ((unsigned int)u) << 16; return c.f;
}
__device__ __forceinline__ unsigned short f2bfu(float f) {
    union { float f; unsigned int i; } c; c.f = f;
    unsigned int x = c.i;
    x += 0x7fffu + ((x >> 16) & 1u);   // round-to-nearest-even
    return (unsigned short)(x >> 16);
}

// ---------- dtype detection (f32 vs bf16 storage) ----------
__global__ void detect_kernel(const unsigned int* __restrict__ x, int* __restrict__ flag) {
    int t = threadIdx.x;
    int cnt = 0;
    for (int i = t; i < 4096; i += 256) {
        unsigned int w = x[i];
        unsigned int e = (w >> 7) & 0xffu;
        if (e >= 140u) cnt++;
    }
    atomicAdd(flag, cnt);
}

// ---------- fused prep: all input conversions + edge histogram ----------
// blockIdx ranges: [0,bx) x->bf16 | [bx,bw) WhT | [bw,ba) ah | [ba,bo) Wo |
// bo: ao | (bo, ...) hist. All roles independent; all read flag (set by detect).
__global__ __launch_bounds__(256) void prep_kernel(
    const void* __restrict__ x_raw,  unsigned short* __restrict__ x_bf,
    const void* __restrict__ Wh_raw, unsigned short* __restrict__ wh_t,
    const void* __restrict__ ah_raw, float* __restrict__ ah32,
    const void* __restrict__ Wo_raw, float* __restrict__ Wo32,
    const void* __restrict__ ao_raw, float* __restrict__ ao32,
    const int* __restrict__ esrc, int* __restrict__ counts,
    const int* __restrict__ flagp, int N, int E,
    int bx, int bw, int ba, int bo)
{
    int b = blockIdx.x;
    bool isf32 = (*flagp > FLAG_THRESH);
    if (b < bx) {                       // x -> bf16, 8 elems/thread
        long i = (long)b * 256 + threadIdx.x;
        long n8 = (long)N * F_IN / 8;
        if (i < n8) {
            unsigned short o[8];
            if (isf32) {
                const float* s = (const float*)x_raw + i * 8;
                #pragma unroll
                for (int j = 0; j < 8; ++j) o[j] = f2bfu(s[j]);
            } else {
                *(uint4*)o = ((const uint4*)x_raw)[i];
            }
            *(uint4*)(x_bf + i * 8) = *(uint4*)o;
        }
    } else if (b < bw) {                // W_heads [8][256][64] -> [8][64][256] bf16
        int i = (b - bx) * 256 + threadIdx.x;
        int d = i & 63, k = (i >> 6) & 255, h = i >> 14;
        float v = isf32 ? ((const float*)Wh_raw)[i] : bfu2f(((const unsigned short*)Wh_raw)[i]);
        wh_t[(h * 64 + d) * 256 + k] = f2bfu(v);
    } else if (b < ba) {                // a_heads -> f32 (1024)
        int i = (b - bw) * 256 + threadIdx.x;
        ah32[i] = isf32 ? ((const float*)ah_raw)[i] : bfu2f(((const unsigned short*)ah_raw)[i]);
    } else if (b < bo) {                // W_out -> f32 (5120)
        int i = (b - ba) * 256 + threadIdx.x;
        Wo32[i] = isf32 ? ((const float*)Wo_raw)[i] : bfu2f(((const unsigned short*)Wo_raw)[i]);
    } else if (b == bo) {               // a_out -> f32 (20)
        int i = threadIdx.x;
        if (i < 2 * NC)
            ao32[i] = isf32 ? ((const float*)ao_raw)[i] : bfu2f(((const unsigned short*)ao_raw)[i]);
    } else {                            // edge histogram
        int e = (b - bo - 1) * 256 + threadIdx.x;
        if (e < E) atomicAdd(&counts[esrc[e]], 1);
    }
}

// ---------- CSR scan ----------
__global__ __launch_bounds__(SCAN_T) void scan_kernel(
    const int* __restrict__ counts, int* __restrict__ row_start, int N, int E)
{
    __shared__ int sums[SCAN_T];
    int t = threadIdx.x;
    int chunk = (N + SCAN_T - 1) / SCAN_T;
    int b = t * chunk, e = min(b + chunk, N);
    int s = 0;
    for (int i = b; i < e; ++i) s += counts[i];
    sums[t] = s;
    __syncthreads();
    for (int off = 1; off < SCAN_T; off <<= 1) {
        int u = (t >= off) ? sums[t - off] : 0;
        __syncthreads();
        sums[t] += u;
        __syncthreads();
    }
    int running = sums[t] - s;
    for (int i = b; i < e; ++i) { row_start[i] = running; running += counts[i]; }
    if (t == SCAN_T - 1) row_start[N] = E;
}

// ---------- CSR scatter + fused layer-1 edge coefficients ----------
__global__ __launch_bounds__(256) void scatter_ev_kernel(
    const int* __restrict__ src, const int* __restrict__ dst,
    const int* __restrict__ row_start, int* __restrict__ cursor,
    const float* __restrict__ s1s, const float* __restrict__ s1d,
    int* __restrict__ csr_dst, float* __restrict__ ev_csr, int E)
{
    int e = blockIdx.x * 256 + threadIdx.x;
    if (e >= E) return;
    int s = src[e], d = dst[e];
    int pos = atomicAdd(&cursor[s], 1);
    int i = row_start[s] + pos;
    csr_dst[i] = d;
    float4 ss0 = *(const float4*)(s1s + s * 8);
    float4 ss1 = *(const float4*)(s1s + s * 8 + 4);
    float4 sd0 = *(const float4*)(s1d + d * 8);
    float4 sd1 = *(const float4*)(s1d + d * 8 + 4);
    float sc[8] = { ss0.x + sd0.x, ss0.y + sd0.y, ss0.z + sd0.z, ss0.w + sd0.w,
                    ss1.x + sd1.x, ss1.y + sd1.y, ss1.z + sd1.z, ss1.w + sd1.w };
    float ev[8];
    #pragma unroll
    for (int h = 0; h < 8; ++h) {
        float lr = sc[h] > 0.f ? sc[h] : ALPHA * sc[h];
        ev[h] = __expf(-lr);
    }
    *(float4*)(ev_csr + (long)i * 8)     = make_float4(ev[0], ev[1], ev[2], ev[3]);
    *(float4*)(ev_csr + (long)i * 8 + 4) = make_float4(ev[4], ev[5], ev[6], ev[7]);
}

// ---------- layer-1 MFMA GEMM + fused attn1 (v5: 2 heads/block) ----------
// grid (ceil(N/64), 4): block = 64 rows x 2 heads. A-frags loaded once,
// reused across both head passes (halves A L3 re-fetch vs head-split v4),
// 3128 blocks keeps full wave residency (8 blocks/CU = 32 waves).
__global__ __launch_bounds__(256) void gemm1_kernel(
    const unsigned short* __restrict__ x_bf,   // [N,256] bf16
    const unsigned short* __restrict__ wh_t,   // [8][64][256] bf16 (d-major)
    const float* __restrict__ ah,              // [8,128] f32
    unsigned short* __restrict__ h_bf,         // [N,512] bf16 out
    float* __restrict__ s1s, float* __restrict__ s1d, int N)
{
    __shared__ unsigned short Os[64][72];

    const int t = threadIdx.x;
    const int w = t >> 6, lane = t & 63;
    const int q = lane >> 4, m = lane & 15;
    const int n0 = blockIdx.x * 64;
    const int h0 = blockIdx.y * 2;

    int r = n0 + 16 * w + m;
    const unsigned short* xr = x_bf + (long)(r < N ? r : N - 1) * 256;
    short8 afrag[8];
    #pragma unroll
    for (int ks = 0; ks < 8; ++ks)
        afrag[ks] = *(const short8*)(xr + ks * 32 + q * 8);

    #pragma unroll
    for (int hi = 0; hi < 2; ++hi) {
        const int h = h0 + hi;
        f32x4 acc[4] = {};
        const unsigned short* Bh = wh_t + (long)h * 64 * 256;
        #pragma unroll
        for (int ks = 0; ks < 8; ++ks) {
            #pragma unroll
            for (int c = 0; c < 4; ++c) {
                short8 b = *(const short8*)(Bh + (c * 16 + m) * 256 + ks * 32 + q * 8);
                acc[c] = __builtin_amdgcn_mfma_f32_16x16x32_bf16(afrag[ks], b, acc[c], 0, 0, 0);
            }
        }

        // fused attn1: per-row dots with a-vector halves, reduce over 16 col-lanes
        const float* a1 = ah + h * 128;
        float a1m = a1[m], a1m16 = a1[16 + m], a1m32 = a1[32 + m], a1m48 = a1[48 + m];
        float a2m = a1[64 + m], a2m16 = a1[80 + m], a2m32 = a1[96 + m], a2m48 = a1[112 + m];
        #pragma unroll
        for (int reg = 0; reg < 4; ++reg) {
            float p1 = acc[0][reg] * a1m + acc[1][reg] * a1m16 + acc[2][reg] * a1m32 + acc[3][reg] * a1m48;
            float p2 = acc[0][reg] * a2m + acc[1][reg] * a2m16 + acc[2][reg] * a2m32 + acc[3][reg] * a2m48;
            #pragma unroll
            for (int off = 1; off < 16; off <<= 1) {
                p1 += __shfl_xor(p1, off);
                p2 += __shfl_xor(p2, off);
            }
            int row = n0 + 16 * w + q * 4 + reg;
            if (m == 0 && row < N) {
                s1s[row * 8 + h] = p1;
                s1d[row * 8 + h] = p2;
            }
        }

        // stage 16x64 bf16 tile via wave-local LDS -> coalesced 16B stores
        // (wave-private rows of Os: no cross-wave hazard, no barrier needed)
        #pragma unroll
        for (int c = 0; c < 4; ++c)
            #pragma unroll
            for (int reg = 0; reg < 4; ++reg)
                Os[16 * w + q * 4 + reg][c * 16 + m] = f2bfu(acc[c][reg]);
        #pragma unroll
        for (int j = 0; j < 2; ++j) {
            int cc = j * 64 + lane;
            int row = cc >> 3, c8 = cc & 7;
            if (n0 + 16 * w + row < N)
                *(uint4*)(h_bf + (long)(n0 + 16 * w + row) * 512 + h * 64 + c8 * 8) =
                    *(const uint4*)&Os[16 * w + row][c8 * 8];
        }
    }
}

// ---------- layer-1 CSR gather: ONE WAVE per node, all 8 heads ----------
__global__ __launch_bounds__(256) void edge_agg1_kernel(
    const int* __restrict__ row_start, const int* __restrict__ csr_dst,
    const float* __restrict__ ev_csr,      // [E*8]
    const uint4* __restrict__ h_q,         // [N*64] uint4 (= [N,512] bf16)
    uint4* __restrict__ xcat_q,            // [N*64]
    int N)
{
    int lane = threadIdx.x & 63;
    int n = blockIdx.x * 4 + (threadIdx.x >> 6);
    if (n >= N) return;
    int h = lane >> 3;
    int beg = row_start[n], end = row_start[n + 1];

    float acc[8] = {0.f, 0.f, 0.f, 0.f, 0.f, 0.f, 0.f, 0.f};
    float rs = 0.f;
    int dnext = csr_dst[beg];              // end > beg guaranteed (self-loop)
    for (int i = beg; i < end; ++i) {
        int d = dnext;
        if (i + 1 < end) dnext = csr_dst[i + 1];
        float ev = ev_csr[(long)i * 8 + h];
        uint4 wv = h_q[(long)d * 64 + lane];
        rs += ev;
        acc[0] += ev * bfu2f((unsigned short)(wv.x & 0xffffu));
        acc[1] += ev * bfu2f((unsigned short)(wv.x >> 16));
        acc[2] += ev * bfu2f((unsigned short)(wv.y & 0xffffu));
        acc[3] += ev * bfu2f((unsigned short)(wv.y >> 16));
        acc[4] += ev * bfu2f((unsigned short)(wv.z & 0xffffu));
        acc[5] += ev * bfu2f((unsigned short)(wv.z >> 16));
        acc[6] += ev * bfu2f((unsigned short)(wv.w & 0xffffu));
        acc[7] += ev * bfu2f((unsigned short)(wv.w >> 16));
    }
    float inv = 1.f / rs;
    unsigned short o[8];
    #pragma unroll
    for (int j = 0; j < 8; ++j) {
        float v = acc[j] * inv;
        v = v > 0.f ? v : __expf(v) - 1.f;   // elu
        o[j] = f2bfu(v);
    }
    xcat_q[(long)n * 64 + lane] = *(const uint4*)o;
}

// ---------- layer-2 GEMM + fused attn2: thread per node; h2 padded [N,16] ----------
__global__ __launch_bounds__(256) void gemm2_kernel(
    const unsigned short* __restrict__ xcat_bf, // [N,512] bf16
    const float* __restrict__ Wo,               // [512,10] f32
    const float* __restrict__ ao,               // [20] f32
    float* __restrict__ h2p,                    // [N,16] f32, pad=0
    float* __restrict__ s2s, float* __restrict__ s2d, int N)
{
    int n = blockIdx.x * 256 + threadIdx.x;
    if (n >= N) return;
    float acc[NC];
    #pragma unroll
    for (int c = 0; c < NC; ++c) acc[c] = 0.f;
    const uint4* xp = (const uint4*)(xcat_bf + (long)n * 512);
    for (int k8 = 0; k8 < 64; ++k8) {
        uint4 w = xp[k8];
        float f[8];
        f[0] = bfu2f((unsigned short)(w.x & 0xffffu)); f[1] = bfu2f((unsigned short)(w.x >> 16));
        f[2] = bfu2f((unsigned short)(w.y & 0xffffu)); f[3] = bfu2f((unsigned short)(w.y >> 16));
        f[4] = bfu2f((unsigned short)(w.z & 0xffffu)); f[5] = bfu2f((unsigned short)(w.z >> 16));
        f[6] = bfu2f((unsigned short)(w.w & 0xffffu)); f[7] = bfu2f((unsigned short)(w.w >> 16));
        #pragma unroll
        for (int u = 0; u < 8; ++u) {
            const float* wr = Wo + (k8 * 8 + u) * NC;
            #pragma unroll
            for (int c = 0; c < NC; ++c) acc[c] += f[u] * wr[c];
        }
    }
    float s1 = 0.f, s2 = 0.f;
    *(float4*)(h2p + (long)n * 16)      = make_float4(acc[0], acc[1], acc[2], acc[3]);
    *(float4*)(h2p + (long)n * 16 + 4)  = make_float4(acc[4], acc[5], acc[6], acc[7]);
    *(float4*)(h2p + (long)n * 16 + 8)  = make_float4(acc[8], acc[9], 0.f, 0.f);
    *(float4*)(h2p + (long)n * 16 + 12) = make_float4(0.f, 0.f, 0.f, 0.f);
    #pragma unroll
    for (int c = 0; c < NC; ++c) {
        s1 += acc[c] * ao[c];
        s2 += acc[c] * ao[NC + c];
    }
    s2s[n] = s1;
    s2d[n] = s2;
}

// ---------- layer-2 CSR gather: wave per node, lane=(edge-slot j, class c) ----------
__global__ __launch_bounds__(256) void edge_agg2_kernel(
    const int* __restrict__ row_start, const int* __restrict__ csr_dst,
    const float* __restrict__ h2p,             // [N,16] f32, pad=0
    const float* __restrict__ s_src2, const float* __restrict__ s_dst2,
    void* __restrict__ out, const int* __restrict__ flagp, int N)
{
    int lane = threadIdx.x & 63;
    int n = blockIdx.x * 4 + (threadIdx.x >> 6);
    if (n >= N) return;
    int c = lane & 15, j = lane >> 4;   // 4 edge slots x 16 classes(padded)
    int beg = row_start[n], end = row_start[n + 1];
    float ss = s_src2[n];
    float rs = 0.f, acc = 0.f;
    for (int i0 = beg; i0 < end; i0 += 4) {
        int i = i0 + j;
        if (i < end) {
            int d = csr_dst[i];
            float sc = ss + s_dst2[d];
            float lr = sc > 0.f ? sc : ALPHA * sc;
            float ev = __expf(-lr);
            rs += ev;
            acc += ev * h2p[(long)d * 16 + c];
        }
    }
    rs  += __shfl_xor(rs, 16, 64);  rs  += __shfl_xor(rs, 32, 64);
    acc += __shfl_xor(acc, 16, 64); acc += __shfl_xor(acc, 32, 64);
    float v = acc / rs;
    v = v > 0.f ? v : __expf(v) - 1.f;           // elu
    float vm = (c < NC) ? v : -1e30f;
    #pragma unroll
    for (int off = 1; off < 16; off <<= 1) vm = fmaxf(vm, __shfl_xor(vm, off, 64));
    float ex = (c < NC) ? __expf(v - vm) : 0.f;
    #pragma unroll
    for (int off = 1; off < 16; off <<= 1) ex += __shfl_xor(ex, off, 64);
    float lse = vm + logf(ex);
    if (c < NC && j == 0) {
        bool isf32 = (*flagp > FLAG_THRESH);
        if (isf32) ((float*)out)[(long)n * NC + c] = v - lse;
        else       ((unsigned short*)out)[(long)n * NC + c] = f2bfu(v - lse);
    }
}

extern "C" void kernel_launch(void* const* d_in, const int* in_sizes, int n_in,
                              void* d_out, int out_size, void* d_ws, size_t ws_size,
                              hipStream_t stream)
{
    const void* x_raw  = d_in[0];
    const int*  esrc   = (const int*)d_in[1];
    const int*  edst   = (const int*)d_in[2];
    const void* Wh_raw = d_in[3];
    const void* ah_raw = d_in[4];
    const void* Wo_raw = d_in[5];
    const void* ao_raw = d_in[6];

    const int N = in_sizes[0] / F_IN;
    const int E = in_sizes[1];

    char* ws = (char*)d_ws;
    size_t off = 0;
    auto alloc = [&](size_t bytes) -> void* {
        void* p = ws + off;
        off = (off + bytes + 255) & ~(size_t)255;
        return p;
    };
    // zero-init region first (flag|counts|cursor contiguous -> ONE memset)
    int*            flag      = (int*)           alloc(4);
    int*            counts    = (int*)           alloc((size_t)N * 4);
    int*            cursor    = (int*)           alloc((size_t)N * 4);
    size_t clear_span = (size_t)((char*)cursor + (size_t)N * 4 - (char*)flag);

    unsigned short* x_bf      = (unsigned short*)alloc((size_t)N * F_IN * 2);
    unsigned short* wh_t      = (unsigned short*)alloc((size_t)H_HEADS * D_HID * F_IN * 2);
    float*          ah32      = (float*)         alloc((size_t)H_HEADS * 2 * D_HID * 4);
    float*          Wo32      = (float*)         alloc((size_t)512 * NC * 4);
    float*          ao32      = (float*)         alloc((size_t)2 * NC * 4);
    unsigned short* h_bf      = (unsigned short*)alloc((size_t)N * 512 * 2);
    unsigned short* xcat_bf   = (unsigned short*)alloc((size_t)N * 512 * 2);
    float*          s1s       = (float*)         alloc((size_t)N * 8 * 4);
    float*          s1d       = (float*)         alloc((size_t)N * 8 * 4);
    float*          h2p       = (float*)         alloc((size_t)N * 16 * 4);
    float*          s2s       = (float*)         alloc((size_t)N * 4);
    float*          s2d       = (float*)         alloc((size_t)N * 4);
    int*            row_start = (int*)           alloc((size_t)(N + 1) * 4);
    int*            csr_dst   = (int*)           alloc((size_t)E * 4);
    float*          ev_csr    = (float*)         alloc((size_t)E * 8 * 4);
    (void)ws_size;

    hipMemsetAsync(flag, 0, clear_span, stream);

    // dtype detect, then fused converts + histogram
    detect_kernel<<<1, 256, 0, stream>>>((const unsigned int*)x_raw, flag);
    int bx = (int)(((long)N * F_IN / 8 + 255) / 256);      // x blocks
    int bw = bx + (H_HEADS * F_IN * D_HID) / 256;          // + WhT blocks
    int ba = bw + (H_HEADS * 2 * D_HID) / 256;             // + ah blocks
    int bo = ba + (512 * NC) / 256;                        // + Wo blocks; bo = ao block
    int nb = bo + 1 + (E + 255) / 256;                     // + hist blocks
    prep_kernel<<<nb, 256, 0, stream>>>(x_raw, x_bf, Wh_raw, wh_t, ah_raw, ah32,
                                        Wo_raw, Wo32, ao_raw, ao32,
                                        esrc, counts, flag, N, E, bx, bw, ba, bo);
    scan_kernel<<<1, SCAN_T, 0, stream>>>(counts, row_start, N, E);

    // layer 1
    dim3 g1((N + 63) / 64, H_HEADS / 2);
    gemm1_kernel<<<g1, 256, 0, stream>>>(x_bf, wh_t, ah32, h_bf, s1s, s1d, N);
    scatter_ev_kernel<<<(E + 255) / 256, 256, 0, stream>>>(esrc, edst, row_start, cursor,
                                                           s1s, s1d, csr_dst, ev_csr, E);
    edge_agg1_kernel<<<(N + 3) / 4, 256, 0, stream>>>(row_start, csr_dst, ev_csr,
                                                      (const uint4*)h_bf, (uint4*)xcat_bf, N);

    // layer 2
    gemm2_kernel<<<(N + 255) / 256, 256, 0, stream>>>(xcat_bf, Wo32, ao32, h2p, s2s, s2d, N);
    edge_agg2_kernel<<<(N + 3) / 4, 256, 0, stream>>>(row_start, csr_dst, h2p, s2s, s2d, d_out, flag, N);
}

// Round 12
// 561.059 us; speedup vs baseline: 4.9790x; 1.0429x over previous
//
#include <hip/hip_runtime.h>
#include <hip/hip_bf16.h>

#define F_IN    256
#define D_HID   64
#define H_HEADS 8
#define NC      10
#define ALPHA   0.2f
#define SCAN_T  1024

typedef __attribute__((ext_vector_type(8))) short short8;
typedef __attribute__((ext_vector_type(4))) float f32x4;

// ---------- bf16 helpers ----------
__device__ __forceinline__ float bfu2f(unsigned short u) {
    union { float f; unsigned int i; } c; c.i = ((unsigned int)u) << 16; return c.f;
}
__device__ __forceinline__ unsigned short f2bfu(float f) {
    union { float f; unsigned int i; } c; c.f = f;
    unsigned int x = c.i;
    x += 0x7fffu + ((x >> 16) & 1u);   // round-to-nearest-even
    return (unsigned short)(x >> 16);
}

// ---------- inline dtype detection (f32 vs bf16 storage), wave-uniform ----------
// MUST be called with ALL 64 lanes active (top of kernel, before divergence):
// __ballot only counts active lanes. f32 data -> ~29/64 low-half-huge hits;
// bf16 data -> 0.
__device__ __forceinline__ bool detect_f32(const void* xraw) {
    unsigned int w = ((const unsigned int*)xraw)[threadIdx.x & 63];
    unsigned int e = (w >> 7) & 0xffu;
    unsigned long long m = __ballot(e >= 140u);
    return __popcll(m) > 8;
}

// ---------- fused prep: all input conversions + edge histogram ----------
// blockIdx ranges: [0,bx) x->bf16 | [bx,bw) W frag-layout | [bw,ba) ah |
// [ba,bo) Wo | bo: ao | (bo,...) hist. All roles independent.
__global__ __launch_bounds__(256) void prep_kernel(
    const void* __restrict__ x_raw,  unsigned short* __restrict__ x_bf,
    const void* __restrict__ Wh_raw, unsigned short* __restrict__ wh_f,
    const void* __restrict__ ah_raw, float* __restrict__ ah32,
    const void* __restrict__ Wo_raw, float* __restrict__ Wo32,
    const void* __restrict__ ao_raw, float* __restrict__ ao32,
    const int* __restrict__ esrc, int* __restrict__ counts,
    int N, int E, int bx, int bw, int ba, int bo)
{
    int b = blockIdx.x;
    bool isf32 = detect_f32(x_raw);   // all lanes active here
    if (b < bx) {                       // x -> bf16, 8 elems/thread
        long i = (long)b * 256 + threadIdx.x;
        long n8 = (long)N * F_IN / 8;
        if (i < n8) {
            unsigned short o[8];
            if (isf32) {
                const float* s = (const float*)x_raw + i * 8;
                #pragma unroll
                for (int j = 0; j < 8; ++j) o[j] = f2bfu(s[j]);
            } else {
                *(uint4*)o = ((const uint4*)x_raw)[i];
            }
            *(uint4*)(x_bf + i * 8) = *(uint4*)o;
        }
    } else if (b < bw) {                // W_heads [8][256][64] -> fragment-major bf16
        int i = (b - bx) * 256 + threadIdx.x;
        int d = i & 63, k = (i >> 6) & 255, h = i >> 14;
        float v = isf32 ? ((const float*)Wh_raw)[i] : bfu2f(((const unsigned short*)Wh_raw)[i]);
        // frag layout: [(h*8+ks)*4+c][lane=q*16+m][j], k=ks*32+q*8+j, d=c*16+m
        int ks = k >> 5, q = (k >> 3) & 3, j = k & 7;
        int c = d >> 4, m = d & 15;
        wh_f[(((h * 8 + ks) * 4 + c) << 9) + (q * 16 + m) * 8 + j] = f2bfu(v);
    } else if (b < ba) {                // a_heads -> f32 (1024)
        int i = (b - bw) * 256 + threadIdx.x;
        ah32[i] = isf32 ? ((const float*)ah_raw)[i] : bfu2f(((const unsigned short*)ah_raw)[i]);
    } else if (b < bo) {                // W_out -> f32 (5120)
        int i = (b - ba) * 256 + threadIdx.x;
        Wo32[i] = isf32 ? ((const float*)Wo_raw)[i] : bfu2f(((const unsigned short*)Wo_raw)[i]);
    } else if (b == bo) {               // a_out -> f32 (20)
        int i = threadIdx.x;
        if (i < 2 * NC)
            ao32[i] = isf32 ? ((const float*)ao_raw)[i] : bfu2f(((const unsigned short*)ao_raw)[i]);
    } else {                            // edge histogram
        int e = (b - bo - 1) * 256 + threadIdx.x;
        if (e < E) atomicAdd(&counts[esrc[e]], 1);
    }
}

// ---------- CSR scan ----------
__global__ __launch_bounds__(SCAN_T) void scan_kernel(
    const int* __restrict__ counts, int* __restrict__ row_start, int N, int E)
{
    __shared__ int sums[SCAN_T];
    int t = threadIdx.x;
    int chunk = (N + SCAN_T - 1) / SCAN_T;
    int b = t * chunk, e = min(b + chunk, N);
    int s = 0;
    for (int i = b; i < e; ++i) s += counts[i];
    sums[t] = s;
    __syncthreads();
    for (int off = 1; off < SCAN_T; off <<= 1) {
        int u = (t >= off) ? sums[t - off] : 0;
        __syncthreads();
        sums[t] += u;
        __syncthreads();
    }
    int running = sums[t] - s;
    for (int i = b; i < e; ++i) { row_start[i] = running; running += counts[i]; }
    if (t == SCAN_T - 1) row_start[N] = E;
}

// ---------- CSR scatter + fused layer-1 edge coefficients ----------
__global__ __launch_bounds__(256) void scatter_ev_kernel(
    const int* __restrict__ src, const int* __restrict__ dst,
    const int* __restrict__ row_start, int* __restrict__ cursor,
    const float* __restrict__ s1s, const float* __restrict__ s1d,
    int* __restrict__ csr_dst, float* __restrict__ ev_csr, int E)
{
    int e = blockIdx.x * 256 + threadIdx.x;
    if (e >= E) return;
    int s = src[e], d = dst[e];
    int pos = atomicAdd(&cursor[s], 1);
    int i = row_start[s] + pos;
    csr_dst[i] = d;
    float4 ss0 = *(const float4*)(s1s + s * 8);
    float4 ss1 = *(const float4*)(s1s + s * 8 + 4);
    float4 sd0 = *(const float4*)(s1d + d * 8);
    float4 sd1 = *(const float4*)(s1d + d * 8 + 4);
    float sc[8] = { ss0.x + sd0.x, ss0.y + sd0.y, ss0.z + sd0.z, ss0.w + sd0.w,
                    ss1.x + sd1.x, ss1.y + sd1.y, ss1.z + sd1.z, ss1.w + sd1.w };
    float ev[8];
    #pragma unroll
    for (int h = 0; h < 8; ++h) {
        float lr = sc[h] > 0.f ? sc[h] : ALPHA * sc[h];
        ev[h] = __expf(-lr);
    }
    *(float4*)(ev_csr + (long)i * 8)     = make_float4(ev[0], ev[1], ev[2], ev[3]);
    *(float4*)(ev_csr + (long)i * 8 + 4) = make_float4(ev[4], ev[5], ev[6], ev[7]);
}

// ---------- layer-1 MFMA GEMM + fused attn1 (v6: fragment-major B) ----------
// grid (ceil(N/64), 4): block = 64 rows x 2 heads. B-frag loads are
// lane-contiguous 16B (1 L2 request per wave instr vs 64 scattered lines).
__global__ __launch_bounds__(256) void gemm1_kernel(
    const unsigned short* __restrict__ x_bf,   // [N,256] bf16
    const unsigned short* __restrict__ wh_f,   // fragment-major bf16
    const float* __restrict__ ah,              // [8,128] f32
    unsigned short* __restrict__ h_bf,         // [N,512] bf16 out
    float* __restrict__ s1s, float* __restrict__ s1d, int N)
{
    __shared__ unsigned short Os[64][72];

    const int t = threadIdx.x;
    const int w = t >> 6, lane = t & 63;
    const int q = lane >> 4, m = lane & 15;
    const int n0 = blockIdx.x * 64;
    const int h0 = blockIdx.y * 2;

    int r = n0 + 16 * w + m;
    const unsigned short* xr = x_bf + (long)(r < N ? r : N - 1) * 256;
    short8 afrag[8];
    #pragma unroll
    for (int ks = 0; ks < 8; ++ks)
        afrag[ks] = *(const short8*)(xr + ks * 32 + q * 8);

    #pragma unroll
    for (int hi = 0; hi < 2; ++hi) {
        const int h = h0 + hi;
        f32x4 acc[4] = {};
        const unsigned short* Bh = wh_f + (((long)h * 32) << 9);
        #pragma unroll
        for (int ks = 0; ks < 8; ++ks) {
            #pragma unroll
            for (int c = 0; c < 4; ++c) {
                short8 b = *(const short8*)(Bh + (((ks * 4 + c) << 9) + lane * 8));
                acc[c] = __builtin_amdgcn_mfma_f32_16x16x32_bf16(afrag[ks], b, acc[c], 0, 0, 0);
            }
        }

        // fused attn1: per-row dots with a-vector halves, reduce over 16 col-lanes
        const float* a1 = ah + h * 128;
        float a1m = a1[m], a1m16 = a1[16 + m], a1m32 = a1[32 + m], a1m48 = a1[48 + m];
        float a2m = a1[64 + m], a2m16 = a1[80 + m], a2m32 = a1[96 + m], a2m48 = a1[112 + m];
        #pragma unroll
        for (int reg = 0; reg < 4; ++reg) {
            float p1 = acc[0][reg] * a1m + acc[1][reg] * a1m16 + acc[2][reg] * a1m32 + acc[3][reg] * a1m48;
            float p2 = acc[0][reg] * a2m + acc[1][reg] * a2m16 + acc[2][reg] * a2m32 + acc[3][reg] * a2m48;
            #pragma unroll
            for (int off = 1; off < 16; off <<= 1) {
                p1 += __shfl_xor(p1, off);
                p2 += __shfl_xor(p2, off);
            }
            int row = n0 + 16 * w + q * 4 + reg;
            if (m == 0 && row < N) {
                s1s[row * 8 + h] = p1;
                s1d[row * 8 + h] = p2;
            }
        }

        // stage 16x64 bf16 tile via wave-private LDS rows -> coalesced 16B stores
        #pragma unroll
        for (int c = 0; c < 4; ++c)
            #pragma unroll
            for (int reg = 0; reg < 4; ++reg)
                Os[16 * w + q * 4 + reg][c * 16 + m] = f2bfu(acc[c][reg]);
        #pragma unroll
        for (int j = 0; j < 2; ++j) {
            int cc = j * 64 + lane;
            int row = cc >> 3, c8 = cc & 7;
            if (n0 + 16 * w + row < N)
                *(uint4*)(h_bf + (long)(n0 + 16 * w + row) * 512 + h * 64 + c8 * 8) =
                    *(const uint4*)&Os[16 * w + row][c8 * 8];
        }
    }
}

// ---------- layer-1 CSR gather: ONE WAVE per node, all 8 heads ----------
__global__ __launch_bounds__(256) void edge_agg1_kernel(
    const int* __restrict__ row_start, const int* __restrict__ csr_dst,
    const float* __restrict__ ev_csr,      // [E*8]
    const uint4* __restrict__ h_q,         // [N*64] uint4 (= [N,512] bf16)
    uint4* __restrict__ xcat_q,            // [N*64]
    int N)
{
    int lane = threadIdx.x & 63;
    int n = blockIdx.x * 4 + (threadIdx.x >> 6);
    if (n >= N) return;
    int h = lane >> 3;
    int beg = row_start[n], end = row_start[n + 1];

    float acc[8] = {0.f, 0.f, 0.f, 0.f, 0.f, 0.f, 0.f, 0.f};
    float rs = 0.f;
    int dnext = csr_dst[beg];              // end > beg guaranteed (self-loop)
    for (int i = beg; i < end; ++i) {
        int d = dnext;
        if (i + 1 < end) dnext = csr_dst[i + 1];
        float ev = ev_csr[(long)i * 8 + h];
        uint4 wv = h_q[(long)d * 64 + lane];
        rs += ev;
        acc[0] += ev * bfu2f((unsigned short)(wv.x & 0xffffu));
        acc[1] += ev * bfu2f((unsigned short)(wv.x >> 16));
        acc[2] += ev * bfu2f((unsigned short)(wv.y & 0xffffu));
        acc[3] += ev * bfu2f((unsigned short)(wv.y >> 16));
        acc[4] += ev * bfu2f((unsigned short)(wv.z & 0xffffu));
        acc[5] += ev * bfu2f((unsigned short)(wv.z >> 16));
        acc[6] += ev * bfu2f((unsigned short)(wv.w & 0xffffu));
        acc[7] += ev * bfu2f((unsigned short)(wv.w >> 16));
    }
    float inv = 1.f / rs;
    unsigned short o[8];
    #pragma unroll
    for (int j = 0; j < 8; ++j) {
        float v = acc[j] * inv;
        v = v > 0.f ? v : __expf(v) - 1.f;   // elu
        o[j] = f2bfu(v);
    }
    xcat_q[(long)n * 64 + lane] = *(const uint4*)o;
}

// ---------- layer-2 GEMM + fused attn2: 2 threads per node (split-k) ----------
__global__ __launch_bounds__(256) void gemm2_kernel(
    const unsigned short* __restrict__ xcat_bf, // [N,512] bf16
    const float* __restrict__ Wo,               // [512,10] f32
    const float* __restrict__ ao,               // [20] f32
    float* __restrict__ h2p,                    // [N,16] f32, pad=0
    float* __restrict__ s2s, float* __restrict__ s2d, int N)
{
    int tid = blockIdx.x * 256 + threadIdx.x;
    int n = tid >> 1;
    if (n >= N) return;
    int half = tid & 1;
    float acc[NC];
    #pragma unroll
    for (int c = 0; c < NC; ++c) acc[c] = 0.f;
    const uint4* xp = (const uint4*)(xcat_bf + (long)n * 512) + half * 32;
    for (int k8 = 0; k8 < 32; ++k8) {
        uint4 w = xp[k8];
        float f[8];
        f[0] = bfu2f((unsigned short)(w.x & 0xffffu)); f[1] = bfu2f((unsigned short)(w.x >> 16));
        f[2] = bfu2f((unsigned short)(w.y & 0xffffu)); f[3] = bfu2f((unsigned short)(w.y >> 16));
        f[4] = bfu2f((unsigned short)(w.z & 0xffffu)); f[5] = bfu2f((unsigned short)(w.z >> 16));
        f[6] = bfu2f((unsigned short)(w.w & 0xffffu)); f[7] = bfu2f((unsigned short)(w.w >> 16));
        #pragma unroll
        for (int u = 0; u < 8; ++u) {
            const float* wr = Wo + ((half * 32 + k8) * 8 + u) * NC;
            #pragma unroll
            for (int c = 0; c < NC; ++c) acc[c] += f[u] * wr[c];
        }
    }
    #pragma unroll
    for (int c = 0; c < NC; ++c) acc[c] += __shfl_xor(acc[c], 1, 64);
    if (half == 0) {
        float s1 = 0.f, s2 = 0.f;
        *(float4*)(h2p + (long)n * 16)      = make_float4(acc[0], acc[1], acc[2], acc[3]);
        *(float4*)(h2p + (long)n * 16 + 4)  = make_float4(acc[4], acc[5], acc[6], acc[7]);
        *(float4*)(h2p + (long)n * 16 + 8)  = make_float4(acc[8], acc[9], 0.f, 0.f);
        *(float4*)(h2p + (long)n * 16 + 12) = make_float4(0.f, 0.f, 0.f, 0.f);
        #pragma unroll
        for (int c = 0; c < NC; ++c) {
            s1 += acc[c] * ao[c];
            s2 += acc[c] * ao[NC + c];
        }
        s2s[n] = s1;
        s2d[n] = s2;
    }
}

// ---------- layer-2 CSR gather: wave per node, lane=(edge-slot j, class c) ----------
__global__ __launch_bounds__(256) void edge_agg2_kernel(
    const int* __restrict__ row_start, const int* __restrict__ csr_dst,
    const float* __restrict__ h2p,             // [N,16] f32, pad=0
    const float* __restrict__ s_src2, const float* __restrict__ s_dst2,
    void* __restrict__ out, const void* __restrict__ x_raw, int N)
{
    // detect BEFORE any divergence: __ballot needs all 64 lanes active
    bool isf32 = detect_f32(x_raw);
    int lane = threadIdx.x & 63;
    int n = blockIdx.x * 4 + (threadIdx.x >> 6);
    if (n >= N) return;
    int c = lane & 15, j = lane >> 4;   // 4 edge slots x 16 classes(padded)
    int beg = row_start[n], end = row_start[n + 1];
    float ss = s_src2[n];
    float rs = 0.f, acc = 0.f;
    for (int i0 = beg; i0 < end; i0 += 4) {
        int i = i0 + j;
        if (i < end) {
            int d = csr_dst[i];
            float sc = ss + s_dst2[d];
            float lr = sc > 0.f ? sc : ALPHA * sc;
            float ev = __expf(-lr);
            rs += ev;
            acc += ev * h2p[(long)d * 16 + c];
        }
    }
    rs  += __shfl_xor(rs, 16, 64);  rs  += __shfl_xor(rs, 32, 64);
    acc += __shfl_xor(acc, 16, 64); acc += __shfl_xor(acc, 32, 64);
    float v = acc / rs;
    v = v > 0.f ? v : __expf(v) - 1.f;           // elu
    float vm = (c < NC) ? v : -1e30f;
    #pragma unroll
    for (int off = 1; off < 16; off <<= 1) vm = fmaxf(vm, __shfl_xor(vm, off, 64));
    float ex = (c < NC) ? __expf(v - vm) : 0.f;
    #pragma unroll
    for (int off = 1; off < 16; off <<= 1) ex += __shfl_xor(ex, off, 64);
    float lse = vm + logf(ex);
    if (c < NC && j == 0) {
        if (isf32) ((float*)out)[(long)n * NC + c] = v - lse;
        else       ((unsigned short*)out)[(long)n * NC + c] = f2bfu(v - lse);
    }
}

extern "C" void kernel_launch(void* const* d_in, const int* in_sizes, int n_in,
                              void* d_out, int out_size, void* d_ws, size_t ws_size,
                              hipStream_t stream)
{
    const void* x_raw  = d_in[0];
    const int*  esrc   = (const int*)d_in[1];
    const int*  edst   = (const int*)d_in[2];
    const void* Wh_raw = d_in[3];
    const void* ah_raw = d_in[4];
    const void* Wo_raw = d_in[5];
    const void* ao_raw = d_in[6];

    const int N = in_sizes[0] / F_IN;
    const int E = in_sizes[1];

    char* ws = (char*)d_ws;
    size_t off = 0;
    auto alloc = [&](size_t bytes) -> void* {
        void* p = ws + off;
        off = (off + bytes + 255) & ~(size_t)255;
        return p;
    };
    // zero-init region first (counts|cursor contiguous -> ONE memset)
    int*            counts    = (int*)           alloc((size_t)N * 4);
    int*            cursor    = (int*)           alloc((size_t)N * 4);
    size_t clear_span = (size_t)((char*)cursor + (size_t)N * 4 - (char*)counts);

    unsigned short* x_bf      = (unsigned short*)alloc((size_t)N * F_IN * 2);
    unsigned short* wh_f      = (unsigned short*)alloc((size_t)H_HEADS * D_HID * F_IN * 2);
    float*          ah32      = (float*)         alloc((size_t)H_HEADS * 2 * D_HID * 4);
    float*          Wo32      = (float*)         alloc((size_t)512 * NC * 4);
    float*          ao32      = (float*)         alloc((size_t)2 * NC * 4);
    unsigned short* h_bf      = (unsigned short*)alloc((size_t)N * 512 * 2);
    unsigned short* xcat_bf   = (unsigned short*)alloc((size_t)N * 512 * 2);
    float*          s1s       = (float*)         alloc((size_t)N * 8 * 4);
    float*          s1d       = (float*)         alloc((size_t)N * 8 * 4);
    float*          h2p       = (float*)         alloc((size_t)N * 16 * 4);
    float*          s2s       = (float*)         alloc((size_t)N * 4);
    float*          s2d       = (float*)         alloc((size_t)N * 4);
    int*            row_start = (int*)           alloc((size_t)(N + 1) * 4);
    int*            csr_dst   = (int*)           alloc((size_t)E * 4);
    float*          ev_csr    = (float*)         alloc((size_t)E * 8 * 4);
    (void)ws_size;

    hipMemsetAsync(counts, 0, clear_span, stream);

    // fused converts + histogram (dtype detected per-block from x sample)
    int bx = (int)(((long)N * F_IN / 8 + 255) / 256);      // x blocks
    int bw = bx + (H_HEADS * F_IN * D_HID) / 256;          // + W frag blocks
    int ba = bw + (H_HEADS * 2 * D_HID) / 256;             // + ah blocks
    int bo = ba + (512 * NC) / 256;                        // + Wo blocks; bo = ao block
    int nb = bo + 1 + (E + 255) / 256;                     // + hist blocks
    prep_kernel<<<nb, 256, 0, stream>>>(x_raw, x_bf, Wh_raw, wh_f, ah_raw, ah32,
                                        Wo_raw, Wo32, ao_raw, ao32,
                                        esrc, counts, N, E, bx, bw, ba, bo);
    scan_kernel<<<1, SCAN_T, 0, stream>>>(counts, row_start, N, E);

    // layer 1
    dim3 g1((N + 63) / 64, H_HEADS / 2);
    gemm1_kernel<<<g1, 256, 0, stream>>>(x_bf, wh_f, ah32, h_bf, s1s, s1d, N);
    scatter_ev_kernel<<<(E + 255) / 256, 256, 0, stream>>>(esrc, edst, row_start, cursor,
                                                           s1s, s1d, csr_dst, ev_csr, E);
    edge_agg1_kernel<<<(N + 3) / 4, 256, 0, stream>>>(row_start, csr_dst, ev_csr,
                                                      (const uint4*)h_bf, (uint4*)xcat_bf, N);

    // layer 2
    gemm2_kernel<<<(2 * N + 255) / 256, 256, 0, stream>>>(xcat_bf, Wo32, ao32, h2p, s2s, s2d, N);
    edge_agg2_kernel<<<(N + 3) / 4, 256, 0, stream>>>(row_start, csr_dst, h2p, s2s, s2d, d_out, x_raw, N);
}

// Round 13
// 542.893 us; speedup vs baseline: 5.1456x; 1.0335x over previous
//
#include <hip/hip_runtime.h>
#include <hip/hip_bf16.h>

#define F_IN    256
#define D_HID   64
#define H_HEADS 8
#define NC      10
#define ALPHA   0.2f
#define SCAN_T  1024

typedef __attribute__((ext_vector_type(8))) short short8;
typedef __attribute__((ext_vector_type(4))) float f32x4;

// ---------- bf16 helpers ----------
__device__ __forceinline__ float bfu2f(unsigned short u) {
    union { float f; unsigned int i; } c; c.i = ((unsigned int)u) << 16; return c.f;
}
__device__ __forceinline__ unsigned short f2bfu(float f) {
    union { float f; unsigned int i; } c; c.f = f;
    unsigned int x = c.i;
    x += 0x7fffu + ((x >> 16) & 1u);   // round-to-nearest-even
    return (unsigned short)(x >> 16);
}

// ---------- inline dtype detection (f32 vs bf16 storage), wave-uniform ----------
// MUST run with ALL 64 lanes active (__ballot counts active lanes only).
__device__ __forceinline__ bool detect_f32(const void* xraw) {
    unsigned int w = ((const unsigned int*)xraw)[threadIdx.x & 63];
    unsigned int e = (w >> 7) & 0xffu;
    unsigned long long m = __ballot(e >= 140u);
    return __popcll(m) > 8;
}

// ---------- fused prep: all input conversions + edge histogram ----------
__global__ __launch_bounds__(256) void prep_kernel(
    const void* __restrict__ x_raw,  unsigned short* __restrict__ x_bf,
    const void* __restrict__ Wh_raw, unsigned short* __restrict__ wh_f,
    const void* __restrict__ ah_raw, float* __restrict__ ah32,
    const void* __restrict__ Wo_raw, float* __restrict__ Wo32,
    const void* __restrict__ ao_raw, float* __restrict__ ao32,
    const int* __restrict__ esrc, int* __restrict__ counts,
    int N, int E, int bx, int bw, int ba, int bo)
{
    int b = blockIdx.x;
    bool isf32 = detect_f32(x_raw);   // all lanes active here
    if (b < bx) {                       // x -> bf16, 8 elems/thread
        long i = (long)b * 256 + threadIdx.x;
        long n8 = (long)N * F_IN / 8;
        if (i < n8) {
            unsigned short o[8];
            if (isf32) {
                const float4* s = (const float4*)x_raw + i * 2;
                float4 a = s[0], bb = s[1];
                o[0] = f2bfu(a.x);  o[1] = f2bfu(a.y);
                o[2] = f2bfu(a.z);  o[3] = f2bfu(a.w);
                o[4] = f2bfu(bb.x); o[5] = f2bfu(bb.y);
                o[6] = f2bfu(bb.z); o[7] = f2bfu(bb.w);
            } else {
                *(uint4*)o = ((const uint4*)x_raw)[i];
            }
            *(uint4*)(x_bf + i * 8) = *(uint4*)o;
        }
    } else if (b < bw) {                // W_heads [8][256][64] -> fragment-major bf16
        int i = (b - bx) * 256 + threadIdx.x;
        int d = i & 63, k = (i >> 6) & 255, h = i >> 14;
        float v = isf32 ? ((const float*)Wh_raw)[i] : bfu2f(((const unsigned short*)Wh_raw)[i]);
        int ks = k >> 5, q = (k >> 3) & 3, j = k & 7;
        int c = d >> 4, m = d & 15;
        wh_f[(((h * 8 + ks) * 4 + c) << 9) + (q * 16 + m) * 8 + j] = f2bfu(v);
    } else if (b < ba) {                // a_heads -> f32 (1024)
        int i = (b - bw) * 256 + threadIdx.x;
        ah32[i] = isf32 ? ((const float*)ah_raw)[i] : bfu2f(((const unsigned short*)ah_raw)[i]);
    } else if (b < bo) {                // W_out -> f32 (5120)
        int i = (b - ba) * 256 + threadIdx.x;
        Wo32[i] = isf32 ? ((const float*)Wo_raw)[i] : bfu2f(((const unsigned short*)Wo_raw)[i]);
    } else if (b == bo) {               // a_out -> f32 (20)
        int i = threadIdx.x;
        if (i < 2 * NC)
            ao32[i] = isf32 ? ((const float*)ao_raw)[i] : bfu2f(((const unsigned short*)ao_raw)[i]);
    } else {                            // edge histogram
        int e = (b - bo - 1) * 256 + threadIdx.x;
        if (e < E) atomicAdd(&counts[esrc[e]], 1);
    }
}

// ---------- CSR scan ----------
__global__ __launch_bounds__(SCAN_T) void scan_kernel(
    const int* __restrict__ counts, int* __restrict__ row_start, int N, int E)
{
    __shared__ int sums[SCAN_T];
    int t = threadIdx.x;
    int chunk = (N + SCAN_T - 1) / SCAN_T;
    int b = t * chunk, e = min(b + chunk, N);
    int s = 0;
    for (int i = b; i < e; ++i) s += counts[i];
    sums[t] = s;
    __syncthreads();
    for (int off = 1; off < SCAN_T; off <<= 1) {
        int u = (t >= off) ? sums[t - off] : 0;
        __syncthreads();
        sums[t] += u;
        __syncthreads();
    }
    int running = sums[t] - s;
    for (int i = b; i < e; ++i) { row_start[i] = running; running += counts[i]; }
    if (t == SCAN_T - 1) row_start[N] = E;
}

// ---------- lean CSR scatter: coalesced reads, one atomic, one 4B scatter ----------
__global__ __launch_bounds__(256) void scatter_kernel(
    const int* __restrict__ src, const int* __restrict__ dst,
    const int* __restrict__ row_start, int* __restrict__ cursor,
    int* __restrict__ csr_dst, int E)
{
    int e = blockIdx.x * 256 + threadIdx.x;
    if (e >= E) return;
    int s = src[e];
    int pos = atomicAdd(&cursor[s], 1);
    csr_dst[row_start[s] + pos] = dst[e];
}

// ---------- layer-1 MFMA GEMM + fused attn1 (fragment-major B, 2 heads/block) ----------
__global__ __launch_bounds__(256) void gemm1_kernel(
    const unsigned short* __restrict__ x_bf,   // [N,256] bf16
    const unsigned short* __restrict__ wh_f,   // fragment-major bf16
    const float* __restrict__ ah,              // [8,128] f32
    unsigned short* __restrict__ h_bf,         // [N,512] bf16 out
    float* __restrict__ s1s, float* __restrict__ s1d, int N)
{
    __shared__ unsigned short Os[64][72];

    const int t = threadIdx.x;
    const int w = t >> 6, lane = t & 63;
    const int q = lane >> 4, m = lane & 15;
    const int n0 = blockIdx.x * 64;
    const int h0 = blockIdx.y * 2;

    int r = n0 + 16 * w + m;
    const unsigned short* xr = x_bf + (long)(r < N ? r : N - 1) * 256;
    short8 afrag[8];
    #pragma unroll
    for (int ks = 0; ks < 8; ++ks)
        afrag[ks] = *(const short8*)(xr + ks * 32 + q * 8);

    #pragma unroll
    for (int hi = 0; hi < 2; ++hi) {
        const int h = h0 + hi;
        f32x4 acc[4] = {};
        const unsigned short* Bh = wh_f + (((long)h * 32) << 9);
        #pragma unroll
        for (int ks = 0; ks < 8; ++ks) {
            #pragma unroll
            for (int c = 0; c < 4; ++c) {
                short8 b = *(const short8*)(Bh + (((ks * 4 + c) << 9) + lane * 8));
                acc[c] = __builtin_amdgcn_mfma_f32_16x16x32_bf16(afrag[ks], b, acc[c], 0, 0, 0);
            }
        }

        const float* a1 = ah + h * 128;
        float a1m = a1[m], a1m16 = a1[16 + m], a1m32 = a1[32 + m], a1m48 = a1[48 + m];
        float a2m = a1[64 + m], a2m16 = a1[80 + m], a2m32 = a1[96 + m], a2m48 = a1[112 + m];
        #pragma unroll
        for (int reg = 0; reg < 4; ++reg) {
            float p1 = acc[0][reg] * a1m + acc[1][reg] * a1m16 + acc[2][reg] * a1m32 + acc[3][reg] * a1m48;
            float p2 = acc[0][reg] * a2m + acc[1][reg] * a2m16 + acc[2][reg] * a2m32 + acc[3][reg] * a2m48;
            #pragma unroll
            for (int off = 1; off < 16; off <<= 1) {
                p1 += __shfl_xor(p1, off);
                p2 += __shfl_xor(p2, off);
            }
            int row = n0 + 16 * w + q * 4 + reg;
            if (m == 0 && row < N) {
                s1s[row * 8 + h] = p1;
                s1d[row * 8 + h] = p2;
            }
        }

        #pragma unroll
        for (int c = 0; c < 4; ++c)
            #pragma unroll
            for (int reg = 0; reg < 4; ++reg)
                Os[16 * w + q * 4 + reg][c * 16 + m] = f2bfu(acc[c][reg]);
        #pragma unroll
        for (int j = 0; j < 2; ++j) {
            int cc = j * 64 + lane;
            int row = cc >> 3, c8 = cc & 7;
            if (n0 + 16 * w + row < N)
                *(uint4*)(h_bf + (long)(n0 + 16 * w + row) * 512 + h * 64 + c8 * 8) =
                    *(const uint4*)&Os[16 * w + row][c8 * 8];
        }
    }
}

// ---------- layer-1 CSR gather v4: wave/node, inline ev, 2-edge unroll ----------
// Lane l: h = l>>3, holds uint4 (8 bf16) of the row. Per edge: s1d[d*8+h] is a
// 32B broadcast line (L2-hot); ev computed inline (no ev_csr detour).
__global__ __launch_bounds__(256) void edge_agg1_kernel(
    const int* __restrict__ row_start, const int* __restrict__ csr_dst,
    const float* __restrict__ s1s, const float* __restrict__ s1d,
    const uint4* __restrict__ h_q,         // [N*64] uint4 (= [N,512] bf16)
    uint4* __restrict__ xcat_q,            // [N*64]
    int N)
{
    int lane = threadIdx.x & 63;
    int n = blockIdx.x * 4 + (threadIdx.x >> 6);
    if (n >= N) return;
    int h = lane >> 3;
    int beg = row_start[n], end = row_start[n + 1];
    float ss = s1s[n * 8 + h];

    float acc[8] = {0.f, 0.f, 0.f, 0.f, 0.f, 0.f, 0.f, 0.f};
    float rs = 0.f;
    int i = beg;
    for (; i + 2 <= end; i += 2) {
        int d0 = csr_dst[i], d1 = csr_dst[i + 1];
        float sd0 = s1d[d0 * 8 + h];
        float sd1 = s1d[d1 * 8 + h];
        uint4 w0 = h_q[(long)d0 * 64 + lane];
        uint4 w1 = h_q[(long)d1 * 64 + lane];
        float sc0 = ss + sd0, sc1 = ss + sd1;
        float lr0 = sc0 > 0.f ? sc0 : ALPHA * sc0;
        float lr1 = sc1 > 0.f ? sc1 : ALPHA * sc1;
        float ev0 = __expf(-lr0), ev1 = __expf(-lr1);
        rs += ev0 + ev1;
        acc[0] += ev0 * bfu2f((unsigned short)(w0.x & 0xffffu)) + ev1 * bfu2f((unsigned short)(w1.x & 0xffffu));
        acc[1] += ev0 * bfu2f((unsigned short)(w0.x >> 16))     + ev1 * bfu2f((unsigned short)(w1.x >> 16));
        acc[2] += ev0 * bfu2f((unsigned short)(w0.y & 0xffffu)) + ev1 * bfu2f((unsigned short)(w1.y & 0xffffu));
        acc[3] += ev0 * bfu2f((unsigned short)(w0.y >> 16))     + ev1 * bfu2f((unsigned short)(w1.y >> 16));
        acc[4] += ev0 * bfu2f((unsigned short)(w0.z & 0xffffu)) + ev1 * bfu2f((unsigned short)(w1.z & 0xffffu));
        acc[5] += ev0 * bfu2f((unsigned short)(w0.z >> 16))     + ev1 * bfu2f((unsigned short)(w1.z >> 16));
        acc[6] += ev0 * bfu2f((unsigned short)(w0.w & 0xffffu)) + ev1 * bfu2f((unsigned short)(w1.w & 0xffffu));
        acc[7] += ev0 * bfu2f((unsigned short)(w0.w >> 16))     + ev1 * bfu2f((unsigned short)(w1.w >> 16));
    }
    if (i < end) {
        int d = csr_dst[i];
        float sd = s1d[d * 8 + h];
        uint4 wv = h_q[(long)d * 64 + lane];
        float sc = ss + sd;
        float lr = sc > 0.f ? sc : ALPHA * sc;
        float ev = __expf(-lr);
        rs += ev;
        acc[0] += ev * bfu2f((unsigned short)(wv.x & 0xffffu));
        acc[1] += ev * bfu2f((unsigned short)(wv.x >> 16));
        acc[2] += ev * bfu2f((unsigned short)(wv.y & 0xffffu));
        acc[3] += ev * bfu2f((unsigned short)(wv.y >> 16));
        acc[4] += ev * bfu2f((unsigned short)(wv.z & 0xffffu));
        acc[5] += ev * bfu2f((unsigned short)(wv.z >> 16));
        acc[6] += ev * bfu2f((unsigned short)(wv.w & 0xffffu));
        acc[7] += ev * bfu2f((unsigned short)(wv.w >> 16));
    }
    float inv = 1.f / rs;
    unsigned short o[8];
    #pragma unroll
    for (int j = 0; j < 8; ++j) {
        float v = acc[j] * inv;
        v = v > 0.f ? v : __expf(v) - 1.f;   // elu
        o[j] = f2bfu(v);
    }
    xcat_q[(long)n * 64 + lane] = *(const uint4*)o;
}

// ---------- layer-2 GEMM + fused attn2: 2 threads per node (split-k) ----------
__global__ __launch_bounds__(256) void gemm2_kernel(
    const unsigned short* __restrict__ xcat_bf, // [N,512] bf16
    const float* __restrict__ Wo,               // [512,10] f32
    const float* __restrict__ ao,               // [20] f32
    float* __restrict__ h2p,                    // [N,16] f32, pad=0
    float* __restrict__ s2s, float* __restrict__ s2d, int N)
{
    int tid = blockIdx.x * 256 + threadIdx.x;
    int n = tid >> 1;
    if (n >= N) return;
    int half = tid & 1;
    float acc[NC];
    #pragma unroll
    for (int c = 0; c < NC; ++c) acc[c] = 0.f;
    const uint4* xp = (const uint4*)(xcat_bf + (long)n * 512) + half * 32;
    for (int k8 = 0; k8 < 32; ++k8) {
        uint4 w = xp[k8];
        float f[8];
        f[0] = bfu2f((unsigned short)(w.x & 0xffffu)); f[1] = bfu2f((unsigned short)(w.x >> 16));
        f[2] = bfu2f((unsigned short)(w.y & 0xffffu)); f[3] = bfu2f((unsigned short)(w.y >> 16));
        f[4] = bfu2f((unsigned short)(w.z & 0xffffu)); f[5] = bfu2f((unsigned short)(w.z >> 16));
        f[6] = bfu2f((unsigned short)(w.w & 0xffffu)); f[7] = bfu2f((unsigned short)(w.w >> 16));
        #pragma unroll
        for (int u = 0; u < 8; ++u) {
            const float* wr = Wo + ((half * 32 + k8) * 8 + u) * NC;
            #pragma unroll
            for (int c = 0; c < NC; ++c) acc[c] += f[u] * wr[c];
        }
    }
    #pragma unroll
    for (int c = 0; c < NC; ++c) acc[c] += __shfl_xor(acc[c], 1, 64);
    if (half == 0) {
        float s1 = 0.f, s2 = 0.f;
        *(float4*)(h2p + (long)n * 16)      = make_float4(acc[0], acc[1], acc[2], acc[3]);
        *(float4*)(h2p + (long)n * 16 + 4)  = make_float4(acc[4], acc[5], acc[6], acc[7]);
        *(float4*)(h2p + (long)n * 16 + 8)  = make_float4(acc[8], acc[9], 0.f, 0.f);
        *(float4*)(h2p + (long)n * 16 + 12) = make_float4(0.f, 0.f, 0.f, 0.f);
        #pragma unroll
        for (int c = 0; c < NC; ++c) {
            s1 += acc[c] * ao[c];
            s2 += acc[c] * ao[NC + c];
        }
        s2s[n] = s1;
        s2d[n] = s2;
    }
}

// ---------- layer-2 CSR gather: wave per node, lane=(edge-slot j, class c) ----------
__global__ __launch_bounds__(256) void edge_agg2_kernel(
    const int* __restrict__ row_start, const int* __restrict__ csr_dst,
    const float* __restrict__ h2p,             // [N,16] f32, pad=0
    const float* __restrict__ s_src2, const float* __restrict__ s_dst2,
    void* __restrict__ out, const void* __restrict__ x_raw, int N)
{
    bool isf32 = detect_f32(x_raw);   // all lanes active
    int lane = threadIdx.x & 63;
    int n = blockIdx.x * 4 + (threadIdx.x >> 6);
    if (n >= N) return;
    int c = lane & 15, j = lane >> 4;   // 4 edge slots x 16 classes(padded)
    int beg = row_start[n], end = row_start[n + 1];
    float ss = s_src2[n];
    float rs = 0.f, acc = 0.f;
    for (int i0 = beg; i0 < end; i0 += 4) {
        int i = i0 + j;
        if (i < end) {
            int d = csr_dst[i];
            float sc = ss + s_dst2[d];
            float lr = sc > 0.f ? sc : ALPHA * sc;
            float ev = __expf(-lr);
            rs += ev;
            acc += ev * h2p[(long)d * 16 + c];
        }
    }
    rs  += __shfl_xor(rs, 16, 64);  rs  += __shfl_xor(rs, 32, 64);
    acc += __shfl_xor(acc, 16, 64); acc += __shfl_xor(acc, 32, 64);
    float v = acc / rs;
    v = v > 0.f ? v : __expf(v) - 1.f;           // elu
    float vm = (c < NC) ? v : -1e30f;
    #pragma unroll
    for (int off = 1; off < 16; off <<= 1) vm = fmaxf(vm, __shfl_xor(vm, off, 64));
    float ex = (c < NC) ? __expf(v - vm) : 0.f;
    #pragma unroll
    for (int off = 1; off < 16; off <<= 1) ex += __shfl_xor(ex, off, 64);
    float lse = vm + logf(ex);
    if (c < NC && j == 0) {
        if (isf32) ((float*)out)[(long)n * NC + c] = v - lse;
        else       ((unsigned short*)out)[(long)n * NC + c] = f2bfu(v - lse);
    }
}

extern "C" void kernel_launch(void* const* d_in, const int* in_sizes, int n_in,
                              void* d_out, int out_size, void* d_ws, size_t ws_size,
                              hipStream_t stream)
{
    const void* x_raw  = d_in[0];
    const int*  esrc   = (const int*)d_in[1];
    const int*  edst   = (const int*)d_in[2];
    const void* Wh_raw = d_in[3];
    const void* ah_raw = d_in[4];
    const void* Wo_raw = d_in[5];
    const void* ao_raw = d_in[6];

    const int N = in_sizes[0] / F_IN;
    const int E = in_sizes[1];

    char* ws = (char*)d_ws;
    size_t off = 0;
    auto alloc = [&](size_t bytes) -> void* {
        void* p = ws + off;
        off = (off + bytes + 255) & ~(size_t)255;
        return p;
    };
    // zero-init region first (counts|cursor contiguous -> ONE memset)
    int*            counts    = (int*)           alloc((size_t)N * 4);
    int*            cursor    = (int*)           alloc((size_t)N * 4);
    size_t clear_span = (size_t)((char*)cursor + (size_t)N * 4 - (char*)counts);

    unsigned short* x_bf      = (unsigned short*)alloc((size_t)N * F_IN * 2);
    unsigned short* wh_f      = (unsigned short*)alloc((size_t)H_HEADS * D_HID * F_IN * 2);
    float*          ah32      = (float*)         alloc((size_t)H_HEADS * 2 * D_HID * 4);
    float*          Wo32      = (float*)         alloc((size_t)512 * NC * 4);
    float*          ao32      = (float*)         alloc((size_t)2 * NC * 4);
    unsigned short* h_bf      = (unsigned short*)alloc((size_t)N * 512 * 2);
    unsigned short* xcat_bf   = (unsigned short*)alloc((size_t)N * 512 * 2);
    float*          s1s       = (float*)         alloc((size_t)N * 8 * 4);
    float*          s1d       = (float*)         alloc((size_t)N * 8 * 4);
    float*          h2p       = (float*)         alloc((size_t)N * 16 * 4);
    float*          s2s       = (float*)         alloc((size_t)N * 4);
    float*          s2d       = (float*)         alloc((size_t)N * 4);
    int*            row_start = (int*)           alloc((size_t)(N + 1) * 4);
    int*            csr_dst   = (int*)           alloc((size_t)E * 4);
    (void)ws_size;

    hipMemsetAsync(counts, 0, clear_span, stream);

    // fused converts + histogram (dtype detected per-block from x sample)
    int bx = (int)(((long)N * F_IN / 8 + 255) / 256);      // x blocks
    int bw = bx + (H_HEADS * F_IN * D_HID) / 256;          // + W frag blocks
    int ba = bw + (H_HEADS * 2 * D_HID) / 256;             // + ah blocks
    int bo = ba + (512 * NC) / 256;                        // + Wo blocks; bo = ao block
    int nb = bo + 1 + (E + 255) / 256;                     // + hist blocks
    prep_kernel<<<nb, 256, 0, stream>>>(x_raw, x_bf, Wh_raw, wh_f, ah_raw, ah32,
                                        Wo_raw, Wo32, ao_raw, ao32,
                                        esrc, counts, N, E, bx, bw, ba, bo);
    scan_kernel<<<1, SCAN_T, 0, stream>>>(counts, row_start, N, E);
    scatter_kernel<<<(E + 255) / 256, 256, 0, stream>>>(esrc, edst, row_start, cursor, csr_dst, E);

    // layer 1
    dim3 g1((N + 63) / 64, H_HEADS / 2);
    gemm1_kernel<<<g1, 256, 0, stream>>>(x_bf, wh_f, ah32, h_bf, s1s, s1d, N);
    edge_agg1_kernel<<<(N + 3) / 4, 256, 0, stream>>>(row_start, csr_dst, s1s, s1d,
                                                      (const uint4*)h_bf, (uint4*)xcat_bf, N);

    // layer 2
    gemm2_kernel<<<(2 * N + 255) / 256, 256, 0, stream>>>(xcat_bf, Wo32, ao32, h2p, s2s, s2d, N);
    edge_agg2_kernel<<<(N + 3) / 4, 256, 0, stream>>>(row_start, csr_dst, h2p, s2s, s2d, d_out, x_raw, N);
}